// Round 2
// baseline (11972.894 us; speedup 1.0000x reference)
//
#include <hip/hip_runtime.h>
#include <cmath>

#define L_   2
#define E_   8
#define NH_  16
#define NKV_ 4
#define HD_  64
#define H_   1024
#define I_   1024
#define B_   2
#define S_   1024
#define T_   (B_*S_)
#define KVD_ (NKV_*HD_)
#define V_   32000

// ---------------- embedding gather: x[t][:] = embed[ids[t]][:] ----------------
__global__ void k_embed(const int* __restrict__ ids, const float* __restrict__ emb,
                        float* __restrict__ x)
{
    const int t = blockIdx.x;
    const int id = ids[t];
    const float* src = emb + (size_t)id * H_;
    float* dst = x + (size_t)t * H_;
    for (int i = threadIdx.x; i < H_; i += 256) dst[i] = src[i];
}

// ---------------- layernorm ----------------
__global__ __launch_bounds__(256)
void k_layernorm(const float* __restrict__ x, const float* __restrict__ g,
                 const float* __restrict__ bb, float* __restrict__ out)
{
    const int t = blockIdx.x;
    const float* row = x + (size_t)t * H_;
    float s = 0.f, ss = 0.f;
    for (int i = threadIdx.x; i < H_; i += 256) { const float v = row[i]; s += v; ss += v * v; }
    #pragma unroll
    for (int off = 32; off > 0; off >>= 1) {
        s  += __shfl_down(s, off, 64);
        ss += __shfl_down(ss, off, 64);
    }
    __shared__ float shs[4], shss[4];
    const int w = threadIdx.x >> 6;
    if ((threadIdx.x & 63) == 0) { shs[w] = s; shss[w] = ss; }
    __syncthreads();
    const float fs  = shs[0] + shs[1] + shs[2] + shs[3];
    const float fss = shss[0] + shss[1] + shss[2] + shss[3];
    const float mean = fs * (1.f / H_);
    const float var  = fss * (1.f / H_) - mean * mean;
    const float rstd = 1.0f / sqrtf(var + 1e-5f);
    float* orow = out + (size_t)t * H_;
    for (int i = threadIdx.x; i < H_; i += 256)
        orow[i] = (row[i] - mean) * rstd * g[i] + bb[i];
}

// ---------------- RoPE (in place, f32 [T, nheads*64]) ----------------
__global__ void k_rope(float* __restrict__ x, int nheads)
{
    const int idx  = blockIdx.x * 256 + threadIdx.x;
    const int i    = idx & 31;
    const int rest = idx >> 5;
    const int head = rest % nheads;
    const int t    = rest / nheads;
    const int pos  = t & (S_ - 1);
    const float p32  = (float)pow(1.0e6, (double)i / 32.0);
    const float invf = 1.0f / p32;
    const float ang  = (float)pos * invf;
    const float c = (float)cos((double)ang);
    const float s = (float)sin((double)ang);
    float* base = x + (size_t)t * (nheads * HD_) + head * HD_;
    const float x1 = base[i];
    const float x2 = base[i + 32];
    base[i]      = x1 * c - x2 * s;
    base[i + 32] = x2 * c + x1 * s;
}

// ---------------- causal GQA attention ----------------
__global__ __launch_bounds__(64)
void k_attn(const float* __restrict__ q, const float* __restrict__ kk,
            const float* __restrict__ vv, float* __restrict__ o)
{
    const int q0   = blockIdx.x * 64;
    const int h    = blockIdx.y;
    const int b    = blockIdx.z;
    const int kvh  = h >> 2;           // NH/NKV = 4
    const int lane = threadIdx.x;
    const int row  = q0 + lane;
    __shared__ float Kl[64][68];
    __shared__ float Vl[64][68];
    float qr[64], oacc[64];
    {
        const float* qs = q + (size_t)(b * S_ + row) * (NH_ * HD_) + h * HD_;
        #pragma unroll
        for (int d4 = 0; d4 < 16; d4++) {
            float4 t = *reinterpret_cast<const float4*>(qs + 4 * d4);
            qr[4*d4+0] = t.x * 0.125f; qr[4*d4+1] = t.y * 0.125f;
            qr[4*d4+2] = t.z * 0.125f; qr[4*d4+3] = t.w * 0.125f;
        }
    }
    #pragma unroll
    for (int d = 0; d < 64; d++) oacc[d] = 0.f;
    float lsum = 0.f;
    const int nkb = (q0 >> 6) + 1;
    for (int kb = 0; kb < nkb; kb++) {
        const int j0 = kb * 64;
        __syncthreads();
        {
            const float* ks = kk + (size_t)(b * S_ + j0 + lane) * KVD_ + kvh * HD_;
            const float* vs = vv + (size_t)(b * S_ + j0 + lane) * KVD_ + kvh * HD_;
            #pragma unroll
            for (int d4 = 0; d4 < 16; d4++) {
                *reinterpret_cast<float4*>(&Kl[lane][4*d4]) = *reinterpret_cast<const float4*>(ks + 4*d4);
                *reinterpret_cast<float4*>(&Vl[lane][4*d4]) = *reinterpret_cast<const float4*>(vs + 4*d4);
            }
        }
        __syncthreads();
        const int jend = min(64, row - j0 + 1);
        for (int j = 0; j < jend; j++) {
            float s = 0.f;
            #pragma unroll
            for (int d4 = 0; d4 < 16; d4++) {
                const float4 kv = *reinterpret_cast<const float4*>(&Kl[j][4*d4]);
                s += qr[4*d4+0]*kv.x + qr[4*d4+1]*kv.y + qr[4*d4+2]*kv.z + qr[4*d4+3]*kv.w;
            }
            const float e = expf(s);
            lsum += e;
            #pragma unroll
            for (int d4 = 0; d4 < 16; d4++) {
                const float4 vw = *reinterpret_cast<const float4*>(&Vl[j][4*d4]);
                oacc[4*d4+0] += e * vw.x; oacc[4*d4+1] += e * vw.y;
                oacc[4*d4+2] += e * vw.z; oacc[4*d4+3] += e * vw.w;
            }
        }
    }
    const float inv = 1.0f / lsum;
    float* od = o + (size_t)(b * S_ + row) * (NH_ * HD_) + h * HD_;
    #pragma unroll
    for (int d4 = 0; d4 < 16; d4++) {
        float4 t;
        t.x = oacc[4*d4+0] * inv; t.y = oacc[4*d4+1] * inv;
        t.z = oacc[4*d4+2] * inv; t.w = oacc[4*d4+3] * inv;
        *reinterpret_cast<float4*>(od + 4*d4) = t;
    }
}

// ---------------- MoE gate: logits + top-2 softmax -> dense weight row [8] ----------------
__global__ __launch_bounds__(64)
void k_gate(const float* __restrict__ h, const float* __restrict__ gwt, float* __restrict__ w)
{
    const int t = blockIdx.x;
    const int lane = threadIdx.x;
    const float* row = h + (size_t)t * H_;
    float acc[E_];
    #pragma unroll
    for (int e = 0; e < E_; e++) acc[e] = 0.f;
    for (int i = lane; i < H_; i += 64) {
        const float xv = row[i];
        #pragma unroll
        for (int e = 0; e < E_; e++) acc[e] += xv * gwt[(size_t)e * H_ + i];
    }
    #pragma unroll
    for (int e = 0; e < E_; e++) {
        #pragma unroll
        for (int off = 32; off > 0; off >>= 1) acc[e] += __shfl_down(acc[e], off, 64);
    }
    if (lane == 0) {
        int i1 = 0; float m1 = acc[0];
        #pragma unroll
        for (int e = 1; e < E_; e++) if (acc[e] > m1) { m1 = acc[e]; i1 = e; }
        int i2 = -1; float m2 = -1e30f;
        #pragma unroll
        for (int e = 0; e < E_; e++) if (e != i1 && acc[e] > m2) { m2 = acc[e]; i2 = e; }
        const float e2  = expf(m2 - m1);
        const float den = 1.0f + e2;
        #pragma unroll
        for (int e = 0; e < E_; e++)
            w[t * E_ + e] = (e == i1) ? (1.0f / den) : ((e == i2) ? (e2 / den) : 0.f);
    }
}

// ---------------- silu(g) * u, in place into g ----------------
__global__ void k_silu_mul(float* __restrict__ g, const float* __restrict__ u)
{
    const int i = blockIdx.x * 256 + threadIdx.x;
    const float gv = g[i];
    const float sg = 1.0f / (1.0f + expf(-gv));
    g[i] = gv * sg * u[i];
}

// ---------------- f32 tiled GEMM: C(MxN) = A(MxK) x B ----------------
// BL=0: B is (K,N) row-major. BL=1: B is (N,K) row-major (B^T given).
// EPI: 0 store | 2 C += | 3 C += scale[row*sstr]*acc
template<int BL, int EPI>
__global__ __launch_bounds__(256, 2)
void k_gemm(const float* __restrict__ A, const float* __restrict__ B,
            float* __restrict__ C,
            const float* __restrict__ scale, int sstr,
            int M, int N, int K)
{
    __shared__ float As[128][20];    // 128x16 tile, padded
    __shared__ float Bs[16][132];    // 16x128 tile (k-major), padded
    const int tid = threadIdx.x;
    const int bm0 = blockIdx.y * 128, bn0 = blockIdx.x * 128;
    const int tx = tid & 15, ty = tid >> 4;
    float acc[8][8];
    #pragma unroll
    for (int i = 0; i < 8; i++)
        #pragma unroll
        for (int j = 0; j < 8; j++) acc[i][j] = 0.f;

    const int ra = tid >> 1, ca = (tid & 1) * 8;

    for (int k0 = 0; k0 < K; k0 += 16) {
        __syncthreads();
        {   // A tile 128x16
            const float* src = A + (size_t)(bm0 + ra) * K + (k0 + ca);
            *reinterpret_cast<float4*>(&As[ra][ca])     = *reinterpret_cast<const float4*>(src);
            *reinterpret_cast<float4*>(&As[ra][ca + 4]) = *reinterpret_cast<const float4*>(src + 4);
        }
        if (BL == 0) {   // B (K,N): 16 rows x 128 cols
            const int kb = tid >> 4, n8 = (tid & 15) * 8;
            const float* src = B + (size_t)(k0 + kb) * N + (bn0 + n8);
            *reinterpret_cast<float4*>(&Bs[kb][n8])     = *reinterpret_cast<const float4*>(src);
            *reinterpret_cast<float4*>(&Bs[kb][n8 + 4]) = *reinterpret_cast<const float4*>(src + 4);
        } else {         // B^T (N,K): 128 rows x 16 cols, store transposed
            const int rb = tid >> 1, cb = (tid & 1) * 8;
            const float* src = B + (size_t)(bn0 + rb) * K + (k0 + cb);
            float4 r0 = *reinterpret_cast<const float4*>(src);
            float4 r1 = *reinterpret_cast<const float4*>(src + 4);
            Bs[cb + 0][rb] = r0.x; Bs[cb + 1][rb] = r0.y;
            Bs[cb + 2][rb] = r0.z; Bs[cb + 3][rb] = r0.w;
            Bs[cb + 4][rb] = r1.x; Bs[cb + 5][rb] = r1.y;
            Bs[cb + 6][rb] = r1.z; Bs[cb + 7][rb] = r1.w;
        }
        __syncthreads();
        #pragma unroll
        for (int kkx = 0; kkx < 16; kkx++) {
            float a[8], b[8];
            #pragma unroll
            for (int i = 0; i < 4; i++) {
                a[i]     = As[ty * 4 + i][kkx];
                a[4 + i] = As[64 + ty * 4 + i][kkx];
            }
            const float4 b0 = *reinterpret_cast<const float4*>(&Bs[kkx][tx * 4]);
            const float4 b1 = *reinterpret_cast<const float4*>(&Bs[kkx][64 + tx * 4]);
            b[0] = b0.x; b[1] = b0.y; b[2] = b0.z; b[3] = b0.w;
            b[4] = b1.x; b[5] = b1.y; b[6] = b1.z; b[7] = b1.w;
            #pragma unroll
            for (int i = 0; i < 8; i++)
                #pragma unroll
                for (int j = 0; j < 8; j++) acc[i][j] += a[i] * b[j];
        }
    }
    #pragma unroll
    for (int i = 0; i < 8; i++) {
        const int row = bm0 + (i & 3) + ((i >> 2) * 64) + ty * 4;
        float sc = 0.f;
        if (EPI == 3) sc = scale[(size_t)row * sstr];
        #pragma unroll
        for (int j = 0; j < 8; j++) {
            const int col = bn0 + (j & 3) + ((j >> 2) * 64) + tx * 4;
            const size_t idx = (size_t)row * N + col;
            if (EPI == 0)      C[idx] = acc[i][j];
            else if (EPI == 2) C[idx] += acc[i][j];
            else               C[idx] += sc * acc[i][j];
        }
    }
}

#define GEMM(BL, EPI, A, Bw, CC, SC, SSTR, M, N, K) \
    k_gemm<BL, EPI><<<dim3((N)/128, (M)/128), 256, 0, stream>>>(A, Bw, CC, SC, SSTR, M, N, K)

extern "C" void kernel_launch(void* const* d_in, const int* in_sizes, int n_in,
                              void* d_out, int out_size, void* d_ws, size_t ws_size,
                              hipStream_t stream)
{
    const int*   ids    = (const int*)  d_in[0];
    const float* embed  = (const float*)d_in[1];
    const float* ln1_g  = (const float*)d_in[2];
    const float* ln1_b  = (const float*)d_in[3];
    const float* wq     = (const float*)d_in[4];
    const float* wk     = (const float*)d_in[5];
    const float* wv     = (const float*)d_in[6];
    const float* wo     = (const float*)d_in[7];
    const float* ln2_g  = (const float*)d_in[8];
    const float* ln2_b  = (const float*)d_in[9];
    const float* gate_w = (const float*)d_in[10];
    const float* exp_wg = (const float*)d_in[11];
    const float* exp_wu = (const float*)d_in[12];
    const float* exp_wd = (const float*)d_in[13];
    const float* sh_wg  = (const float*)d_in[14];
    const float* sh_wu  = (const float*)d_in[15];
    const float* sh_wd  = (const float*)d_in[16];
    const float* fn_g   = (const float*)d_in[17];
    const float* fn_b   = (const float*)d_in[18];
    const float* lm     = (const float*)d_in[19];
    float* out = (float*)d_out;

    // workspace (f32): ~52 MB total
    float* x  = (float*)d_ws;                    // T*H residual
    float* h  = x  + (size_t)T_ * H_;            // T*H ln output
    float* qb = h  + (size_t)T_ * H_;            // T*H
    float* kb = qb + (size_t)T_ * H_;            // T*256
    float* vb = kb + (size_t)T_ * KVD_;          // T*256
    float* ob = vb + (size_t)T_ * KVD_;          // T*H attn out
    float* gb = ob + (size_t)T_ * H_;            // T*I
    float* ub = gb + (size_t)T_ * I_;            // T*I
    float* gw = ub + (size_t)T_ * I_;            // T*8 gate weights

    k_embed<<<T_, 256, 0, stream>>>(ids, embed, x);

    for (int l = 0; l < L_; l++) {
        k_layernorm<<<T_, 256, 0, stream>>>(x, ln1_g + (size_t)l * H_, ln1_b + (size_t)l * H_, h);

        GEMM(0, 0, h, wq + (size_t)l * H_ * H_,   qb, nullptr, 0, T_, H_,   H_);
        GEMM(0, 0, h, wk + (size_t)l * H_ * KVD_, kb, nullptr, 0, T_, KVD_, H_);
        GEMM(0, 0, h, wv + (size_t)l * H_ * KVD_, vb, nullptr, 0, T_, KVD_, H_);

        k_rope<<<(T_ * NH_  * 32) / 256, 256, 0, stream>>>(qb, NH_);
        k_rope<<<(T_ * NKV_ * 32) / 256, 256, 0, stream>>>(kb, NKV_);

        k_attn<<<dim3(S_ / 64, NH_, B_), 64, 0, stream>>>(qb, kb, vb, ob);

        GEMM(0, 2, ob, wo + (size_t)l * H_ * H_, x, nullptr, 0, T_, H_, H_);

        k_layernorm<<<T_, 256, 0, stream>>>(x, ln2_g + (size_t)l * H_, ln2_b + (size_t)l * H_, h);
        k_gate<<<T_, 64, 0, stream>>>(h, gate_w + (size_t)l * E_ * H_, gw);

        // shared expert
        GEMM(1, 0, h, sh_wg + (size_t)l * I_ * H_, gb, nullptr, 0, T_, I_, H_);
        GEMM(1, 0, h, sh_wu + (size_t)l * I_ * H_, ub, nullptr, 0, T_, I_, H_);
        k_silu_mul<<<(T_ * I_) / 256, 256, 0, stream>>>(gb, ub);
        GEMM(1, 2, gb, sh_wd + (size_t)l * H_ * I_, x, nullptr, 0, T_, H_, I_);

        // routed experts (dense over all tokens; w_e = 0 rows contribute exactly 0)
        for (int e = 0; e < E_; e++) {
            const float* wg_e = exp_wg + ((size_t)l * E_ + e) * I_ * H_;
            const float* wu_e = exp_wu + ((size_t)l * E_ + e) * I_ * H_;
            const float* wd_e = exp_wd + ((size_t)l * E_ + e) * H_ * I_;
            GEMM(1, 0, h, wg_e, gb, nullptr, 0, T_, I_, H_);
            GEMM(1, 0, h, wu_e, ub, nullptr, 0, T_, I_, H_);
            k_silu_mul<<<(T_ * I_) / 256, 256, 0, stream>>>(gb, ub);
            GEMM(1, 3, gb, wd_e, x, gw + e, E_, T_, H_, I_);
        }
    }

    k_layernorm<<<T_, 256, 0, stream>>>(x, fn_g, fn_b, h);
    GEMM(1, 0, h, lm, out, nullptr, 0, T_, V_, H_);
}

// Round 3
// 7766.164 us; speedup vs baseline: 1.5417x; 1.5417x over previous
//
#include <hip/hip_runtime.h>
#include <cmath>

#define L_   2
#define E_   8
#define NH_  16
#define NKV_ 4
#define HD_  64
#define H_   1024
#define I_   1024
#define B_   2
#define S_   1024
#define T_   (B_*S_)
#define KVD_ (NKV_*HD_)
#define V_   32000
#define CAP_ 5120   // padded compacted rows: 4096 + 8*128 slack

typedef float f32x4 __attribute__((ext_vector_type(4)));
typedef short s16x4 __attribute__((ext_vector_type(4)));
typedef short s16x8 __attribute__((ext_vector_type(8)));

__device__ __forceinline__ short f2bf(float f) {
    unsigned u = __float_as_uint(f);
    u = (u + 0x7fffu + ((u >> 16) & 1u)) >> 16;   // RNE to bf16
    return (short)u;
}

// ---------------- embedding gather ----------------
__global__ void k_embed(const int* __restrict__ ids, const float* __restrict__ emb,
                        float* __restrict__ x)
{
    const int t = blockIdx.x;
    const int id = ids[t];
    const float* src = emb + (size_t)id * H_;
    float* dst = x + (size_t)t * H_;
    for (int i = threadIdx.x; i < H_; i += 256) dst[i] = src[i];
}

// ---------------- layernorm ----------------
__global__ __launch_bounds__(256)
void k_layernorm(const float* __restrict__ x, const float* __restrict__ g,
                 const float* __restrict__ bb, float* __restrict__ out)
{
    const int t = blockIdx.x;
    const float* row = x + (size_t)t * H_;
    float s = 0.f, ss = 0.f;
    for (int i = threadIdx.x; i < H_; i += 256) { const float v = row[i]; s += v; ss += v * v; }
    #pragma unroll
    for (int off = 32; off > 0; off >>= 1) {
        s  += __shfl_down(s, off, 64);
        ss += __shfl_down(ss, off, 64);
    }
    __shared__ float shs[4], shss[4];
    const int w = threadIdx.x >> 6;
    if ((threadIdx.x & 63) == 0) { shs[w] = s; shss[w] = ss; }
    __syncthreads();
    const float fs  = shs[0] + shs[1] + shs[2] + shs[3];
    const float fss = shss[0] + shss[1] + shss[2] + shss[3];
    const float mean = fs * (1.f / H_);
    const float var  = fss * (1.f / H_) - mean * mean;
    const float rstd = 1.0f / sqrtf(var + 1e-5f);
    float* orow = out + (size_t)t * H_;
    for (int i = threadIdx.x; i < H_; i += 256)
        orow[i] = (row[i] - mean) * rstd * g[i] + bb[i];
}

// ---------------- RoPE ----------------
__global__ void k_rope(float* __restrict__ x, int nheads)
{
    const int idx  = blockIdx.x * 256 + threadIdx.x;
    const int i    = idx & 31;
    const int rest = idx >> 5;
    const int head = rest % nheads;
    const int t    = rest / nheads;
    const int pos  = t & (S_ - 1);
    const float p32  = (float)pow(1.0e6, (double)i / 32.0);
    const float invf = 1.0f / p32;
    const float ang  = (float)pos * invf;
    const float c = (float)cos((double)ang);
    const float s = (float)sin((double)ang);
    float* base = x + (size_t)t * (nheads * HD_) + head * HD_;
    const float x1 = base[i];
    const float x2 = base[i + 32];
    base[i]      = x1 * c - x2 * s;
    base[i + 32] = x2 * c + x1 * s;
}

// ---------------- causal GQA attention ----------------
__global__ __launch_bounds__(64)
void k_attn(const float* __restrict__ q, const float* __restrict__ kk,
            const float* __restrict__ vv, float* __restrict__ o)
{
    const int q0   = blockIdx.x * 64;
    const int h    = blockIdx.y;
    const int b    = blockIdx.z;
    const int kvh  = h >> 2;
    const int lane = threadIdx.x;
    const int row  = q0 + lane;
    __shared__ float Kl[64][68];
    __shared__ float Vl[64][68];
    float qr[64], oacc[64];
    {
        const float* qs = q + (size_t)(b * S_ + row) * (NH_ * HD_) + h * HD_;
        #pragma unroll
        for (int d4 = 0; d4 < 16; d4++) {
            float4 t = *reinterpret_cast<const float4*>(qs + 4 * d4);
            qr[4*d4+0] = t.x * 0.125f; qr[4*d4+1] = t.y * 0.125f;
            qr[4*d4+2] = t.z * 0.125f; qr[4*d4+3] = t.w * 0.125f;
        }
    }
    #pragma unroll
    for (int d = 0; d < 64; d++) oacc[d] = 0.f;
    float lsum = 0.f;
    const int nkb = (q0 >> 6) + 1;
    for (int kb = 0; kb < nkb; kb++) {
        const int j0 = kb * 64;
        __syncthreads();
        {
            const float* ks = kk + (size_t)(b * S_ + j0 + lane) * KVD_ + kvh * HD_;
            const float* vs = vv + (size_t)(b * S_ + j0 + lane) * KVD_ + kvh * HD_;
            #pragma unroll
            for (int d4 = 0; d4 < 16; d4++) {
                *reinterpret_cast<float4*>(&Kl[lane][4*d4]) = *reinterpret_cast<const float4*>(ks + 4*d4);
                *reinterpret_cast<float4*>(&Vl[lane][4*d4]) = *reinterpret_cast<const float4*>(vs + 4*d4);
            }
        }
        __syncthreads();
        const int jend = min(64, row - j0 + 1);
        for (int j = 0; j < jend; j++) {
            float s = 0.f;
            #pragma unroll
            for (int d4 = 0; d4 < 16; d4++) {
                const float4 kv = *reinterpret_cast<const float4*>(&Kl[j][4*d4]);
                s += qr[4*d4+0]*kv.x + qr[4*d4+1]*kv.y + qr[4*d4+2]*kv.z + qr[4*d4+3]*kv.w;
            }
            const float e = expf(s);
            lsum += e;
            #pragma unroll
            for (int d4 = 0; d4 < 16; d4++) {
                const float4 vw = *reinterpret_cast<const float4*>(&Vl[j][4*d4]);
                oacc[4*d4+0] += e * vw.x; oacc[4*d4+1] += e * vw.y;
                oacc[4*d4+2] += e * vw.z; oacc[4*d4+3] += e * vw.w;
            }
        }
    }
    const float inv = 1.0f / lsum;
    float* od = o + (size_t)(b * S_ + row) * (NH_ * HD_) + h * HD_;
    #pragma unroll
    for (int d4 = 0; d4 < 16; d4++) {
        float4 t;
        t.x = oacc[4*d4+0] * inv; t.y = oacc[4*d4+1] * inv;
        t.z = oacc[4*d4+2] * inv; t.w = oacc[4*d4+3] * inv;
        *reinterpret_cast<float4*>(od + 4*d4) = t;
    }
}

// ---------------- MoE gate ----------------
__global__ __launch_bounds__(64)
void k_gate(const float* __restrict__ h, const float* __restrict__ gwt, float* __restrict__ w)
{
    const int t = blockIdx.x;
    const int lane = threadIdx.x;
    const float* row = h + (size_t)t * H_;
    float acc[E_];
    #pragma unroll
    for (int e = 0; e < E_; e++) acc[e] = 0.f;
    for (int i = lane; i < H_; i += 64) {
        const float xv = row[i];
        #pragma unroll
        for (int e = 0; e < E_; e++) acc[e] += xv * gwt[(size_t)e * H_ + i];
    }
    #pragma unroll
    for (int e = 0; e < E_; e++) {
        #pragma unroll
        for (int off = 32; off > 0; off >>= 1) acc[e] += __shfl_down(acc[e], off, 64);
    }
    if (lane == 0) {
        int i1 = 0; float m1 = acc[0];
        #pragma unroll
        for (int e = 1; e < E_; e++) if (acc[e] > m1) { m1 = acc[e]; i1 = e; }
        int i2 = -1; float m2 = -1e30f;
        #pragma unroll
        for (int e = 0; e < E_; e++) if (e != i1 && acc[e] > m2) { m2 = acc[e]; i2 = e; }
        const float e2  = expf(m2 - m1);
        const float den = 1.0f + e2;
        #pragma unroll
        for (int e = 0; e < E_; e++)
            w[t * E_ + e] = (e == i1) ? (1.0f / den) : ((e == i2) ? (e2 / den) : 0.f);
    }
}

// ---------------- build per-expert token lists (deterministic, ordered) ----------------
__global__ __launch_bounds__(512)
void k_build(const float* __restrict__ gw, int* __restrict__ idx, float* __restrict__ wl,
             int* __restrict__ cnt, int* __restrict__ seg)
{
    const int e = threadIdx.x >> 6;
    const int lane = threadIdx.x & 63;
    __shared__ int scnt[E_], sseg[E_];
    int c = 0;
    for (int t0 = 0; t0 < T_; t0 += 64) {
        const float v = gw[(size_t)(t0 + lane) * E_ + e];
        c += __popcll(__ballot(v > 0.f));
    }
    if (lane == 0) scnt[e] = c;
    __syncthreads();
    if (threadIdx.x == 0) {
        int off = 0;
        for (int q = 0; q < E_; q++) {
            sseg[q] = off; cnt[q] = scnt[q]; seg[q] = off;
            off += (scnt[q] + 127) & ~127;
        }
    }
    __syncthreads();
    int pos = sseg[e];
    for (int t0 = 0; t0 < T_; t0 += 64) {
        const int t = t0 + lane;
        const float v = gw[(size_t)t * E_ + e];
        const unsigned long long m = __ballot(v > 0.f);
        if (v > 0.f) {
            const int p = pos + __popcll(m & ((1ull << lane) - 1ull));
            idx[p] = t; wl[p] = v;
        }
        pos += __popcll(m);
    }
}

// ---------------- f32 SIMT GEMM: C(MxN) = A(MxK) x B ----------------
// BL=0: B (K,N) row-major. BL=1: B (N,K) row-major (B^T).
// EPI: 0 store | 2 C += | 4 C = silu(C) * acc
template<int BL, int EPI>
__global__ __launch_bounds__(256, 2)
void k_gemm(const float* __restrict__ A, const float* __restrict__ B,
            float* __restrict__ C, int M, int N, int K)
{
    __shared__ float As[128][20];
    __shared__ float Bs[16][132];
    const int tid = threadIdx.x;
    const int bm0 = blockIdx.y * 128, bn0 = blockIdx.x * 128;
    const int tx = tid & 15, ty = tid >> 4;
    float acc[8][8];
    #pragma unroll
    for (int i = 0; i < 8; i++)
        #pragma unroll
        for (int j = 0; j < 8; j++) acc[i][j] = 0.f;

    const int ra = tid >> 1, ca = (tid & 1) * 8;

    for (int k0 = 0; k0 < K; k0 += 16) {
        __syncthreads();
        {
            const float* src = A + (size_t)(bm0 + ra) * K + (k0 + ca);
            *reinterpret_cast<float4*>(&As[ra][ca])     = *reinterpret_cast<const float4*>(src);
            *reinterpret_cast<float4*>(&As[ra][ca + 4]) = *reinterpret_cast<const float4*>(src + 4);
        }
        if (BL == 0) {
            const int kb = tid >> 4, n8 = (tid & 15) * 8;
            const float* src = B + (size_t)(k0 + kb) * N + (bn0 + n8);
            *reinterpret_cast<float4*>(&Bs[kb][n8])     = *reinterpret_cast<const float4*>(src);
            *reinterpret_cast<float4*>(&Bs[kb][n8 + 4]) = *reinterpret_cast<const float4*>(src + 4);
        } else {
            const int rb = tid >> 1, cb = (tid & 1) * 8;
            const float* src = B + (size_t)(bn0 + rb) * K + (k0 + cb);
            float4 r0 = *reinterpret_cast<const float4*>(src);
            float4 r1 = *reinterpret_cast<const float4*>(src + 4);
            Bs[cb + 0][rb] = r0.x; Bs[cb + 1][rb] = r0.y;
            Bs[cb + 2][rb] = r0.z; Bs[cb + 3][rb] = r0.w;
            Bs[cb + 4][rb] = r1.x; Bs[cb + 5][rb] = r1.y;
            Bs[cb + 6][rb] = r1.z; Bs[cb + 7][rb] = r1.w;
        }
        __syncthreads();
        #pragma unroll
        for (int kkx = 0; kkx < 16; kkx++) {
            float a[8], b[8];
            #pragma unroll
            for (int i = 0; i < 4; i++) {
                a[i]     = As[ty * 4 + i][kkx];
                a[4 + i] = As[64 + ty * 4 + i][kkx];
            }
            const float4 b0 = *reinterpret_cast<const float4*>(&Bs[kkx][tx * 4]);
            const float4 b1 = *reinterpret_cast<const float4*>(&Bs[kkx][64 + tx * 4]);
            b[0] = b0.x; b[1] = b0.y; b[2] = b0.z; b[3] = b0.w;
            b[4] = b1.x; b[5] = b1.y; b[6] = b1.z; b[7] = b1.w;
            #pragma unroll
            for (int i = 0; i < 8; i++)
                #pragma unroll
                for (int j = 0; j < 8; j++) acc[i][j] += a[i] * b[j];
        }
    }
    #pragma unroll
    for (int i = 0; i < 8; i++) {
        const int row = bm0 + (i & 3) + ((i >> 2) * 64) + ty * 4;
        #pragma unroll
        for (int j = 0; j < 8; j++) {
            const int col = bn0 + (j & 3) + ((j >> 2) * 64) + tx * 4;
            const size_t p = (size_t)row * N + col;
            if (EPI == 0)      C[p] = acc[i][j];
            else if (EPI == 2) C[p] += acc[i][j];
            else if (EPI == 4) {
                const float gv = C[p];
                C[p] = gv * (1.f / (1.f + expf(-gv))) * acc[i][j];
            }
        }
    }
}

// ---------------- sparse MoE GEMM (f32 SIMT, gather/scatter) ----------------
// OP 0: gbuf[s+r] = h[idx[s+r]] @ Wg_e^T          (gather A, store)
// OP 1: gbuf[s+r] = silu(gbuf[s+r]) * (h[idx]@Wu) (gather A, silu-fuse)
// OP 2: x[idx[s+r]] += wl[s+r] * (gbuf[s+r] @ Wd) (flat A, scatter +=; launched per-expert)
template<int OP>
__global__ __launch_bounds__(256, 2)
void k_gemm_moe(const float* __restrict__ A, const float* __restrict__ Wb,
                float* __restrict__ Cb, float* __restrict__ xout,
                const int* __restrict__ idx, const float* __restrict__ wl,
                const int* __restrict__ cnt, const int* __restrict__ seg,
                int N, int K, int eBase)
{
    const int e = eBase + blockIdx.z;
    const int c = cnt[e];
    const int bm0 = blockIdx.y * 128;
    if (bm0 >= c) return;
    const int s = seg[e];
    const float* B = Wb + (size_t)e * N * K;
    const int bn0 = blockIdx.x * 128;

    __shared__ float As[128][20];
    __shared__ float Bs[16][132];
    const int tid = threadIdx.x;
    const int tx = tid & 15, ty = tid >> 4;
    float acc[8][8];
    #pragma unroll
    for (int i = 0; i < 8; i++)
        #pragma unroll
        for (int j = 0; j < 8; j++) acc[i][j] = 0.f;

    const int ra = tid >> 1, ca = (tid & 1) * 8;
    const int lr = min(bm0 + ra, c - 1);
    const size_t arow = (OP < 2) ? (size_t)idx[s + lr] : (size_t)(s + lr);
    const float* asrc = A + arow * K;

    for (int k0 = 0; k0 < K; k0 += 16) {
        __syncthreads();
        {
            const float* src = asrc + k0 + ca;
            *reinterpret_cast<float4*>(&As[ra][ca])     = *reinterpret_cast<const float4*>(src);
            *reinterpret_cast<float4*>(&As[ra][ca + 4]) = *reinterpret_cast<const float4*>(src + 4);
        }
        {
            const float* src = B + (size_t)(bn0 + ra) * K + (k0 + ca);
            float4 r0 = *reinterpret_cast<const float4*>(src);
            float4 r1 = *reinterpret_cast<const float4*>(src + 4);
            Bs[ca + 0][ra] = r0.x; Bs[ca + 1][ra] = r0.y;
            Bs[ca + 2][ra] = r0.z; Bs[ca + 3][ra] = r0.w;
            Bs[ca + 4][ra] = r1.x; Bs[ca + 5][ra] = r1.y;
            Bs[ca + 6][ra] = r1.z; Bs[ca + 7][ra] = r1.w;
        }
        __syncthreads();
        #pragma unroll
        for (int kkx = 0; kkx < 16; kkx++) {
            float a[8], b[8];
            #pragma unroll
            for (int i = 0; i < 4; i++) {
                a[i]     = As[ty * 4 + i][kkx];
                a[4 + i] = As[64 + ty * 4 + i][kkx];
            }
            const float4 b0 = *reinterpret_cast<const float4*>(&Bs[kkx][tx * 4]);
            const float4 b1 = *reinterpret_cast<const float4*>(&Bs[kkx][64 + tx * 4]);
            b[0] = b0.x; b[1] = b0.y; b[2] = b0.z; b[3] = b0.w;
            b[4] = b1.x; b[5] = b1.y; b[6] = b1.z; b[7] = b1.w;
            #pragma unroll
            for (int i = 0; i < 8; i++)
                #pragma unroll
                for (int j = 0; j < 8; j++) acc[i][j] += a[i] * b[j];
        }
    }
    #pragma unroll
    for (int i = 0; i < 8; i++) {
        const int row = bm0 + (i & 3) + ((i >> 2) * 64) + ty * 4;
        if (row >= c) continue;
        int tok = 0; float wv = 0.f;
        if (OP == 2) { tok = idx[s + row]; wv = wl[s + row]; }
        #pragma unroll
        for (int j = 0; j < 8; j++) {
            const int col = bn0 + (j & 3) + ((j >> 2) * 64) + tx * 4;
            if (OP == 0) {
                Cb[(size_t)(s + row) * N + col] = acc[i][j];
            } else if (OP == 1) {
                const size_t p = (size_t)(s + row) * N + col;
                const float gv = Cb[p];
                Cb[p] = gv * (1.f / (1.f + expf(-gv))) * acc[i][j];
            } else {
                xout[(size_t)tok * N + col] += wv * acc[i][j];
            }
        }
    }
}

// ---------------- bf16 MFMA GEMM: C(M,N) f32 = A(M,K) f32 x B(N,K) f32 ----------------
// 128x128 tile, 4 waves (2x2 of 64x64), 16x16x32 bf16 MFMA, reg-staged f32->bf16.
__global__ __launch_bounds__(256)
void k_gemm_mfma_bt(const float* __restrict__ A, const float* __restrict__ Bm,
                    float* __restrict__ C, int M, int N, int K)
{
    __shared__ short Al[128 * 32];
    __shared__ short Bl[128 * 32];
    const int mB = M >> 7;
    const int l  = blockIdx.x;
    const int g  = l / (mB * 8);
    const int ii = l - g * (mB * 8);
    const int bm0 = (ii % mB) * 128;
    const int bn0 = (g * 8 + ii / mB) * 128;

    const int tid  = threadIdx.x;
    const int lane = tid & 63, w = tid >> 6;
    const int wr = w >> 1, wc = w & 1;
    const int fr = lane & 15, fg = lane >> 4;

    const int srow = tid >> 1, sk = (tid & 1) * 16;
    const float* pa = A  + (size_t)(bm0 + srow) * K + sk;
    const float* pb = Bm + (size_t)(bn0 + srow) * K + sk;

    f32x4 acc[4][4];
    #pragma unroll
    for (int m = 0; m < 4; m++)
        #pragma unroll
        for (int n = 0; n < 4; n++) acc[m][n] = (f32x4){0.f, 0.f, 0.f, 0.f};

    float4 ra[4], rb[4];
    #pragma unroll
    for (int q = 0; q < 4; q++) {
        ra[q] = *reinterpret_cast<const float4*>(pa + 4 * q);
        rb[q] = *reinterpret_cast<const float4*>(pb + 4 * q);
    }

    for (int k0 = 0; k0 < K; k0 += 32) {
        s16x8 apk0, apk1, bpk0, bpk1;
        apk0[0]=f2bf(ra[0].x); apk0[1]=f2bf(ra[0].y); apk0[2]=f2bf(ra[0].z); apk0[3]=f2bf(ra[0].w);
        apk0[4]=f2bf(ra[1].x); apk0[5]=f2bf(ra[1].y); apk0[6]=f2bf(ra[1].z); apk0[7]=f2bf(ra[1].w);
        apk1[0]=f2bf(ra[2].x); apk1[1]=f2bf(ra[2].y); apk1[2]=f2bf(ra[2].z); apk1[3]=f2bf(ra[2].w);
        apk1[4]=f2bf(ra[3].x); apk1[5]=f2bf(ra[3].y); apk1[6]=f2bf(ra[3].z); apk1[7]=f2bf(ra[3].w);
        bpk0[0]=f2bf(rb[0].x); bpk0[1]=f2bf(rb[0].y); bpk0[2]=f2bf(rb[0].z); bpk0[3]=f2bf(rb[0].w);
        bpk0[4]=f2bf(rb[1].x); bpk0[5]=f2bf(rb[1].y); bpk0[6]=f2bf(rb[1].z); bpk0[7]=f2bf(rb[1].w);
        bpk1[0]=f2bf(rb[2].x); bpk1[1]=f2bf(rb[2].y); bpk1[2]=f2bf(rb[2].z); bpk1[3]=f2bf(rb[2].w);
        bpk1[4]=f2bf(rb[3].x); bpk1[5]=f2bf(rb[3].y); bpk1[6]=f2bf(rb[3].z); bpk1[7]=f2bf(rb[3].w);

        __syncthreads();
        *reinterpret_cast<s16x8*>(&Al[srow * 32 + sk])     = apk0;
        *reinterpret_cast<s16x8*>(&Al[srow * 32 + sk + 8]) = apk1;
        *reinterpret_cast<s16x8*>(&Bl[srow * 32 + sk])     = bpk0;
        *reinterpret_cast<s16x8*>(&Bl[srow * 32 + sk + 8]) = bpk1;
        __syncthreads();

        if (k0 + 32 < K) {
            #pragma unroll
            for (int q = 0; q < 4; q++) {
                ra[q] = *reinterpret_cast<const float4*>(pa + k0 + 32 + 4 * q);
                rb[q] = *reinterpret_cast<const float4*>(pb + k0 + 32 + 4 * q);
            }
        }

        s16x8 af[4], bfv[4];
        #pragma unroll
        for (int m = 0; m < 4; m++) {
            const int base = (wr * 64 + m * 16 + fr) * 32 + fg * 4;
            s16x4 lo = *reinterpret_cast<const s16x4*>(&Al[base]);
            s16x4 hi = *reinterpret_cast<const s16x4*>(&Al[base + 16]);
            af[m] = __builtin_shufflevector(lo, hi, 0, 1, 2, 3, 4, 5, 6, 7);
        }
        #pragma unroll
        for (int n = 0; n < 4; n++) {
            const int base = (wc * 64 + n * 16 + fr) * 32 + fg * 4;
            s16x4 lo = *reinterpret_cast<const s16x4*>(&Bl[base]);
            s16x4 hi = *reinterpret_cast<const s16x4*>(&Bl[base + 16]);
            bfv[n] = __builtin_shufflevector(lo, hi, 0, 1, 2, 3, 4, 5, 6, 7);
        }
        #pragma unroll
        for (int m = 0; m < 4; m++)
            #pragma unroll
            for (int n = 0; n < 4; n++)
                acc[m][n] = __builtin_amdgcn_mfma_f32_16x16x32_bf16(af[m], bfv[n], acc[m][n], 0, 0, 0);
    }

    #pragma unroll
    for (int m = 0; m < 4; m++) {
        #pragma unroll
        for (int n = 0; n < 4; n++) {
            #pragma unroll
            for (int r = 0; r < 4; r++) {
                const int row = bm0 + wr * 64 + m * 16 + fg * 4 + r;
                const int col = bn0 + wc * 64 + n * 16 + fr;
                C[(size_t)row * N + col] = acc[m][n][r];
            }
        }
    }
}

#define GEMM(BL, EPI, A, Bw, CC, M, N, K) \
    k_gemm<BL, EPI><<<dim3((N)/128, (M)/128), 256, 0, stream>>>(A, Bw, CC, M, N, K)

extern "C" void kernel_launch(void* const* d_in, const int* in_sizes, int n_in,
                              void* d_out, int out_size, void* d_ws, size_t ws_size,
                              hipStream_t stream)
{
    const int*   ids    = (const int*)  d_in[0];
    const float* embed  = (const float*)d_in[1];
    const float* ln1_g  = (const float*)d_in[2];
    const float* ln1_b  = (const float*)d_in[3];
    const float* wq     = (const float*)d_in[4];
    const float* wk     = (const float*)d_in[5];
    const float* wv     = (const float*)d_in[6];
    const float* wo     = (const float*)d_in[7];
    const float* ln2_g  = (const float*)d_in[8];
    const float* ln2_b  = (const float*)d_in[9];
    const float* gate_w = (const float*)d_in[10];
    const float* exp_wg = (const float*)d_in[11];
    const float* exp_wu = (const float*)d_in[12];
    const float* exp_wd = (const float*)d_in[13];
    const float* sh_wg  = (const float*)d_in[14];
    const float* sh_wu  = (const float*)d_in[15];
    const float* sh_wd  = (const float*)d_in[16];
    const float* fn_g   = (const float*)d_in[17];
    const float* fn_b   = (const float*)d_in[18];
    const float* lm     = (const float*)d_in[19];
    float* out = (float*)d_out;

    float* x    = (float*)d_ws;                    // T*H
    float* h    = x    + (size_t)T_ * H_;          // T*H
    float* qb   = h    + (size_t)T_ * H_;          // T*H
    float* kb   = qb   + (size_t)T_ * H_;          // T*KVD
    float* vb   = kb   + (size_t)T_ * KVD_;        // T*KVD
    float* ob   = vb   + (size_t)T_ * KVD_;        // T*H
    float* gbuf = ob   + (size_t)T_ * H_;          // CAP*I
    float* gw   = gbuf + (size_t)CAP_ * I_;        // T*8
    float* wl   = gw   + (size_t)T_ * E_;          // CAP
    int*   idx  = (int*)(wl + CAP_);               // CAP
    int*   cnt  = idx + CAP_;                      // 8
    int*   seg  = cnt + E_;                        // 8

    k_embed<<<T_, 256, 0, stream>>>(ids, embed, x);

    for (int l = 0; l < L_; l++) {
        k_layernorm<<<T_, 256, 0, stream>>>(x, ln1_g + (size_t)l * H_, ln1_b + (size_t)l * H_, h);

        GEMM(0, 0, h, wq + (size_t)l * H_ * H_,   qb, T_, H_,   H_);
        GEMM(0, 0, h, wk + (size_t)l * H_ * KVD_, kb, T_, KVD_, H_);
        GEMM(0, 0, h, wv + (size_t)l * H_ * KVD_, vb, T_, KVD_, H_);

        k_rope<<<(T_ * NH_  * 32) / 256, 256, 0, stream>>>(qb, NH_);
        k_rope<<<(T_ * NKV_ * 32) / 256, 256, 0, stream>>>(kb, NKV_);

        k_attn<<<dim3(S_ / 64, NH_, B_), 64, 0, stream>>>(qb, kb, vb, ob);

        GEMM(0, 2, ob, wo + (size_t)l * H_ * H_, x, T_, H_, H_);

        k_layernorm<<<T_, 256, 0, stream>>>(x, ln2_g + (size_t)l * H_, ln2_b + (size_t)l * H_, h);
        k_gate<<<T_, 64, 0, stream>>>(h, gate_w + (size_t)l * E_ * H_, gw);
        k_build<<<1, 512, 0, stream>>>(gw, idx, wl, cnt, seg);

        // shared expert (silu fused into wu epilogue)
        GEMM(1, 0, h, sh_wg + (size_t)l * I_ * H_, gbuf, T_, I_, H_);
        GEMM(1, 4, h, sh_wu + (size_t)l * I_ * H_, gbuf, T_, I_, H_);
        GEMM(1, 2, gbuf, sh_wd + (size_t)l * H_ * I_, x, T_, H_, I_);

        // routed experts, sparse
        const float* wg_l = exp_wg + (size_t)l * E_ * I_ * H_;
        const float* wu_l = exp_wu + (size_t)l * E_ * I_ * H_;
        const float* wd_l = exp_wd + (size_t)l * E_ * H_ * I_;
        k_gemm_moe<0><<<dim3(I_/128, T_/128, E_), 256, 0, stream>>>(
            h, wg_l, gbuf, nullptr, idx, wl, cnt, seg, I_, H_, 0);
        k_gemm_moe<1><<<dim3(I_/128, T_/128, E_), 256, 0, stream>>>(
            h, wu_l, gbuf, nullptr, idx, wl, cnt, seg, I_, H_, 0);
        for (int e = 0; e < E_; e++)   // sequential: deterministic scatter order, no races
            k_gemm_moe<2><<<dim3(H_/128, T_/128, 1), 256, 0, stream>>>(
                gbuf, wd_l, nullptr, x, idx, wl, cnt, seg, H_, I_, e);
    }

    k_layernorm<<<T_, 256, 0, stream>>>(x, fn_g, fn_b, h);
    k_gemm_mfma_bt<<<(T_/128) * (V_/128), 256, 0, stream>>>(h, lm, out, T_, V_, H_);
}

// Round 6
// 3569.128 us; speedup vs baseline: 3.3546x; 2.1759x over previous
//
#include <hip/hip_runtime.h>
#include <cmath>

#define L_   2
#define E_   8
#define NH_  16
#define NKV_ 4
#define HD_  64
#define H_   1024
#define I_   1024
#define B_   2
#define S_   1024
#define T_   (B_*S_)
#define V_   32000
#define CAP_ 5120

typedef float f32x4 __attribute__((ext_vector_type(4)));
typedef short s16x4 __attribute__((ext_vector_type(4)));
typedef short s16x8 __attribute__((ext_vector_type(8)));

__device__ __forceinline__ short f2bf(float f) {
    unsigned u = __float_as_uint(f);
    u = (u + 0x7fffu + ((u >> 16) & 1u)) >> 16;   // RNE
    return (short)u;
}

// ---------------- embedding ----------------
__global__ void k_embed(const int* __restrict__ ids, const float* __restrict__ emb,
                        float* __restrict__ x)
{
    const int t = blockIdx.x;
    const float* src = emb + (size_t)ids[t] * H_;
    float* dst = x + (size_t)t * H_;
    for (int i = threadIdx.x; i < H_; i += 256) dst[i] = src[i];
}

// ---------------- layernorm ----------------
__global__ __launch_bounds__(256)
void k_layernorm(const float* __restrict__ x, const float* __restrict__ g,
                 const float* __restrict__ bb, float* __restrict__ out)
{
    const int t = blockIdx.x;
    const float* row = x + (size_t)t * H_;
    float s = 0.f, ss = 0.f;
    for (int i = threadIdx.x; i < H_; i += 256) { const float v = row[i]; s += v; ss += v * v; }
    #pragma unroll
    for (int off = 32; off > 0; off >>= 1) {
        s  += __shfl_down(s, off, 64);
        ss += __shfl_down(ss, off, 64);
    }
    __shared__ float shs[4], shss[4];
    const int w = threadIdx.x >> 6;
    if ((threadIdx.x & 63) == 0) { shs[w] = s; shss[w] = ss; }
    __syncthreads();
    const float fs  = shs[0] + shs[1] + shs[2] + shs[3];
    const float fss = shss[0] + shss[1] + shss[2] + shss[3];
    const float mean = fs * (1.f / H_);
    const float var  = fss * (1.f / H_) - mean * mean;
    const float rstd = 1.0f / sqrtf(var + 1e-5f);
    float* orow = out + (size_t)t * H_;
    for (int i = threadIdx.x; i < H_; i += 256)
        orow[i] = (row[i] - mean) * rstd * g[i] + bb[i];
}

// ---------------- RoPE (generic stride) ----------------
__global__ void k_rope(float* __restrict__ x, int rowStride, int nheads)
{
    const int idx  = blockIdx.x * 256 + threadIdx.x;
    const int i    = idx & 31;
    const int rest = idx >> 5;
    const int head = rest % nheads;
    const int t    = rest / nheads;
    const int pos  = t & (S_ - 1);
    const float p32  = (float)pow(1.0e6, (double)i / 32.0);
    const float invf = 1.0f / p32;
    const float ang  = (float)pos * invf;
    const float c = (float)cos((double)ang);
    const float s = (float)sin((double)ang);
    float* base = x + (size_t)t * rowStride + head * HD_;
    const float x1 = base[i];
    const float x2 = base[i + 32];
    base[i]      = x1 * c - x2 * s;
    base[i + 32] = x2 * c + x1 * s;
}

// ---------------- causal GQA attention, 4-wave split-K ----------------
__global__ __launch_bounds__(256)
void k_attn4(const float* __restrict__ q, const float* __restrict__ kv,
             float* __restrict__ o)
{
    const int q0 = blockIdx.x * 64, h = blockIdx.y, b = blockIdx.z;
    const int kvh = h >> 2;
    const int tid = threadIdx.x, lane = tid & 63, w = tid >> 6;
    const int row = q0 + lane;
    __shared__ float tiles[4][2][32][68];
    __shared__ float lsums[4][64];
    float (*Kw)[68] = tiles[w][0];
    float (*Vw)[68] = tiles[w][1];

    float qr[64], oacc[64];
    {
        const float* qs = q + (size_t)(b * S_ + row) * H_ + h * HD_;
        #pragma unroll
        for (int d4 = 0; d4 < 16; d4++) {
            float4 t = *reinterpret_cast<const float4*>(qs + 4 * d4);
            qr[4*d4+0] = t.x * 0.125f; qr[4*d4+1] = t.y * 0.125f;
            qr[4*d4+2] = t.z * 0.125f; qr[4*d4+3] = t.w * 0.125f;
        }
    }
    #pragma unroll
    for (int d = 0; d < 64; d++) oacc[d] = 0.f;
    float lsum = 0.f;

    const int nkb = (q0 >> 5) + 2;
    const int r = lane >> 1, half = (lane & 1) * 32;
    for (int kb = w; kb < nkb; kb += 4) {
        const int j0 = kb * 32;
        {
            const float* srck = kv + (size_t)(b * S_ + j0 + r) * 512 + kvh * 64 + half;
            const float* srcv = srck + 256;
            #pragma unroll
            for (int d4 = 0; d4 < 8; d4++) {
                *reinterpret_cast<float4*>(&Kw[r][half + 4*d4]) = *reinterpret_cast<const float4*>(srck + 4*d4);
                *reinterpret_cast<float4*>(&Vw[r][half + 4*d4]) = *reinterpret_cast<const float4*>(srcv + 4*d4);
            }
        }
        __builtin_amdgcn_wave_barrier();
        const int jend = min(32, row - j0 + 1);
        for (int j = 0; j < jend; j++) {
            float s = 0.f;
            #pragma unroll
            for (int d4 = 0; d4 < 16; d4++) {
                const float4 kvv = *reinterpret_cast<const float4*>(&Kw[j][4*d4]);
                s += qr[4*d4+0]*kvv.x + qr[4*d4+1]*kvv.y + qr[4*d4+2]*kvv.z + qr[4*d4+3]*kvv.w;
            }
            const float e = expf(s);
            lsum += e;
            #pragma unroll
            for (int d4 = 0; d4 < 16; d4++) {
                const float4 vw = *reinterpret_cast<const float4*>(&Vw[j][4*d4]);
                oacc[4*d4+0] += e * vw.x; oacc[4*d4+1] += e * vw.y;
                oacc[4*d4+2] += e * vw.z; oacc[4*d4+3] += e * vw.w;
            }
        }
        __builtin_amdgcn_wave_barrier();
    }

    // cross-wave combine
    lsums[w][lane] = lsum;
    float (*cb)[68] = reinterpret_cast<float(*)[68]>(&tiles[0][0][0][0]);
    if (w == 0) {
        #pragma unroll
        for (int d4 = 0; d4 < 16; d4++)
            *reinterpret_cast<float4*>(&cb[lane][4*d4]) =
                make_float4(oacc[4*d4+0], oacc[4*d4+1], oacc[4*d4+2], oacc[4*d4+3]);
    }
    __syncthreads();
    if (w == 1) {
        #pragma unroll
        for (int d = 0; d < 64; d++) cb[lane][d] += oacc[d];
    }
    __syncthreads();
    if (w == 2) {
        #pragma unroll
        for (int d = 0; d < 64; d++) cb[lane][d] += oacc[d];
    }
    __syncthreads();
    if (w == 3) {
        #pragma unroll
        for (int d = 0; d < 64; d++) cb[lane][d] += oacc[d];
    }
    __syncthreads();
    if (w == 0) {
        const float inv = 1.0f / (lsums[0][lane] + lsums[1][lane] + lsums[2][lane] + lsums[3][lane]);
        float* od = o + (size_t)(b * S_ + row) * H_ + h * HD_;
        #pragma unroll
        for (int d4 = 0; d4 < 16; d4++) {
            float4 t;
            t.x = cb[lane][4*d4+0] * inv; t.y = cb[lane][4*d4+1] * inv;
            t.z = cb[lane][4*d4+2] * inv; t.w = cb[lane][4*d4+3] * inv;
            *reinterpret_cast<float4*>(od + 4*d4) = t;
        }
    }
}

// ---------------- MoE gate ----------------
__global__ __launch_bounds__(64)
void k_gate(const float* __restrict__ h, const float* __restrict__ gwt, float* __restrict__ w)
{
    const int t = blockIdx.x;
    const int lane = threadIdx.x;
    const float* row = h + (size_t)t * H_;
    float acc[E_];
    #pragma unroll
    for (int e = 0; e < E_; e++) acc[e] = 0.f;
    for (int i = lane; i < H_; i += 64) {
        const float xv = row[i];
        #pragma unroll
        for (int e = 0; e < E_; e++) acc[e] += xv * gwt[(size_t)e * H_ + i];
    }
    #pragma unroll
    for (int e = 0; e < E_; e++) {
        #pragma unroll
        for (int off = 32; off > 0; off >>= 1) acc[e] += __shfl_down(acc[e], off, 64);
    }
    if (lane == 0) {
        int i1 = 0; float m1 = acc[0];
        #pragma unroll
        for (int e = 1; e < E_; e++) if (acc[e] > m1) { m1 = acc[e]; i1 = e; }
        int i2 = -1; float m2 = -1e30f;
        #pragma unroll
        for (int e = 0; e < E_; e++) if (e != i1 && acc[e] > m2) { m2 = acc[e]; i2 = e; }
        const float e2  = expf(m2 - m1);
        const float den = 1.0f + e2;
        #pragma unroll
        for (int e = 0; e < E_; e++)
            w[t * E_ + e] = (e == i1) ? (1.0f / den) : ((e == i2) ? (e2 / den) : 0.f);
    }
}

// ---------------- build per-expert token lists + per-token positions ----------------
__global__ __launch_bounds__(512)
void k_build(const float* __restrict__ gw, int* __restrict__ idx, float* __restrict__ wl,
             int* __restrict__ pos, int* __restrict__ cnt, int* __restrict__ seg)
{
    const int e = threadIdx.x >> 6;
    const int lane = threadIdx.x & 63;
    __shared__ int scnt[E_], sseg[E_];
    int c = 0;
    for (int t0 = 0; t0 < T_; t0 += 64) {
        const float v = gw[(size_t)(t0 + lane) * E_ + e];
        c += __popcll(__ballot(v > 0.f));
    }
    if (lane == 0) scnt[e] = c;
    __syncthreads();
    if (threadIdx.x == 0) {
        int off = 0;
        for (int q = 0; q < E_; q++) {
            sseg[q] = off; cnt[q] = scnt[q]; seg[q] = off;
            off += (scnt[q] + 127) & ~127;
        }
    }
    __syncthreads();
    int p = sseg[e];
    for (int t0 = 0; t0 < T_; t0 += 64) {
        const int t = t0 + lane;
        const float v = gw[(size_t)t * E_ + e];
        const unsigned long long m = __ballot(v > 0.f);
        if (v > 0.f) {
            const int pp = p + __popcll(m & ((1ull << lane) - 1ull));
            idx[pp] = t; wl[pp] = v;
            int slot = 0;
            for (int q = 0; q < e; q++) slot += (gw[(size_t)t * E_ + q] > 0.f) ? 1 : 0;
            pos[t * 2 + slot] = pp;
        }
        p += __popcll(m);
    }
}

// ---------------- combine: x[t] += w0*ebuf[p0] + w1*ebuf[p1] ----------------
__global__ void k_combine(float* __restrict__ x, const float* __restrict__ ebuf,
                          const float* __restrict__ wl, const int* __restrict__ pos)
{
    const int id = blockIdx.x * 256 + threadIdx.x;
    const int t = id >> 10;
    const int hc = id & 1023;
    const int p0 = pos[t * 2], p1 = pos[t * 2 + 1];
    x[id] += wl[p0] * ebuf[(size_t)p0 * H_ + hc] + wl[p1] * ebuf[(size_t)p1 * H_ + hc];
}

// ---------------- f32 SIMT GEMM ----------------
template<int BL, int EPI>
__global__ __launch_bounds__(256, 2)
void k_gemm(const float* __restrict__ A, const float* __restrict__ B,
            float* __restrict__ C, int M, int N, int K)
{
    __shared__ float As[128][20];
    __shared__ float Bs[16][132];
    const int tid = threadIdx.x;
    const int bm0 = blockIdx.y * 128, bn0 = blockIdx.x * 128;
    const int tx = tid & 15, ty = tid >> 4;
    float acc[8][8];
    #pragma unroll
    for (int i = 0; i < 8; i++)
        #pragma unroll
        for (int j = 0; j < 8; j++) acc[i][j] = 0.f;
    const int ra = tid >> 1, ca = (tid & 1) * 8;
    for (int k0 = 0; k0 < K; k0 += 16) {
        __syncthreads();
        {
            const float* src = A + (size_t)(bm0 + ra) * K + (k0 + ca);
            *reinterpret_cast<float4*>(&As[ra][ca])     = *reinterpret_cast<const float4*>(src);
            *reinterpret_cast<float4*>(&As[ra][ca + 4]) = *reinterpret_cast<const float4*>(src + 4);
        }
        if (BL == 0) {
            const int kb = tid >> 4, n8 = (tid & 15) * 8;
            const float* src = B + (size_t)(k0 + kb) * N + (bn0 + n8);
            *reinterpret_cast<float4*>(&Bs[kb][n8])     = *reinterpret_cast<const float4*>(src);
            *reinterpret_cast<float4*>(&Bs[kb][n8 + 4]) = *reinterpret_cast<const float4*>(src + 4);
        } else {
            const float* src = B + (size_t)(bn0 + ra) * K + (k0 + ca);
            float4 r0 = *reinterpret_cast<const float4*>(src);
            float4 r1 = *reinterpret_cast<const float4*>(src + 4);
            Bs[ca + 0][ra] = r0.x; Bs[ca + 1][ra] = r0.y;
            Bs[ca + 2][ra] = r0.z; Bs[ca + 3][ra] = r0.w;
            Bs[ca + 4][ra] = r1.x; Bs[ca + 5][ra] = r1.y;
            Bs[ca + 6][ra] = r1.z; Bs[ca + 7][ra] = r1.w;
        }
        __syncthreads();
        #pragma unroll
        for (int kkx = 0; kkx < 16; kkx++) {
            float a[8], b[8];
            #pragma unroll
            for (int i = 0; i < 4; i++) {
                a[i]     = As[ty * 4 + i][kkx];
                a[4 + i] = As[64 + ty * 4 + i][kkx];
            }
            const float4 b0 = *reinterpret_cast<const float4*>(&Bs[kkx][tx * 4]);
            const float4 b1 = *reinterpret_cast<const float4*>(&Bs[kkx][64 + tx * 4]);
            b[0] = b0.x; b[1] = b0.y; b[2] = b0.z; b[3] = b0.w;
            b[4] = b1.x; b[5] = b1.y; b[6] = b1.z; b[7] = b1.w;
            #pragma unroll
            for (int i = 0; i < 8; i++)
                #pragma unroll
                for (int j = 0; j < 8; j++) acc[i][j] += a[i] * b[j];
        }
    }
    #pragma unroll
    for (int i = 0; i < 8; i++) {
        const int row = bm0 + (i & 3) + ((i >> 2) * 64) + ty * 4;
        #pragma unroll
        for (int j = 0; j < 8; j++) {
            const int col = bn0 + (j & 3) + ((j >> 2) * 64) + tx * 4;
            const size_t p = (size_t)row * N + col;
            if (EPI == 0)      C[p] = acc[i][j];
            else if (EPI == 2) C[p] += acc[i][j];
            else if (EPI == 4) {
                const float gv = C[p];
                C[p] = gv * (1.f / (1.f + expf(-gv))) * acc[i][j];
            }
        }
    }
}

// ---------------- fused q/k/v GEMM ----------------
__global__ __launch_bounds__(256, 2)
void k_gemm_qkv(const float* __restrict__ A, const float* __restrict__ Bq,
                const float* __restrict__ Bk, const float* __restrict__ Bv,
                float* __restrict__ Cq, float* __restrict__ Ckv)
{
    const int bn0 = blockIdx.x * 128, bm0 = blockIdx.y * 128;
    const float* B; float* C; int ldb, ldc, bcol, ccol;
    if (bn0 < 1024)      { B = Bq; ldb = 1024; bcol = bn0;        C = Cq;  ldc = 1024; ccol = bn0; }
    else if (bn0 < 1280) { B = Bk; ldb = 256;  bcol = bn0 - 1024; C = Ckv; ldc = 512;  ccol = bn0 - 1024; }
    else                 { B = Bv; ldb = 256;  bcol = bn0 - 1280; C = Ckv; ldc = 512;  ccol = bn0 - 1024; }

    __shared__ float As[128][20];
    __shared__ float Bs[16][132];
    const int tid = threadIdx.x;
    const int tx = tid & 15, ty = tid >> 4;
    float acc[8][8];
    #pragma unroll
    for (int i = 0; i < 8; i++)
        #pragma unroll
        for (int j = 0; j < 8; j++) acc[i][j] = 0.f;
    const int ra = tid >> 1, ca = (tid & 1) * 8;
    for (int k0 = 0; k0 < H_; k0 += 16) {
        __syncthreads();
        {
            const float* src = A + (size_t)(bm0 + ra) * H_ + (k0 + ca);
            *reinterpret_cast<float4*>(&As[ra][ca])     = *reinterpret_cast<const float4*>(src);
            *reinterpret_cast<float4*>(&As[ra][ca + 4]) = *reinterpret_cast<const float4*>(src + 4);
        }
        {
            const int kb = tid >> 4, n8 = (tid & 15) * 8;
            const float* src = B + (size_t)(k0 + kb) * ldb + (bcol + n8);
            *reinterpret_cast<float4*>(&Bs[kb][n8])     = *reinterpret_cast<const float4*>(src);
            *reinterpret_cast<float4*>(&Bs[kb][n8 + 4]) = *reinterpret_cast<const float4*>(src + 4);
        }
        __syncthreads();
        #pragma unroll
        for (int kkx = 0; kkx < 16; kkx++) {
            float a[8], b[8];
            #pragma unroll
            for (int i = 0; i < 4; i++) {
                a[i]     = As[ty * 4 + i][kkx];
                a[4 + i] = As[64 + ty * 4 + i][kkx];
            }
            const float4 b0 = *reinterpret_cast<const float4*>(&Bs[kkx][tx * 4]);
            const float4 b1 = *reinterpret_cast<const float4*>(&Bs[kkx][64 + tx * 4]);
            b[0] = b0.x; b[1] = b0.y; b[2] = b0.z; b[3] = b0.w;
            b[4] = b1.x; b[5] = b1.y; b[6] = b1.z; b[7] = b1.w;
            #pragma unroll
            for (int i = 0; i < 8; i++)
                #pragma unroll
                for (int j = 0; j < 8; j++) acc[i][j] += a[i] * b[j];
        }
    }
    #pragma unroll
    for (int i = 0; i < 8; i++) {
        const int row = bm0 + (i & 3) + ((i >> 2) * 64) + ty * 4;
        #pragma unroll
        for (int j = 0; j < 8; j++) {
            const int col = ccol + (j & 3) + ((j >> 2) * 64) + tx * 4;
            C[(size_t)row * ldc + col] = acc[i][j];
        }
    }
}

// ---------------- f32 sparse MoE GEMM ----------------
template<int OP>
__global__ __launch_bounds__(256, 2)
void k_gemm_moe(const float* __restrict__ A, const float* __restrict__ Wb,
                float* __restrict__ Cb,
                const int* __restrict__ idx, const int* __restrict__ cnt,
                const int* __restrict__ seg, int N, int K)
{
    const int e = blockIdx.z;
    const int c = cnt[e];
    const int bm0 = blockIdx.y * 128;
    if (bm0 >= c) return;
    const int s = seg[e];
    const float* B = Wb + (size_t)e * N * K;
    const int bn0 = blockIdx.x * 128;

    __shared__ float As[128][20];
    __shared__ float Bs[16][132];
    const int tid = threadIdx.x;
    const int tx = tid & 15, ty = tid >> 4;
    float acc[8][8];
    #pragma unroll
    for (int i = 0; i < 8; i++)
        #pragma unroll
        for (int j = 0; j < 8; j++) acc[i][j] = 0.f;

    const int ra = tid >> 1, ca = (tid & 1) * 8;
    const int lr = min(bm0 + ra, c - 1);
    const size_t arow = (OP < 2) ? (size_t)idx[s + lr] : (size_t)(s + lr);
    const float* asrc = A + arow * K;

    for (int k0 = 0; k0 < K; k0 += 16) {
        __syncthreads();
        {
            const float* src = asrc + k0 + ca;
            *reinterpret_cast<float4*>(&As[ra][ca])     = *reinterpret_cast<const float4*>(src);
            *reinterpret_cast<float4*>(&As[ra][ca + 4]) = *reinterpret_cast<const float4*>(src + 4);
        }
        {
            const float* src = B + (size_t)(bn0 + ra) * K + (k0 + ca);
            float4 r0 = *reinterpret_cast<const float4*>(src);
            float4 r1 = *reinterpret_cast<const float4*>(src + 4);
            Bs[ca + 0][ra] = r0.x; Bs[ca + 1][ra] = r0.y;
            Bs[ca + 2][ra] = r0.z; Bs[ca + 3][ra] = r0.w;
            Bs[ca + 4][ra] = r1.x; Bs[ca + 5][ra] = r1.y;
            Bs[ca + 6][ra] = r1.z; Bs[ca + 7][ra] = r1.w;
        }
        __syncthreads();
        #pragma unroll
        for (int kkx = 0; kkx < 16; kkx++) {
            float a[8], b[8];
            #pragma unroll
            for (int i = 0; i < 4; i++) {
                a[i]     = As[ty * 4 + i][kkx];
                a[4 + i] = As[64 + ty * 4 + i][kkx];
            }
            const float4 b0 = *reinterpret_cast<const float4*>(&Bs[kkx][tx * 4]);
            const float4 b1 = *reinterpret_cast<const float4*>(&Bs[kkx][64 + tx * 4]);
            b[0] = b0.x; b[1] = b0.y; b[2] = b0.z; b[3] = b0.w;
            b[4] = b1.x; b[5] = b1.y; b[6] = b1.z; b[7] = b1.w;
            #pragma unroll
            for (int i = 0; i < 8; i++)
                #pragma unroll
                for (int j = 0; j < 8; j++) acc[i][j] += a[i] * b[j];
        }
    }
    #pragma unroll
    for (int i = 0; i < 8; i++) {
        const int row = bm0 + (i & 3) + ((i >> 2) * 64) + ty * 4;
        if (row >= c) continue;
        #pragma unroll
        for (int j = 0; j < 8; j++) {
            const int col = bn0 + (j & 3) + ((j >> 2) * 64) + tx * 4;
            const size_t p = (size_t)(s + row) * N + col;
            if (OP == 1) {
                const float gv = Cb[p];
                Cb[p] = gv * (1.f / (1.f + expf(-gv))) * acc[i][j];
            } else {
                Cb[p] = acc[i][j];
            }
        }
    }
}

// ---------------- bf16 MFMA GEMM (lm_head) ----------------
__global__ __launch_bounds__(256)
void k_gemm_mfma_bt(const float* __restrict__ A, const float* __restrict__ Bm,
                    float* __restrict__ C, int M, int N, int K)
{
    __shared__ short Al[128 * 32];
    __shared__ short Bl[128 * 32];
    const int mB = M >> 7;
    const int l  = blockIdx.x;
    const int g  = l / (mB * 8);
    const int ii = l - g * (mB * 8);
    const int bm0 = (ii % mB) * 128;
    const int bn0 = (g * 8 + ii / mB) * 128;

    const int tid  = threadIdx.x;
    const int lane = tid & 63, w = tid >> 6;
    const int wr = w >> 1, wc = w & 1;
    const int fr = lane & 15, fg = lane >> 4;

    const int srow = tid >> 1, sk = (tid & 1) * 16;
    const float* pa = A  + (size_t)(bm0 + srow) * K + sk;
    const float* pb = Bm + (size_t)(bn0 + srow) * K + sk;

    f32x4 acc[4][4];
    #pragma unroll
    for (int m = 0; m < 4; m++)
        #pragma unroll
        for (int n = 0; n < 4; n++) acc[m][n] = (f32x4){0.f, 0.f, 0.f, 0.f};

    float4 ra[4], rb[4];
    #pragma unroll
    for (int q = 0; q < 4; q++) {
        ra[q] = *reinterpret_cast<const float4*>(pa + 4 * q);
        rb[q] = *reinterpret_cast<const float4*>(pb + 4 * q);
    }

    for (int k0 = 0; k0 < K; k0 += 32) {
        s16x8 apk0, apk1, bpk0, bpk1;
        apk0[0]=f2bf(ra[0].x); apk0[1]=f2bf(ra[0].y); apk0[2]=f2bf(ra[0].z); apk0[3]=f2bf(ra[0].w);
        apk0[4]=f2bf(ra[1].x); apk0[5]=f2bf(ra[1].y); apk0[6]=f2bf(ra[1].z); apk0[7]=f2bf(ra[1].w);
        apk1[0]=f2bf(ra[2].x); apk1[1]=f2bf(ra[2].y); apk1[2]=f2bf(ra[2].z); apk1[3]=f2bf(ra[2].w);
        apk1[4]=f2bf(ra[3].x); apk1[5]=f2bf(ra[3].y); apk1[6]=f2bf(ra[3].z); apk1[7]=f2bf(ra[3].w);
        bpk0[0]=f2bf(rb[0].x); bpk0[1]=f2bf(rb[0].y); bpk0[2]=f2bf(rb[0].z); bpk0[3]=f2bf(rb[0].w);
        bpk0[4]=f2bf(rb[1].x); bpk0[5]=f2bf(rb[1].y); bpk0[6]=f2bf(rb[1].z); bpk0[7]=f2bf(rb[1].w);
        bpk1[0]=f2bf(rb[2].x); bpk1[1]=f2bf(rb[2].y); bpk1[2]=f2bf(rb[2].z); bpk1[3]=f2bf(rb[2].w);
        bpk1[4]=f2bf(rb[3].x); bpk1[5]=f2bf(rb[3].y); bpk1[6]=f2bf(rb[3].z); bpk1[7]=f2bf(rb[3].w);

        __syncthreads();
        *reinterpret_cast<s16x8*>(&Al[srow * 32 + sk])     = apk0;
        *reinterpret_cast<s16x8*>(&Al[srow * 32 + sk + 8]) = apk1;
        *reinterpret_cast<s16x8*>(&Bl[srow * 32 + sk])     = bpk0;
        *reinterpret_cast<s16x8*>(&Bl[srow * 32 + sk + 8]) = bpk1;
        __syncthreads();

        if (k0 + 32 < K) {
            #pragma unroll
            for (int q = 0; q < 4; q++) {
                ra[q] = *reinterpret_cast<const float4*>(pa + k0 + 32 + 4 * q);
                rb[q] = *reinterpret_cast<const float4*>(pb + k0 + 32 + 4 * q);
            }
        }

        s16x8 af[4], bfv[4];
        #pragma unroll
        for (int m = 0; m < 4; m++) {
            const int base = (wr * 64 + m * 16 + fr) * 32 + fg * 4;
            s16x4 lo = *reinterpret_cast<const s16x4*>(&Al[base]);
            s16x4 hi = *reinterpret_cast<const s16x4*>(&Al[base + 16]);
            af[m] = __builtin_shufflevector(lo, hi, 0, 1, 2, 3, 4, 5, 6, 7);
        }
        #pragma unroll
        for (int n = 0; n < 4; n++) {
            const int base = (wc * 64 + n * 16 + fr) * 32 + fg * 4;
            s16x4 lo = *reinterpret_cast<const s16x4*>(&Bl[base]);
            s16x4 hi = *reinterpret_cast<const s16x4*>(&Bl[base + 16]);
            bfv[n] = __builtin_shufflevector(lo, hi, 0, 1, 2, 3, 4, 5, 6, 7);
        }
        #pragma unroll
        for (int m = 0; m < 4; m++)
            #pragma unroll
            for (int n = 0; n < 4; n++)
                acc[m][n] = __builtin_amdgcn_mfma_f32_16x16x32_bf16(af[m], bfv[n], acc[m][n], 0, 0, 0);
    }

    #pragma unroll
    for (int m = 0; m < 4; m++)
        #pragma unroll
        for (int n = 0; n < 4; n++)
            #pragma unroll
            for (int r = 0; r < 4; r++) {
                const int row = bm0 + wr * 64 + m * 16 + fg * 4 + r;
                const int col = bn0 + wc * 64 + n * 16 + fr;
                C[(size_t)row * N + col] = acc[m][n][r];
            }
}

// ---------------- bf16 MFMA MoE/shared GEMM ----------------
template<int MODE, int EPI>
__global__ __launch_bounds__(256)
void k_mfma_moe(const float* __restrict__ A, const float* __restrict__ Wb,
                float* __restrict__ Cb,
                const int* __restrict__ idx, const int* __restrict__ cnt,
                const int* __restrict__ seg, int N, int K)
{
    int c = T_, s = 0;
    const float* B = Wb;
    const int bm0 = blockIdx.y * 128, bn0 = blockIdx.x * 128;
    if (MODE >= 1) {
        const int e = blockIdx.z;
        c = cnt[e];
        if (bm0 >= c) return;
        s = seg[e];
        B = Wb + (size_t)e * N * K;
    }
    __shared__ short Al[128 * 32];
    __shared__ short Bl[128 * 32];
    const int tid  = threadIdx.x;
    const int lane = tid & 63, w = tid >> 6;
    const int wr = w >> 1, wc = w & 1;
    const int fr = lane & 15, fg = lane >> 4;
    const int srow = tid >> 1, sk = (tid & 1) * 16;

    int arow;
    if (MODE == 0)      arow = bm0 + srow;
    else if (MODE == 1) arow = idx[s + min(bm0 + srow, c - 1)];
    else                arow = s + min(bm0 + srow, c - 1);
    const float* pa = A + (size_t)arow * K + sk;
    const float* pb = B + (size_t)(bn0 + srow) * K + sk;

    f32x4 acc[4][4];
    #pragma unroll
    for (int m = 0; m < 4; m++)
        #pragma unroll
        for (int n = 0; n < 4; n++) acc[m][n] = (f32x4){0.f, 0.f, 0.f, 0.f};

    float4 ra[4], rb[4];
    #pragma unroll
    for (int q = 0; q < 4; q++) {
        ra[q] = *reinterpret_cast<const float4*>(pa + 4 * q);
        rb[q] = *reinterpret_cast<const float4*>(pb + 4 * q);
    }

    for (int k0 = 0; k0 < K; k0 += 32) {
        s16x8 apk0, apk1, bpk0, bpk1;
        apk0[0]=f2bf(ra[0].x); apk0[1]=f2bf(ra[0].y); apk0[2]=f2bf(ra[0].z); apk0[3]=f2bf(ra[0].w);
        apk0[4]=f2bf(ra[1].x); apk0[5]=f2bf(ra[1].y); apk0[6]=f2bf(ra[1].z); apk0[7]=f2bf(ra[1].w);
        apk1[0]=f2bf(ra[2].x); apk1[1]=f2bf(ra[2].y); apk1[2]=f2bf(ra[2].z); apk1[3]=f2bf(ra[2].w);
        apk1[4]=f2bf(ra[3].x); apk1[5]=f2bf(ra[3].y); apk1[6]=f2bf(ra[3].z); apk1[7]=f2bf(ra[3].w);
        bpk0[0]=f2bf(rb[0].x); bpk0[1]=f2bf(rb[0].y); bpk0[2]=f2bf(rb[0].z); bpk0[3]=f2bf(rb[0].w);
        bpk0[4]=f2bf(rb[1].x); bpk0[5]=f2bf(rb[1].y); bpk0[6]=f2bf(rb[1].z); bpk0[7]=f2bf(rb[1].w);
        bpk1[0]=f2bf(rb[2].x); bpk1[1]=f2bf(rb[2].y); bpk1[2]=f2bf(rb[2].z); bpk1[3]=f2bf(rb[2].w);
        bpk1[4]=f2bf(rb[3].x); bpk1[5]=f2bf(rb[3].y); bpk1[6]=f2bf(rb[3].z); bpk1[7]=f2bf(rb[3].w);

        __syncthreads();
        *reinterpret_cast<s16x8*>(&Al[srow * 32 + sk])     = apk0;
        *reinterpret_cast<s16x8*>(&Al[srow * 32 + sk + 8]) = apk1;
        *reinterpret_cast<s16x8*>(&Bl[srow * 32 + sk])     = bpk0;
        *reinterpret_cast<s16x8*>(&Bl[srow * 32 + sk + 8]) = bpk1;
        __syncthreads();

        if (k0 + 32 < K) {
            #pragma unroll
            for (int q = 0; q < 4; q++) {
                ra[q] = *reinterpret_cast<const float4*>(pa + k0 + 32 + 4 * q);
                rb[q] = *reinterpret_cast<const float4*>(pb + k0 + 32 + 4 * q);
            }
        }

        s16x8 af[4], bfv[4];
        #pragma unroll
        for (int m = 0; m < 4; m++) {
            const int base = (wr * 64 + m * 16 + fr) * 32 + fg * 4;
            s16x4 lo = *reinterpret_cast<const s16x4*>(&Al[base]);
            s16x4 hi = *reinterpret_cast<const s16x4*>(&Al[base + 16]);
            af[m] = __builtin_shufflevector(lo, hi, 0, 1, 2, 3, 4, 5, 6, 7);
        }
        #pragma unroll
        for (int n = 0; n < 4; n++) {
            const int base = (wc * 64 + n * 16 + fr) * 32 + fg * 4;
            s16x4 lo = *reinterpret_cast<const s16x4*>(&Bl[base]);
            s16x4 hi = *reinterpret_cast<const s16x4*>(&Bl[base + 16]);
            bfv[n] = __builtin_shufflevector(lo, hi, 0, 1, 2, 3, 4, 5, 6, 7);
        }
        #pragma unroll
        for (int m = 0; m < 4; m++)
            #pragma unroll
            for (int n = 0; n < 4; n++)
                acc[m][n] = __builtin_amdgcn_mfma_f32_16x16x32_bf16(af[m], bfv[n], acc[m][n], 0, 0, 0);
    }

    #pragma unroll
    for (int m = 0; m < 4; m++)
        #pragma unroll
        for (int n = 0; n < 4; n++)
            #pragma unroll
            for (int r = 0; r < 4; r++) {
                const int row = bm0 + wr * 64 + m * 16 + fg * 4 + r;
                if (MODE >= 1 && row >= c) continue;
                const int col = bn0 + wc * 64 + n * 16 + fr;
                const size_t p = (size_t)((MODE >= 1 ? s : 0) + row) * N + col;
                if (EPI == 0)      Cb[p] = acc[m][n][r];
                else if (EPI == 1) {
                    const float gv = Cb[p];
                    Cb[p] = gv * (1.f / (1.f + expf(-gv))) * acc[m][n][r];
                } else               Cb[p] += acc[m][n][r];
            }
}

#define GEMM(BL, EPI, A, Bw, CC, M, N, K) \
    k_gemm<BL, EPI><<<dim3((N)/128, (M)/128), 256, 0, stream>>>(A, Bw, CC, M, N, K)

extern "C" void kernel_launch(void* const* d_in, const int* in_sizes, int n_in,
                              void* d_out, int out_size, void* d_ws, size_t ws_size,
                              hipStream_t stream)
{
    const int*   ids    = (const int*)  d_in[0];
    const float* embed  = (const float*)d_in[1];
    const float* ln1_g  = (const float*)d_in[2];
    const float* ln1_b  = (const float*)d_in[3];
    const float* wq     = (const float*)d_in[4];
    const float* wk     = (const float*)d_in[5];
    const float* wv     = (const float*)d_in[6];
    const float* wo     = (const float*)d_in[7];
    const float* ln2_g  = (const float*)d_in[8];
    const float* ln2_b  = (const float*)d_in[9];
    const float* gate_w = (const float*)d_in[10];
    const float* exp_wg = (const float*)d_in[11];
    const float* exp_wu = (const float*)d_in[12];
    const float* exp_wd = (const float*)d_in[13];
    const float* sh_wg  = (const float*)d_in[14];
    const float* sh_wu  = (const float*)d_in[15];
    const float* sh_wd  = (const float*)d_in[16];
    const float* fn_g   = (const float*)d_in[17];
    const float* fn_b   = (const float*)d_in[18];
    const float* lm     = (const float*)d_in[19];
    float* out = (float*)d_out;

    float* x    = (float*)d_ws;                 // T*H
    float* h    = x + 2097152;                  // T*H
    float* qb   = h + 2097152;                  // T*H   (R1, aliased by ebuf)
    float* kv   = qb + 2097152;                 // T*512 [k|v] packed
    float* ob   = kv + 1048576;                 // T*H
    float* ebuf = qb;                           // CAP*H aliases qb..(incl kv,ob)
    float* gbuf = qb + 5242880;                 // CAP*I
    float* gw   = gbuf + 5242880;               // T*8
    float* wl   = gw + (size_t)T_ * E_;         // CAP
    int*   idx  = (int*)(wl + CAP_);            // CAP
    int*   pos  = idx + CAP_;                   // T*2
    int*   cnt  = pos + 2 * T_;                 // 8
    int*   seg  = cnt + E_;                     // 8

    k_embed<<<T_, 256, 0, stream>>>(ids, embed, x);

    for (int l = 0; l < L_; l++) {
        k_layernorm<<<T_, 256, 0, stream>>>(x, ln1_g + (size_t)l * H_, ln1_b + (size_t)l * H_, h);

        k_gemm_qkv<<<dim3(12, 16), 256, 0, stream>>>(
            h, wq + (size_t)l * H_ * H_, wk + (size_t)l * H_ * 256, wv + (size_t)l * H_ * 256, qb, kv);

        k_rope<<<(T_ * NH_  * 32) / 256, 256, 0, stream>>>(qb, 1024, NH_);
        k_rope<<<(T_ * NKV_ * 32) / 256, 256, 0, stream>>>(kv, 512,  NKV_);

        k_attn4<<<dim3(S_ / 64, NH_, B_), 256, 0, stream>>>(qb, kv, ob);

        GEMM(0, 2, ob, wo + (size_t)l * H_ * H_, x, T_, H_, H_);

        k_layernorm<<<T_, 256, 0, stream>>>(x, ln2_g + (size_t)l * H_, ln2_b + (size_t)l * H_, h);
        k_gate<<<T_, 64, 0, stream>>>(h, gate_w + (size_t)l * E_ * H_, gw);
        k_build<<<1, 512, 0, stream>>>(gw, idx, wl, pos, cnt, seg);

        const float* wg_l = exp_wg + (size_t)l * E_ * I_ * H_;
        const float* wu_l = exp_wu + (size_t)l * E_ * I_ * H_;
        const float* wd_l = exp_wd + (size_t)l * E_ * H_ * I_;

        if (l == 0) {   // routing-critical layer: all f32
            GEMM(1, 0, h, sh_wg + (size_t)l * I_ * H_, gbuf, T_, I_, H_);
            GEMM(1, 4, h, sh_wu + (size_t)l * I_ * H_, gbuf, T_, I_, H_);
            GEMM(1, 2, gbuf, sh_wd + (size_t)l * H_ * I_, x, T_, H_, I_);
            k_gemm_moe<0><<<dim3(8, 16, E_), 256, 0, stream>>>(h, wg_l, gbuf, idx, cnt, seg, I_, H_);
            k_gemm_moe<1><<<dim3(8, 16, E_), 256, 0, stream>>>(h, wu_l, gbuf, idx, cnt, seg, I_, H_);
            k_gemm_moe<2><<<dim3(8, 16, E_), 256, 0, stream>>>(gbuf, wd_l, ebuf, idx, cnt, seg, H_, I_);
        } else {        // last layer: value path only -> bf16 MFMA
            k_mfma_moe<0, 0><<<dim3(8, 16, 1), 256, 0, stream>>>(h, sh_wg + (size_t)l * I_ * H_, gbuf, nullptr, nullptr, nullptr, I_, H_);
            k_mfma_moe<0, 1><<<dim3(8, 16, 1), 256, 0, stream>>>(h, sh_wu + (size_t)l * I_ * H_, gbuf, nullptr, nullptr, nullptr, I_, H_);
            k_mfma_moe<0, 2><<<dim3(8, 16, 1), 256, 0, stream>>>(gbuf, sh_wd + (size_t)l * H_ * I_, x, nullptr, nullptr, nullptr, H_, I_);
            k_mfma_moe<1, 0><<<dim3(8, 16, E_), 256, 0, stream>>>(h, wg_l, gbuf, idx, cnt, seg, I_, H_);
            k_mfma_moe<1, 1><<<dim3(8, 16, E_), 256, 0, stream>>>(h, wu_l, gbuf, idx, cnt, seg, I_, H_);
            k_mfma_moe<2, 0><<<dim3(8, 16, E_), 256, 0, stream>>>(gbuf, wd_l, ebuf, idx, cnt, seg, H_, I_);
        }
        k_combine<<<(T_ * H_) / 256, 256, 0, stream>>>(x, ebuf, wl, pos);
    }

    k_layernorm<<<T_, 256, 0, stream>>>(x, fn_g, fn_b, h);
    k_gemm_mfma_bt<<<(T_ / 128) * (V_ / 128), 256, 0, stream>>>(h, lm, out, T_, V_, H_);
}

// Round 8
// 2492.454 us; speedup vs baseline: 4.8037x; 1.4320x over previous
//
#include <hip/hip_runtime.h>
#include <cmath>

#define L_   2
#define E_   8
#define NH_  16
#define NKV_ 4
#define HD_  64
#define H_   1024
#define I_   1024
#define B_   2
#define S_   1024
#define T_   (B_*S_)
#define V_   32000
#define CAP_ 5120
#define LDST 36   // LDS row stride in shorts: bank = (row*18 + col/2)%32, conflict-free

typedef float f32x4 __attribute__((ext_vector_type(4)));
typedef short s16x4 __attribute__((ext_vector_type(4)));
typedef short s16x8 __attribute__((ext_vector_type(8)));

__device__ __forceinline__ short f2bf(float f) {
    unsigned u = __float_as_uint(f);
    u = (u + 0x7fffu + ((u >> 16) & 1u)) >> 16;   // RNE
    return (short)u;
}
__device__ __forceinline__ float bf2f(short h) {
    return __uint_as_float(((unsigned)(unsigned short)h) << 16);
}

// ---------------- embedding ----------------
__global__ void k_embed(const int* __restrict__ ids, const float* __restrict__ emb,
                        float* __restrict__ x)
{
    const int t = blockIdx.x;
    const float* src = emb + (size_t)ids[t] * H_;
    float* dst = x + (size_t)t * H_;
    for (int i = threadIdx.x; i < H_; i += 256) dst[i] = src[i];
}

// ---------------- layernorm ----------------
__global__ __launch_bounds__(256)
void k_layernorm(const float* __restrict__ x, const float* __restrict__ g,
                 const float* __restrict__ bb, float* __restrict__ out)
{
    const int t = blockIdx.x;
    const float* row = x + (size_t)t * H_;
    float s = 0.f, ss = 0.f;
    for (int i = threadIdx.x; i < H_; i += 256) { const float v = row[i]; s += v; ss += v * v; }
    #pragma unroll
    for (int off = 32; off > 0; off >>= 1) {
        s  += __shfl_down(s, off, 64);
        ss += __shfl_down(ss, off, 64);
    }
    __shared__ float shs[4], shss[4];
    const int w = threadIdx.x >> 6;
    if ((threadIdx.x & 63) == 0) { shs[w] = s; shss[w] = ss; }
    __syncthreads();
    const float fs  = shs[0] + shs[1] + shs[2] + shs[3];
    const float fss = shss[0] + shss[1] + shss[2] + shss[3];
    const float mean = fs * (1.f / H_);
    const float var  = fss * (1.f / H_) - mean * mean;
    const float rstd = 1.0f / sqrtf(var + 1e-5f);
    float* orow = out + (size_t)t * H_;
    for (int i = threadIdx.x; i < H_; i += 256)
        orow[i] = (row[i] - mean) * rstd * g[i] + bb[i];
}

// ---------------- RoPE ----------------
__global__ void k_rope(float* __restrict__ x, int rowStride, int nheads)
{
    const int idx  = blockIdx.x * 256 + threadIdx.x;
    const int i    = idx & 31;
    const int rest = idx >> 5;
    const int head = rest % nheads;
    const int t    = rest / nheads;
    const int pos  = t & (S_ - 1);
    const float p32  = (float)pow(1.0e6, (double)i / 32.0);
    const float invf = 1.0f / p32;
    const float ang  = (float)pos * invf;
    const float c = (float)cos((double)ang);
    const float s = (float)sin((double)ang);
    float* base = x + (size_t)t * rowStride + head * HD_;
    const float x1 = base[i];
    const float x2 = base[i + 32];
    base[i]      = x1 * c - x2 * s;
    base[i + 32] = x2 * c + x1 * s;
}

// ---------------- causal GQA attention, 4-wave split-K ----------------
__global__ __launch_bounds__(256)
void k_attn4(const float* __restrict__ q, const float* __restrict__ kv,
             float* __restrict__ o)
{
    const int q0 = blockIdx.x * 64, h = blockIdx.y, b = blockIdx.z;
    const int kvh = h >> 2;
    const int tid = threadIdx.x, lane = tid & 63, w = tid >> 6;
    const int row = q0 + lane;
    __shared__ float tiles[4][2][32][68];
    __shared__ float lsums[4][64];
    float (*Kw)[68] = tiles[w][0];
    float (*Vw)[68] = tiles[w][1];

    float qr[64], oacc[64];
    {
        const float* qs = q + (size_t)(b * S_ + row) * H_ + h * HD_;
        #pragma unroll
        for (int d4 = 0; d4 < 16; d4++) {
            float4 t = *reinterpret_cast<const float4*>(qs + 4 * d4);
            qr[4*d4+0] = t.x * 0.125f; qr[4*d4+1] = t.y * 0.125f;
            qr[4*d4+2] = t.z * 0.125f; qr[4*d4+3] = t.w * 0.125f;
        }
    }
    #pragma unroll
    for (int d = 0; d < 64; d++) oacc[d] = 0.f;
    float lsum = 0.f;

    const int nkb = (q0 >> 5) + 2;
    const int r = lane >> 1, half = (lane & 1) * 32;
    for (int kb = w; kb < nkb; kb += 4) {
        const int j0 = kb * 32;
        {
            const float* srck = kv + (size_t)(b * S_ + j0 + r) * 512 + kvh * 64 + half;
            const float* srcv = srck + 256;
            #pragma unroll
            for (int d4 = 0; d4 < 8; d4++) {
                *reinterpret_cast<float4*>(&Kw[r][half + 4*d4]) = *reinterpret_cast<const float4*>(srck + 4*d4);
                *reinterpret_cast<float4*>(&Vw[r][half + 4*d4]) = *reinterpret_cast<const float4*>(srcv + 4*d4);
            }
        }
        __builtin_amdgcn_wave_barrier();
        const int jend = min(32, row - j0 + 1);
        for (int j = 0; j < jend; j++) {
            float s = 0.f;
            #pragma unroll
            for (int d4 = 0; d4 < 16; d4++) {
                const float4 kvv = *reinterpret_cast<const float4*>(&Kw[j][4*d4]);
                s += qr[4*d4+0]*kvv.x + qr[4*d4+1]*kvv.y + qr[4*d4+2]*kvv.z + qr[4*d4+3]*kvv.w;
            }
            const float e = expf(s);
            lsum += e;
            #pragma unroll
            for (int d4 = 0; d4 < 16; d4++) {
                const float4 vw = *reinterpret_cast<const float4*>(&Vw[j][4*d4]);
                oacc[4*d4+0] += e * vw.x; oacc[4*d4+1] += e * vw.y;
                oacc[4*d4+2] += e * vw.z; oacc[4*d4+3] += e * vw.w;
            }
        }
        __builtin_amdgcn_wave_barrier();
    }

    lsums[w][lane] = lsum;
    float (*cb)[68] = reinterpret_cast<float(*)[68]>(&tiles[0][0][0][0]);
    if (w == 0) {
        #pragma unroll
        for (int d4 = 0; d4 < 16; d4++)
            *reinterpret_cast<float4*>(&cb[lane][4*d4]) =
                make_float4(oacc[4*d4+0], oacc[4*d4+1], oacc[4*d4+2], oacc[4*d4+3]);
    }
    __syncthreads();
    if (w == 1) {
        #pragma unroll
        for (int d = 0; d < 64; d++) cb[lane][d] += oacc[d];
    }
    __syncthreads();
    if (w == 2) {
        #pragma unroll
        for (int d = 0; d < 64; d++) cb[lane][d] += oacc[d];
    }
    __syncthreads();
    if (w == 3) {
        #pragma unroll
        for (int d = 0; d < 64; d++) cb[lane][d] += oacc[d];
    }
    __syncthreads();
    if (w == 0) {
        const float inv = 1.0f / (lsums[0][lane] + lsums[1][lane] + lsums[2][lane] + lsums[3][lane]);
        float* od = o + (size_t)(b * S_ + row) * H_ + h * HD_;
        #pragma unroll
        for (int d4 = 0; d4 < 16; d4++) {
            float4 t;
            t.x = cb[lane][4*d4+0] * inv; t.y = cb[lane][4*d4+1] * inv;
            t.z = cb[lane][4*d4+2] * inv; t.w = cb[lane][4*d4+3] * inv;
            *reinterpret_cast<float4*>(od + 4*d4) = t;
        }
    }
}

// ---------------- MoE gate ----------------
__global__ __launch_bounds__(64)
void k_gate(const float* __restrict__ h, const float* __restrict__ gwt, float* __restrict__ w)
{
    const int t = blockIdx.x;
    const int lane = threadIdx.x;
    const float* row = h + (size_t)t * H_;
    float acc[E_];
    #pragma unroll
    for (int e = 0; e < E_; e++) acc[e] = 0.f;
    for (int i = lane; i < H_; i += 64) {
        const float xv = row[i];
        #pragma unroll
        for (int e = 0; e < E_; e++) acc[e] += xv * gwt[(size_t)e * H_ + i];
    }
    #pragma unroll
    for (int e = 0; e < E_; e++) {
        #pragma unroll
        for (int off = 32; off > 0; off >>= 1) acc[e] += __shfl_down(acc[e], off, 64);
    }
    if (lane == 0) {
        int i1 = 0; float m1 = acc[0];
        #pragma unroll
        for (int e = 1; e < E_; e++) if (acc[e] > m1) { m1 = acc[e]; i1 = e; }
        int i2 = -1; float m2 = -1e30f;
        #pragma unroll
        for (int e = 0; e < E_; e++) if (e != i1 && acc[e] > m2) { m2 = acc[e]; i2 = e; }
        const float e2  = expf(m2 - m1);
        const float den = 1.0f + e2;
        #pragma unroll
        for (int e = 0; e < E_; e++)
            w[t * E_ + e] = (e == i1) ? (1.0f / den) : ((e == i2) ? (e2 / den) : 0.f);
    }
}

// ---------------- build per-expert token lists ----------------
__global__ __launch_bounds__(512)
void k_build(const float* __restrict__ gw, int* __restrict__ idx, float* __restrict__ wl,
             int* __restrict__ pos, int* __restrict__ cnt, int* __restrict__ seg)
{
    const int e = threadIdx.x >> 6;
    const int lane = threadIdx.x & 63;
    __shared__ int scnt[E_], sseg[E_];
    int c = 0;
    for (int t0 = 0; t0 < T_; t0 += 64) {
        const float v = gw[(size_t)(t0 + lane) * E_ + e];
        c += __popcll(__ballot(v > 0.f));
    }
    if (lane == 0) scnt[e] = c;
    __syncthreads();
    if (threadIdx.x == 0) {
        int off = 0;
        for (int q = 0; q < E_; q++) {
            sseg[q] = off; cnt[q] = scnt[q]; seg[q] = off;
            off += (scnt[q] + 127) & ~127;
        }
    }
    __syncthreads();
    int p = sseg[e];
    for (int t0 = 0; t0 < T_; t0 += 64) {
        const int t = t0 + lane;
        const float v = gw[(size_t)t * E_ + e];
        const unsigned long long m = __ballot(v > 0.f);
        if (v > 0.f) {
            const int pp = p + __popcll(m & ((1ull << lane) - 1ull));
            idx[pp] = t; wl[pp] = v;
            int slot = 0;
            for (int q = 0; q < e; q++) slot += (gw[(size_t)t * E_ + q] > 0.f) ? 1 : 0;
            pos[t * 2 + slot] = pp;
        }
        p += __popcll(m);
    }
}

// ---------------- combine ----------------
__global__ void k_combine(float* __restrict__ x, const float* __restrict__ ebuf,
                          const float* __restrict__ wl, const int* __restrict__ pos)
{
    const int id = blockIdx.x * 256 + threadIdx.x;
    const int t = id >> 10;
    const int hc = id & 1023;
    const int p0 = pos[t * 2], p1 = pos[t * 2 + 1];
    x[id] += wl[p0] * ebuf[(size_t)p0 * H_ + hc] + wl[p1] * ebuf[(size_t)p1 * H_ + hc];
}

// ---------------- f32 SIMT GEMM (qkv/wo only now) ----------------
template<int BL, int EPI>
__global__ __launch_bounds__(256, 2)
void k_gemm(const float* __restrict__ A, const float* __restrict__ B,
            float* __restrict__ C, int M, int N, int K)
{
    __shared__ float As[128][20];
    __shared__ float Bs[16][132];
    const int tid = threadIdx.x;
    const int bm0 = blockIdx.y * 128, bn0 = blockIdx.x * 128;
    const int tx = tid & 15, ty = tid >> 4;
    float acc[8][8];
    #pragma unroll
    for (int i = 0; i < 8; i++)
        #pragma unroll
        for (int j = 0; j < 8; j++) acc[i][j] = 0.f;
    const int ra = tid >> 1, ca = (tid & 1) * 8;
    for (int k0 = 0; k0 < K; k0 += 16) {
        __syncthreads();
        {
            const float* src = A + (size_t)(bm0 + ra) * K + (k0 + ca);
            *reinterpret_cast<float4*>(&As[ra][ca])     = *reinterpret_cast<const float4*>(src);
            *reinterpret_cast<float4*>(&As[ra][ca + 4]) = *reinterpret_cast<const float4*>(src + 4);
        }
        if (BL == 0) {
            const int kb = tid >> 4, n8 = (tid & 15) * 8;
            const float* src = B + (size_t)(k0 + kb) * N + (bn0 + n8);
            *reinterpret_cast<float4*>(&Bs[kb][n8])     = *reinterpret_cast<const float4*>(src);
            *reinterpret_cast<float4*>(&Bs[kb][n8 + 4]) = *reinterpret_cast<const float4*>(src + 4);
        } else {
            const float* src = B + (size_t)(bn0 + ra) * K + (k0 + ca);
            float4 r0 = *reinterpret_cast<const float4*>(src);
            float4 r1 = *reinterpret_cast<const float4*>(src + 4);
            Bs[ca + 0][ra] = r0.x; Bs[ca + 1][ra] = r0.y;
            Bs[ca + 2][ra] = r0.z; Bs[ca + 3][ra] = r0.w;
            Bs[ca + 4][ra] = r1.x; Bs[ca + 5][ra] = r1.y;
            Bs[ca + 6][ra] = r1.z; Bs[ca + 7][ra] = r1.w;
        }
        __syncthreads();
        #pragma unroll
        for (int kkx = 0; kkx < 16; kkx++) {
            float a[8], b[8];
            #pragma unroll
            for (int i = 0; i < 4; i++) {
                a[i]     = As[ty * 4 + i][kkx];
                a[4 + i] = As[64 + ty * 4 + i][kkx];
            }
            const float4 b0 = *reinterpret_cast<const float4*>(&Bs[kkx][tx * 4]);
            const float4 b1 = *reinterpret_cast<const float4*>(&Bs[kkx][64 + tx * 4]);
            b[0] = b0.x; b[1] = b0.y; b[2] = b0.z; b[3] = b0.w;
            b[4] = b1.x; b[5] = b1.y; b[6] = b1.z; b[7] = b1.w;
            #pragma unroll
            for (int i = 0; i < 8; i++)
                #pragma unroll
                for (int j = 0; j < 8; j++) acc[i][j] += a[i] * b[j];
        }
    }
    #pragma unroll
    for (int i = 0; i < 8; i++) {
        const int row = bm0 + (i & 3) + ((i >> 2) * 64) + ty * 4;
        #pragma unroll
        for (int j = 0; j < 8; j++) {
            const int col = bn0 + (j & 3) + ((j >> 2) * 64) + tx * 4;
            const size_t p = (size_t)row * N + col;
            if (EPI == 0)      C[p] = acc[i][j];
            else if (EPI == 2) C[p] += acc[i][j];
        }
    }
}

// ---------------- fused q/k/v GEMM ----------------
__global__ __launch_bounds__(256, 2)
void k_gemm_qkv(const float* __restrict__ A, const float* __restrict__ Bq,
                const float* __restrict__ Bk, const float* __restrict__ Bv,
                float* __restrict__ Cq, float* __restrict__ Ckv)
{
    const int bn0 = blockIdx.x * 128, bm0 = blockIdx.y * 128;
    const float* B; float* C; int ldb, ldc, bcol, ccol;
    if (bn0 < 1024)      { B = Bq; ldb = 1024; bcol = bn0;        C = Cq;  ldc = 1024; ccol = bn0; }
    else if (bn0 < 1280) { B = Bk; ldb = 256;  bcol = bn0 - 1024; C = Ckv; ldc = 512;  ccol = bn0 - 1024; }
    else                 { B = Bv; ldb = 256;  bcol = bn0 - 1280; C = Ckv; ldc = 512;  ccol = bn0 - 1024; }

    __shared__ float As[128][20];
    __shared__ float Bs[16][132];
    const int tid = threadIdx.x;
    const int tx = tid & 15, ty = tid >> 4;
    float acc[8][8];
    #pragma unroll
    for (int i = 0; i < 8; i++)
        #pragma unroll
        for (int j = 0; j < 8; j++) acc[i][j] = 0.f;
    const int ra = tid >> 1, ca = (tid & 1) * 8;
    for (int k0 = 0; k0 < H_; k0 += 16) {
        __syncthreads();
        {
            const float* src = A + (size_t)(bm0 + ra) * H_ + (k0 + ca);
            *reinterpret_cast<float4*>(&As[ra][ca])     = *reinterpret_cast<const float4*>(src);
            *reinterpret_cast<float4*>(&As[ra][ca + 4]) = *reinterpret_cast<const float4*>(src + 4);
        }
        {
            const int kb = tid >> 4, n8 = (tid & 15) * 8;
            const float* src = B + (size_t)(k0 + kb) * ldb + (bcol + n8);
            *reinterpret_cast<float4*>(&Bs[kb][n8])     = *reinterpret_cast<const float4*>(src);
            *reinterpret_cast<float4*>(&Bs[kb][n8 + 4]) = *reinterpret_cast<const float4*>(src + 4);
        }
        __syncthreads();
        #pragma unroll
        for (int kkx = 0; kkx < 16; kkx++) {
            float a[8], b[8];
            #pragma unroll
            for (int i = 0; i < 4; i++) {
                a[i]     = As[ty * 4 + i][kkx];
                a[4 + i] = As[64 + ty * 4 + i][kkx];
            }
            const float4 b0 = *reinterpret_cast<const float4*>(&Bs[kkx][tx * 4]);
            const float4 b1 = *reinterpret_cast<const float4*>(&Bs[kkx][64 + tx * 4]);
            b[0] = b0.x; b[1] = b0.y; b[2] = b0.z; b[3] = b0.w;
            b[4] = b1.x; b[5] = b1.y; b[6] = b1.z; b[7] = b1.w;
            #pragma unroll
            for (int i = 0; i < 8; i++)
                #pragma unroll
                for (int j = 0; j < 8; j++) acc[i][j] += a[i] * b[j];
        }
    }
    #pragma unroll
    for (int i = 0; i < 8; i++) {
        const int row = bm0 + (i & 3) + ((i >> 2) * 64) + ty * 4;
        #pragma unroll
        for (int j = 0; j < 8; j++) {
            const int col = ccol + (j & 3) + ((j >> 2) * 64) + tx * 4;
            C[(size_t)row * ldc + col] = acc[i][j];
        }
    }
}

// ---------------- bf16 MFMA GEMM (lm_head), padded LDS ----------------
__global__ __launch_bounds__(256)
void k_gemm_mfma_bt(const float* __restrict__ A, const float* __restrict__ Bm,
                    float* __restrict__ C, int M, int N, int K)
{
    __shared__ short Al[128 * LDST];
    __shared__ short Bl[128 * LDST];
    const int mB = M >> 7;
    const int l  = blockIdx.x;
    const int g  = l / (mB * 8);
    const int ii = l - g * (mB * 8);
    const int bm0 = (ii % mB) * 128;
    const int bn0 = (g * 8 + ii / mB) * 128;

    const int tid  = threadIdx.x;
    const int lane = tid & 63, w = tid >> 6;
    const int wr = w >> 1, wc = w & 1;
    const int fr = lane & 15, fg = lane >> 4;

    const int srow = tid >> 1, sk = (tid & 1) * 16;
    const float* pa = A  + (size_t)(bm0 + srow) * K + sk;
    const float* pb = Bm + (size_t)(bn0 + srow) * K + sk;

    f32x4 acc[4][4];
    #pragma unroll
    for (int m = 0; m < 4; m++)
        #pragma unroll
        for (int n = 0; n < 4; n++) acc[m][n] = (f32x4){0.f, 0.f, 0.f, 0.f};

    float4 ra[4], rb[4];
    #pragma unroll
    for (int q = 0; q < 4; q++) {
        ra[q] = *reinterpret_cast<const float4*>(pa + 4 * q);
        rb[q] = *reinterpret_cast<const float4*>(pb + 4 * q);
    }

    for (int k0 = 0; k0 < K; k0 += 32) {
        s16x8 apk0, apk1, bpk0, bpk1;
        apk0[0]=f2bf(ra[0].x); apk0[1]=f2bf(ra[0].y); apk0[2]=f2bf(ra[0].z); apk0[3]=f2bf(ra[0].w);
        apk0[4]=f2bf(ra[1].x); apk0[5]=f2bf(ra[1].y); apk0[6]=f2bf(ra[1].z); apk0[7]=f2bf(ra[1].w);
        apk1[0]=f2bf(ra[2].x); apk1[1]=f2bf(ra[2].y); apk1[2]=f2bf(ra[2].z); apk1[3]=f2bf(ra[2].w);
        apk1[4]=f2bf(ra[3].x); apk1[5]=f2bf(ra[3].y); apk1[6]=f2bf(ra[3].z); apk1[7]=f2bf(ra[3].w);
        bpk0[0]=f2bf(rb[0].x); bpk0[1]=f2bf(rb[0].y); bpk0[2]=f2bf(rb[0].z); bpk0[3]=f2bf(rb[0].w);
        bpk0[4]=f2bf(rb[1].x); bpk0[5]=f2bf(rb[1].y); bpk0[6]=f2bf(rb[1].z); bpk0[7]=f2bf(rb[1].w);
        bpk1[0]=f2bf(rb[2].x); bpk1[1]=f2bf(rb[2].y); bpk1[2]=f2bf(rb[2].z); bpk1[3]=f2bf(rb[2].w);
        bpk1[4]=f2bf(rb[3].x); bpk1[5]=f2bf(rb[3].y); bpk1[6]=f2bf(rb[3].z); bpk1[7]=f2bf(rb[3].w);

        __syncthreads();
        *reinterpret_cast<s16x8*>(&Al[srow * LDST + sk])     = apk0;
        *reinterpret_cast<s16x8*>(&Al[srow * LDST + sk + 8]) = apk1;
        *reinterpret_cast<s16x8*>(&Bl[srow * LDST + sk])     = bpk0;
        *reinterpret_cast<s16x8*>(&Bl[srow * LDST + sk + 8]) = bpk1;
        __syncthreads();

        if (k0 + 32 < K) {
            #pragma unroll
            for (int q = 0; q < 4; q++) {
                ra[q] = *reinterpret_cast<const float4*>(pa + k0 + 32 + 4 * q);
                rb[q] = *reinterpret_cast<const float4*>(pb + k0 + 32 + 4 * q);
            }
        }

        s16x8 af[4], bfv[4];
        #pragma unroll
        for (int m = 0; m < 4; m++) {
            const int base = (wr * 64 + m * 16 + fr) * LDST + fg * 4;
            s16x4 lo = *reinterpret_cast<const s16x4*>(&Al[base]);
            s16x4 hi = *reinterpret_cast<const s16x4*>(&Al[base + 16]);
            af[m] = __builtin_shufflevector(lo, hi, 0, 1, 2, 3, 4, 5, 6, 7);
        }
        #pragma unroll
        for (int n = 0; n < 4; n++) {
            const int base = (wc * 64 + n * 16 + fr) * LDST + fg * 4;
            s16x4 lo = *reinterpret_cast<const s16x4*>(&Bl[base]);
            s16x4 hi = *reinterpret_cast<const s16x4*>(&Bl[base + 16]);
            bfv[n] = __builtin_shufflevector(lo, hi, 0, 1, 2, 3, 4, 5, 6, 7);
        }
        #pragma unroll
        for (int m = 0; m < 4; m++)
            #pragma unroll
            for (int n = 0; n < 4; n++)
                acc[m][n] = __builtin_amdgcn_mfma_f32_16x16x32_bf16(af[m], bfv[n], acc[m][n], 0, 0, 0);
    }

    #pragma unroll
    for (int m = 0; m < 4; m++)
        #pragma unroll
        for (int n = 0; n < 4; n++)
            #pragma unroll
            for (int r = 0; r < 4; r++) {
                const int row = bm0 + wr * 64 + m * 16 + fg * 4 + r;
                const int col = bn0 + wc * 64 + n * 16 + fr;
                C[(size_t)row * N + col] = acc[m][n][r];
            }
}

// ---------------- bf16 MFMA MoE/shared GEMM (L2, value-path), padded LDS ----------------
template<int MODE, int EPI>
__global__ __launch_bounds__(256)
void k_mfma_moe(const float* __restrict__ A, const float* __restrict__ Wb,
                float* __restrict__ Cb,
                const int* __restrict__ idx, const int* __restrict__ cnt,
                const int* __restrict__ seg, int N, int K)
{
    int c = T_, s = 0;
    const float* B = Wb;
    const int bm0 = blockIdx.y * 128, bn0 = blockIdx.x * 128;
    if (MODE >= 1) {
        const int e = blockIdx.z;
        c = cnt[e];
        if (bm0 >= c) return;
        s = seg[e];
        B = Wb + (size_t)e * N * K;
    }
    __shared__ short Al[128 * LDST];
    __shared__ short Bl[128 * LDST];
    const int tid  = threadIdx.x;
    const int lane = tid & 63, w = tid >> 6;
    const int wr = w >> 1, wc = w & 1;
    const int fr = lane & 15, fg = lane >> 4;
    const int srow = tid >> 1, sk = (tid & 1) * 16;

    int arow;
    if (MODE == 0)      arow = bm0 + srow;
    else if (MODE == 1) arow = idx[s + min(bm0 + srow, c - 1)];
    else                arow = s + min(bm0 + srow, c - 1);
    const float* pa = A + (size_t)arow * K + sk;
    const float* pb = B + (size_t)(bn0 + srow) * K + sk;

    f32x4 acc[4][4];
    #pragma unroll
    for (int m = 0; m < 4; m++)
        #pragma unroll
        for (int n = 0; n < 4; n++) acc[m][n] = (f32x4){0.f, 0.f, 0.f, 0.f};

    float4 ra[4], rb[4];
    #pragma unroll
    for (int q = 0; q < 4; q++) {
        ra[q] = *reinterpret_cast<const float4*>(pa + 4 * q);
        rb[q] = *reinterpret_cast<const float4*>(pb + 4 * q);
    }

    for (int k0 = 0; k0 < K; k0 += 32) {
        s16x8 apk0, apk1, bpk0, bpk1;
        apk0[0]=f2bf(ra[0].x); apk0[1]=f2bf(ra[0].y); apk0[2]=f2bf(ra[0].z); apk0[3]=f2bf(ra[0].w);
        apk0[4]=f2bf(ra[1].x); apk0[5]=f2bf(ra[1].y); apk0[6]=f2bf(ra[1].z); apk0[7]=f2bf(ra[1].w);
        apk1[0]=f2bf(ra[2].x); apk1[1]=f2bf(ra[2].y); apk1[2]=f2bf(ra[2].z); apk1[3]=f2bf(ra[2].w);
        apk1[4]=f2bf(ra[3].x); apk1[5]=f2bf(ra[3].y); apk1[6]=f2bf(ra[3].z); apk1[7]=f2bf(ra[3].w);
        bpk0[0]=f2bf(rb[0].x); bpk0[1]=f2bf(rb[0].y); bpk0[2]=f2bf(rb[0].z); bpk0[3]=f2bf(rb[0].w);
        bpk0[4]=f2bf(rb[1].x); bpk0[5]=f2bf(rb[1].y); bpk0[6]=f2bf(rb[1].z); bpk0[7]=f2bf(rb[1].w);
        bpk1[0]=f2bf(rb[2].x); bpk1[1]=f2bf(rb[2].y); bpk1[2]=f2bf(rb[2].z); bpk1[3]=f2bf(rb[2].w);
        bpk1[4]=f2bf(rb[3].x); bpk1[5]=f2bf(rb[3].y); bpk1[6]=f2bf(rb[3].z); bpk1[7]=f2bf(rb[3].w);

        __syncthreads();
        *reinterpret_cast<s16x8*>(&Al[srow * LDST + sk])     = apk0;
        *reinterpret_cast<s16x8*>(&Al[srow * LDST + sk + 8]) = apk1;
        *reinterpret_cast<s16x8*>(&Bl[srow * LDST + sk])     = bpk0;
        *reinterpret_cast<s16x8*>(&Bl[srow * LDST + sk + 8]) = bpk1;
        __syncthreads();

        if (k0 + 32 < K) {
            #pragma unroll
            for (int q = 0; q < 4; q++) {
                ra[q] = *reinterpret_cast<const float4*>(pa + k0 + 32 + 4 * q);
                rb[q] = *reinterpret_cast<const float4*>(pb + k0 + 32 + 4 * q);
            }
        }

        s16x8 af[4], bfv[4];
        #pragma unroll
        for (int m = 0; m < 4; m++) {
            const int base = (wr * 64 + m * 16 + fr) * LDST + fg * 4;
            s16x4 lo = *reinterpret_cast<const s16x4*>(&Al[base]);
            s16x4 hi = *reinterpret_cast<const s16x4*>(&Al[base + 16]);
            af[m] = __builtin_shufflevector(lo, hi, 0, 1, 2, 3, 4, 5, 6, 7);
        }
        #pragma unroll
        for (int n = 0; n < 4; n++) {
            const int base = (wc * 64 + n * 16 + fr) * LDST + fg * 4;
            s16x4 lo = *reinterpret_cast<const s16x4*>(&Bl[base]);
            s16x4 hi = *reinterpret_cast<const s16x4*>(&Bl[base + 16]);
            bfv[n] = __builtin_shufflevector(lo, hi, 0, 1, 2, 3, 4, 5, 6, 7);
        }
        #pragma unroll
        for (int m = 0; m < 4; m++)
            #pragma unroll
            for (int n = 0; n < 4; n++)
                acc[m][n] = __builtin_amdgcn_mfma_f32_16x16x32_bf16(af[m], bfv[n], acc[m][n], 0, 0, 0);
    }

    #pragma unroll
    for (int m = 0; m < 4; m++)
        #pragma unroll
        for (int n = 0; n < 4; n++)
            #pragma unroll
            for (int r = 0; r < 4; r++) {
                const int row = bm0 + wr * 64 + m * 16 + fg * 4 + r;
                if (MODE >= 1 && row >= c) continue;
                const int col = bn0 + wc * 64 + n * 16 + fr;
                const size_t p = (size_t)((MODE >= 1 ? s : 0) + row) * N + col;
                if (EPI == 0)      Cb[p] = acc[m][n][r];
                else if (EPI == 1) {
                    const float gv = Cb[p];
                    Cb[p] = gv * (1.f / (1.f + expf(-gv))) * acc[m][n][r];
                } else               Cb[p] += acc[m][n][r];
            }
}

// ---------------- split-bf16 MFMA GEMM (L1, routing-safe, ~1e-5 rel err) ----------------
// a = hi + lo (bf16 pair); a*b ~= hi*hi + lo*hi + hi*lo (3 MFMAs per fragment)
template<int MODE, int EPI>
__global__ __launch_bounds__(256)
void k_mfma_sp(const float* __restrict__ A, const float* __restrict__ Wb,
               float* __restrict__ Cb,
               const int* __restrict__ idx, const int* __restrict__ cnt,
               const int* __restrict__ seg, int N, int K)
{
    int c = T_, s = 0;
    const float* B = Wb;
    const int bm0 = blockIdx.y * 128, bn0 = blockIdx.x * 128;
    if (MODE >= 1) {
        const int e = blockIdx.z;
        c = cnt[e];
        if (bm0 >= c) return;
        s = seg[e];
        B = Wb + (size_t)e * N * K;
    }
    __shared__ short Ahi[128 * LDST];
    __shared__ short Alo[128 * LDST];
    __shared__ short Bhi[128 * LDST];
    __shared__ short Blo[128 * LDST];
    const int tid  = threadIdx.x;
    const int lane = tid & 63, w = tid >> 6;
    const int wr = w >> 1, wc = w & 1;
    const int fr = lane & 15, fg = lane >> 4;
    const int srow = tid >> 1, sk = (tid & 1) * 16;

    int arow;
    if (MODE == 0)      arow = bm0 + srow;
    else if (MODE == 1) arow = idx[s + min(bm0 + srow, c - 1)];
    else                arow = s + min(bm0 + srow, c - 1);
    const float* pa = A + (size_t)arow * K + sk;
    const float* pb = B + (size_t)(bn0 + srow) * K + sk;

    f32x4 acc[4][4];
    #pragma unroll
    for (int m = 0; m < 4; m++)
        #pragma unroll
        for (int n = 0; n < 4; n++) acc[m][n] = (f32x4){0.f, 0.f, 0.f, 0.f};

    float va[16], vb[16];
    #pragma unroll
    for (int q = 0; q < 4; q++) {
        float4 t = *reinterpret_cast<const float4*>(pa + 4 * q);
        va[4*q] = t.x; va[4*q+1] = t.y; va[4*q+2] = t.z; va[4*q+3] = t.w;
        t = *reinterpret_cast<const float4*>(pb + 4 * q);
        vb[4*q] = t.x; vb[4*q+1] = t.y; vb[4*q+2] = t.z; vb[4*q+3] = t.w;
    }

    for (int k0 = 0; k0 < K; k0 += 32) {
        s16x8 ah0, ah1, al0, al1, bh0, bh1, bl0, bl1;
        #pragma unroll
        for (int i = 0; i < 8; i++) {
            short h = f2bf(va[i]);     ah0[i] = h; al0[i] = f2bf(va[i] - bf2f(h));
            h = f2bf(va[8 + i]);       ah1[i] = h; al1[i] = f2bf(va[8 + i] - bf2f(h));
            h = f2bf(vb[i]);           bh0[i] = h; bl0[i] = f2bf(vb[i] - bf2f(h));
            h = f2bf(vb[8 + i]);       bh1[i] = h; bl1[i] = f2bf(vb[8 + i] - bf2f(h));
        }

        __syncthreads();
        *reinterpret_cast<s16x8*>(&Ahi[srow * LDST + sk])     = ah0;
        *reinterpret_cast<s16x8*>(&Ahi[srow * LDST + sk + 8]) = ah1;
        *reinterpret_cast<s16x8*>(&Alo[srow * LDST + sk])     = al0;
        *reinterpret_cast<s16x8*>(&Alo[srow * LDST + sk + 8]) = al1;
        *reinterpret_cast<s16x8*>(&Bhi[srow * LDST + sk])     = bh0;
        *reinterpret_cast<s16x8*>(&Bhi[srow * LDST + sk + 8]) = bh1;
        *reinterpret_cast<s16x8*>(&Blo[srow * LDST + sk])     = bl0;
        *reinterpret_cast<s16x8*>(&Blo[srow * LDST + sk + 8]) = bl1;
        __syncthreads();

        if (k0 + 32 < K) {
            #pragma unroll
            for (int q = 0; q < 4; q++) {
                float4 t = *reinterpret_cast<const float4*>(pa + k0 + 32 + 4 * q);
                va[4*q] = t.x; va[4*q+1] = t.y; va[4*q+2] = t.z; va[4*q+3] = t.w;
                t = *reinterpret_cast<const float4*>(pb + k0 + 32 + 4 * q);
                vb[4*q] = t.x; vb[4*q+1] = t.y; vb[4*q+2] = t.z; vb[4*q+3] = t.w;
            }
        }

        s16x8 afh[4], afl[4];
        #pragma unroll
        for (int m = 0; m < 4; m++) {
            const int base = (wr * 64 + m * 16 + fr) * LDST + fg * 4;
            s16x4 lo = *reinterpret_cast<const s16x4*>(&Ahi[base]);
            s16x4 hi = *reinterpret_cast<const s16x4*>(&Ahi[base + 16]);
            afh[m] = __builtin_shufflevector(lo, hi, 0, 1, 2, 3, 4, 5, 6, 7);
            lo = *reinterpret_cast<const s16x4*>(&Alo[base]);
            hi = *reinterpret_cast<const s16x4*>(&Alo[base + 16]);
            afl[m] = __builtin_shufflevector(lo, hi, 0, 1, 2, 3, 4, 5, 6, 7);
        }
        #pragma unroll
        for (int n = 0; n < 4; n++) {
            const int base = (wc * 64 + n * 16 + fr) * LDST + fg * 4;
            s16x4 lo = *reinterpret_cast<const s16x4*>(&Bhi[base]);
            s16x4 hi = *reinterpret_cast<const s16x4*>(&Bhi[base + 16]);
            s16x8 bh = __builtin_shufflevector(lo, hi, 0, 1, 2, 3, 4, 5, 6, 7);
            lo = *reinterpret_cast<const s16x4*>(&Blo[base]);
            hi = *reinterpret_cast<const s16x4*>(&Blo[base + 16]);
            s16x8 bl = __builtin_shufflevector(lo, hi, 0, 1, 2, 3, 4, 5, 6, 7);
            #pragma unroll
            for (int m = 0; m < 4; m++) {
                acc[m][n] = __builtin_amdgcn_mfma_f32_16x16x32_bf16(afh[m], bh, acc[m][n], 0, 0, 0);
                acc[m][n] = __builtin_amdgcn_mfma_f32_16x16x32_bf16(afl[m], bh, acc[m][n], 0, 0, 0);
                acc[m][n] = __builtin_amdgcn_mfma_f32_16x16x32_bf16(afh[m], bl, acc[m][n], 0, 0, 0);
            }
        }
    }

    #pragma unroll
    for (int m = 0; m < 4; m++)
        #pragma unroll
        for (int n = 0; n < 4; n++)
            #pragma unroll
            for (int r = 0; r < 4; r++) {
                const int row = bm0 + wr * 64 + m * 16 + fg * 4 + r;
                if (MODE >= 1 && row >= c) continue;
                const int col = bn0 + wc * 64 + n * 16 + fr;
                const size_t p = (size_t)((MODE >= 1 ? s : 0) + row) * N + col;
                if (EPI == 0)      Cb[p] = acc[m][n][r];
                else if (EPI == 1) {
                    const float gv = Cb[p];
                    Cb[p] = gv * (1.f / (1.f + expf(-gv))) * acc[m][n][r];
                } else               Cb[p] += acc[m][n][r];
            }
}

#define GEMM(BL, EPI, A, Bw, CC, M, N, K) \
    k_gemm<BL, EPI><<<dim3((N)/128, (M)/128), 256, 0, stream>>>(A, Bw, CC, M, N, K)

extern "C" void kernel_launch(void* const* d_in, const int* in_sizes, int n_in,
                              void* d_out, int out_size, void* d_ws, size_t ws_size,
                              hipStream_t stream)
{
    const int*   ids    = (const int*)  d_in[0];
    const float* embed  = (const float*)d_in[1];
    const float* ln1_g  = (const float*)d_in[2];
    const float* ln1_b  = (const float*)d_in[3];
    const float* wq     = (const float*)d_in[4];
    const float* wk     = (const float*)d_in[5];
    const float* wv     = (const float*)d_in[6];
    const float* wo     = (const float*)d_in[7];
    const float* ln2_g  = (const float*)d_in[8];
    const float* ln2_b  = (const float*)d_in[9];
    const float* gate_w = (const float*)d_in[10];
    const float* exp_wg = (const float*)d_in[11];
    const float* exp_wu = (const float*)d_in[12];
    const float* exp_wd = (const float*)d_in[13];
    const float* sh_wg  = (const float*)d_in[14];
    const float* sh_wu  = (const float*)d_in[15];
    const float* sh_wd  = (const float*)d_in[16];
    const float* fn_g   = (const float*)d_in[17];
    const float* fn_b   = (const float*)d_in[18];
    const float* lm     = (const float*)d_in[19];
    float* out = (float*)d_out;

    float* x    = (float*)d_ws;                 // T*H
    float* h    = x + 2097152;                  // T*H
    float* qb   = h + 2097152;                  // T*H   (R1, aliased by ebuf)
    float* kv   = qb + 2097152;                 // T*512 [k|v] packed
    float* ob   = kv + 1048576;                 // T*H
    float* ebuf = qb;                           // CAP*H aliases qb..(incl kv,ob)
    float* gbuf = qb + 5242880;                 // CAP*I
    float* gw   = gbuf + 5242880;               // T*8
    float* wl   = gw + (size_t)T_ * E_;         // CAP
    int*   idx  = (int*)(wl + CAP_);            // CAP
    int*   pos  = idx + CAP_;                   // T*2
    int*   cnt  = pos + 2 * T_;                 // 8
    int*   seg  = cnt + E_;                     // 8

    k_embed<<<T_, 256, 0, stream>>>(ids, embed, x);

    for (int l = 0; l < L_; l++) {
        k_layernorm<<<T_, 256, 0, stream>>>(x, ln1_g + (size_t)l * H_, ln1_b + (size_t)l * H_, h);

        k_gemm_qkv<<<dim3(12, 16), 256, 0, stream>>>(
            h, wq + (size_t)l * H_ * H_, wk + (size_t)l * H_ * 256, wv + (size_t)l * H_ * 256, qb, kv);

        k_rope<<<(T_ * NH_  * 32) / 256, 256, 0, stream>>>(qb, 1024, NH_);
        k_rope<<<(T_ * NKV_ * 32) / 256, 256, 0, stream>>>(kv, 512,  NKV_);

        k_attn4<<<dim3(S_ / 64, NH_, B_), 256, 0, stream>>>(qb, kv, ob);

        GEMM(0, 2, ob, wo + (size_t)l * H_ * H_, x, T_, H_, H_);

        k_layernorm<<<T_, 256, 0, stream>>>(x, ln2_g + (size_t)l * H_, ln2_b + (size_t)l * H_, h);
        k_gate<<<T_, 64, 0, stream>>>(h, gate_w + (size_t)l * E_ * H_, gw);
        k_build<<<1, 512, 0, stream>>>(gw, idx, wl, pos, cnt, seg);

        const float* wg_l = exp_wg + (size_t)l * E_ * I_ * H_;
        const float* wu_l = exp_wu + (size_t)l * E_ * I_ * H_;
        const float* wd_l = exp_wd + (size_t)l * E_ * H_ * I_;

        if (l == 0) {   // routing-critical layer: split-bf16 MFMA (~1e-5 rel err)
            k_mfma_sp<0, 0><<<dim3(8, 16, 1), 256, 0, stream>>>(h, sh_wg + (size_t)l * I_ * H_, gbuf, nullptr, nullptr, nullptr, I_, H_);
            k_mfma_sp<0, 1><<<dim3(8, 16, 1), 256, 0, stream>>>(h, sh_wu + (size_t)l * I_ * H_, gbuf, nullptr, nullptr, nullptr, I_, H_);
            k_mfma_sp<0, 2><<<dim3(8, 16, 1), 256, 0, stream>>>(gbuf, sh_wd + (size_t)l * H_ * I_, x, nullptr, nullptr, nullptr, H_, I_);
            k_mfma_sp<1, 0><<<dim3(8, 16, E_), 256, 0, stream>>>(h, wg_l, gbuf, idx, cnt, seg, I_, H_);
            k_mfma_sp<1, 1><<<dim3(8, 16, E_), 256, 0, stream>>>(h, wu_l, gbuf, idx, cnt, seg, I_, H_);
            k_mfma_sp<2, 0><<<dim3(8, 16, E_), 256, 0, stream>>>(gbuf, wd_l, ebuf, idx, cnt, seg, H_, I_);
        } else {        // last layer: value path only -> plain bf16 MFMA
            k_mfma_moe<0, 0><<<dim3(8, 16, 1), 256, 0, stream>>>(h, sh_wg + (size_t)l * I_ * H_, gbuf, nullptr, nullptr, nullptr, I_, H_);
            k_mfma_moe<0, 1><<<dim3(8, 16, 1), 256, 0, stream>>>(h, sh_wu + (size_t)l * I_ * H_, gbuf, nullptr, nullptr, nullptr, I_, H_);
            k_mfma_moe<0, 2><<<dim3(8, 16, 1), 256, 0, stream>>>(gbuf, sh_wd + (size_t)l * H_ * I_, x, nullptr, nullptr, nullptr, H_, I_);
            k_mfma_moe<1, 0><<<dim3(8, 16, E_), 256, 0, stream>>>(h, wg_l, gbuf, idx, cnt, seg, I_, H_);
            k_mfma_moe<1, 1><<<dim3(8, 16, E_), 256, 0, stream>>>(h, wu_l, gbuf, idx, cnt, seg, I_, H_);
            k_mfma_moe<2, 0><<<dim3(8, 16, E_), 256, 0, stream>>>(gbuf, wd_l, ebuf, idx, cnt, seg, H_, I_);
        }
        k_combine<<<(T_ * H_) / 256, 256, 0, stream>>>(x, ebuf, wl, pos);
    }

    k_layernorm<<<T_, 256, 0, stream>>>(x, fn_g, fn_b, h);
    k_gemm_mfma_bt<<<(T_ / 128) * (V_ / 128), 256, 0, stream>>>(h, lm, out, T_, V_, H_);
}

// Round 9
// 2457.794 us; speedup vs baseline: 4.8714x; 1.0141x over previous
//
#include <hip/hip_runtime.h>
#include <cmath>

#define L_   2
#define E_   8
#define NH_  16
#define NKV_ 4
#define HD_  64
#define H_   1024
#define I_   1024
#define B_   2
#define S_   1024
#define T_   (B_*S_)
#define V_   32000
#define CAP_ 5120
#define LDST 36   // LDS row stride in shorts: bank=(row*18+col/2)%32 -> only free 2-way aliases

typedef float f32x4 __attribute__((ext_vector_type(4)));
typedef short s16x4 __attribute__((ext_vector_type(4)));
typedef short s16x8 __attribute__((ext_vector_type(8)));

__device__ __forceinline__ short f2bf(float f) {
    unsigned u = __float_as_uint(f);
    u = (u + 0x7fffu + ((u >> 16) & 1u)) >> 16;   // RNE
    return (short)u;
}
__device__ __forceinline__ float bf2f(short h) {
    return __uint_as_float(((unsigned)(unsigned short)h) << 16);
}

// ---------------- converters (run once per launch) ----------------
__global__ __launch_bounds__(256)
void k_cvt(const float* __restrict__ s, short* __restrict__ d, int n8)
{
    const int i = blockIdx.x * 256 + threadIdx.x;
    if (i >= n8) return;
    const float4 a = *reinterpret_cast<const float4*>(s + (size_t)i * 8);
    const float4 b = *reinterpret_cast<const float4*>(s + (size_t)i * 8 + 4);
    s16x8 o;
    o[0]=f2bf(a.x); o[1]=f2bf(a.y); o[2]=f2bf(a.z); o[3]=f2bf(a.w);
    o[4]=f2bf(b.x); o[5]=f2bf(b.y); o[6]=f2bf(b.z); o[7]=f2bf(b.w);
    *reinterpret_cast<s16x8*>(d + (size_t)i * 8) = o;
}

__global__ __launch_bounds__(256)
void k_cvt_sp(const float* __restrict__ s, short* __restrict__ dh, short* __restrict__ dl, int n8)
{
    const int i = blockIdx.x * 256 + threadIdx.x;
    if (i >= n8) return;
    const float4 a = *reinterpret_cast<const float4*>(s + (size_t)i * 8);
    const float4 b = *reinterpret_cast<const float4*>(s + (size_t)i * 8 + 4);
    float v[8] = {a.x, a.y, a.z, a.w, b.x, b.y, b.z, b.w};
    s16x8 oh, ol;
    #pragma unroll
    for (int j = 0; j < 8; j++) {
        const short hh = f2bf(v[j]);
        oh[j] = hh;
        ol[j] = f2bf(v[j] - bf2f(hh));
    }
    *reinterpret_cast<s16x8*>(dh + (size_t)i * 8) = oh;
    *reinterpret_cast<s16x8*>(dl + (size_t)i * 8) = ol;
}

// ---------------- embedding ----------------
__global__ void k_embed(const int* __restrict__ ids, const float* __restrict__ emb,
                        float* __restrict__ x)
{
    const int t = blockIdx.x;
    const float* src = emb + (size_t)ids[t] * H_;
    float* dst = x + (size_t)t * H_;
    for (int i = threadIdx.x; i < H_; i += 256) dst[i] = src[i];
}

// ---------------- layernorm ----------------
__global__ __launch_bounds__(256)
void k_layernorm(const float* __restrict__ x, const float* __restrict__ g,
                 const float* __restrict__ bb, float* __restrict__ out)
{
    const int t = blockIdx.x;
    const float* row = x + (size_t)t * H_;
    float s = 0.f, ss = 0.f;
    for (int i = threadIdx.x; i < H_; i += 256) { const float v = row[i]; s += v; ss += v * v; }
    #pragma unroll
    for (int off = 32; off > 0; off >>= 1) {
        s  += __shfl_down(s, off, 64);
        ss += __shfl_down(ss, off, 64);
    }
    __shared__ float shs[4], shss[4];
    const int w = threadIdx.x >> 6;
    if ((threadIdx.x & 63) == 0) { shs[w] = s; shss[w] = ss; }
    __syncthreads();
    const float fs  = shs[0] + shs[1] + shs[2] + shs[3];
    const float fss = shss[0] + shss[1] + shss[2] + shss[3];
    const float mean = fs * (1.f / H_);
    const float var  = fss * (1.f / H_) - mean * mean;
    const float rstd = 1.0f / sqrtf(var + 1e-5f);
    float* orow = out + (size_t)t * H_;
    for (int i = threadIdx.x; i < H_; i += 256)
        orow[i] = (row[i] - mean) * rstd * g[i] + bb[i];
}

// ---------------- RoPE ----------------
__global__ void k_rope(float* __restrict__ x, int rowStride, int nheads)
{
    const int idx  = blockIdx.x * 256 + threadIdx.x;
    const int i    = idx & 31;
    const int rest = idx >> 5;
    const int head = rest % nheads;
    const int t    = rest / nheads;
    const int pos  = t & (S_ - 1);
    const float p32  = (float)pow(1.0e6, (double)i / 32.0);
    const float invf = 1.0f / p32;
    const float ang  = (float)pos * invf;
    const float c = (float)cos((double)ang);
    const float s = (float)sin((double)ang);
    float* base = x + (size_t)t * rowStride + head * HD_;
    const float x1 = base[i];
    const float x2 = base[i + 32];
    base[i]      = x1 * c - x2 * s;
    base[i + 32] = x2 * c + x1 * s;
}

// ---------------- causal GQA attention, 4-wave split-K ----------------
__global__ __launch_bounds__(256)
void k_attn4(const float* __restrict__ q, const float* __restrict__ kv,
             float* __restrict__ o)
{
    const int q0 = blockIdx.x * 64, h = blockIdx.y, b = blockIdx.z;
    const int kvh = h >> 2;
    const int tid = threadIdx.x, lane = tid & 63, w = tid >> 6;
    const int row = q0 + lane;
    __shared__ float tiles[4][2][32][68];
    __shared__ float lsums[4][64];
    float (*Kw)[68] = tiles[w][0];
    float (*Vw)[68] = tiles[w][1];

    float qr[64], oacc[64];
    {
        const float* qs = q + (size_t)(b * S_ + row) * H_ + h * HD_;
        #pragma unroll
        for (int d4 = 0; d4 < 16; d4++) {
            float4 t = *reinterpret_cast<const float4*>(qs + 4 * d4);
            qr[4*d4+0] = t.x * 0.125f; qr[4*d4+1] = t.y * 0.125f;
            qr[4*d4+2] = t.z * 0.125f; qr[4*d4+3] = t.w * 0.125f;
        }
    }
    #pragma unroll
    for (int d = 0; d < 64; d++) oacc[d] = 0.f;
    float lsum = 0.f;

    const int nkb = (q0 >> 5) + 2;
    const int r = lane >> 1, half = (lane & 1) * 32;
    for (int kb = w; kb < nkb; kb += 4) {
        const int j0 = kb * 32;
        {
            const float* srck = kv + (size_t)(b * S_ + j0 + r) * 512 + kvh * 64 + half;
            const float* srcv = srck + 256;
            #pragma unroll
            for (int d4 = 0; d4 < 8; d4++) {
                *reinterpret_cast<float4*>(&Kw[r][half + 4*d4]) = *reinterpret_cast<const float4*>(srck + 4*d4);
                *reinterpret_cast<float4*>(&Vw[r][half + 4*d4]) = *reinterpret_cast<const float4*>(srcv + 4*d4);
            }
        }
        __builtin_amdgcn_wave_barrier();
        const int jend = min(32, row - j0 + 1);
        for (int j = 0; j < jend; j++) {
            float s = 0.f;
            #pragma unroll
            for (int d4 = 0; d4 < 16; d4++) {
                const float4 kvv = *reinterpret_cast<const float4*>(&Kw[j][4*d4]);
                s += qr[4*d4+0]*kvv.x + qr[4*d4+1]*kvv.y + qr[4*d4+2]*kvv.z + qr[4*d4+3]*kvv.w;
            }
            const float e = expf(s);
            lsum += e;
            #pragma unroll
            for (int d4 = 0; d4 < 16; d4++) {
                const float4 vw = *reinterpret_cast<const float4*>(&Vw[j][4*d4]);
                oacc[4*d4+0] += e * vw.x; oacc[4*d4+1] += e * vw.y;
                oacc[4*d4+2] += e * vw.z; oacc[4*d4+3] += e * vw.w;
            }
        }
        __builtin_amdgcn_wave_barrier();
    }

    lsums[w][lane] = lsum;
    float (*cb)[68] = reinterpret_cast<float(*)[68]>(&tiles[0][0][0][0]);
    if (w == 0) {
        #pragma unroll
        for (int d4 = 0; d4 < 16; d4++)
            *reinterpret_cast<float4*>(&cb[lane][4*d4]) =
                make_float4(oacc[4*d4+0], oacc[4*d4+1], oacc[4*d4+2], oacc[4*d4+3]);
    }
    __syncthreads();
    if (w == 1) {
        #pragma unroll
        for (int d = 0; d < 64; d++) cb[lane][d] += oacc[d];
    }
    __syncthreads();
    if (w == 2) {
        #pragma unroll
        for (int d = 0; d < 64; d++) cb[lane][d] += oacc[d];
    }
    __syncthreads();
    if (w == 3) {
        #pragma unroll
        for (int d = 0; d < 64; d++) cb[lane][d] += oacc[d];
    }
    __syncthreads();
    if (w == 0) {
        const float inv = 1.0f / (lsums[0][lane] + lsums[1][lane] + lsums[2][lane] + lsums[3][lane]);
        float* od = o + (size_t)(b * S_ + row) * H_ + h * HD_;
        #pragma unroll
        for (int d4 = 0; d4 < 16; d4++) {
            float4 t;
            t.x = cb[lane][4*d4+0] * inv; t.y = cb[lane][4*d4+1] * inv;
            t.z = cb[lane][4*d4+2] * inv; t.w = cb[lane][4*d4+3] * inv;
            *reinterpret_cast<float4*>(od + 4*d4) = t;
        }
    }
}

// ---------------- MoE gate ----------------
__global__ __launch_bounds__(64)
void k_gate(const float* __restrict__ h, const float* __restrict__ gwt, float* __restrict__ w)
{
    const int t = blockIdx.x;
    const int lane = threadIdx.x;
    const float* row = h + (size_t)t * H_;
    float acc[E_];
    #pragma unroll
    for (int e = 0; e < E_; e++) acc[e] = 0.f;
    for (int i = lane; i < H_; i += 64) {
        const float xv = row[i];
        #pragma unroll
        for (int e = 0; e < E_; e++) acc[e] += xv * gwt[(size_t)e * H_ + i];
    }
    #pragma unroll
    for (int e = 0; e < E_; e++) {
        #pragma unroll
        for (int off = 32; off > 0; off >>= 1) acc[e] += __shfl_down(acc[e], off, 64);
    }
    if (lane == 0) {
        int i1 = 0; float m1 = acc[0];
        #pragma unroll
        for (int e = 1; e < E_; e++) if (acc[e] > m1) { m1 = acc[e]; i1 = e; }
        int i2 = -1; float m2 = -1e30f;
        #pragma unroll
        for (int e = 0; e < E_; e++) if (e != i1 && acc[e] > m2) { m2 = acc[e]; i2 = e; }
        const float e2  = expf(m2 - m1);
        const float den = 1.0f + e2;
        #pragma unroll
        for (int e = 0; e < E_; e++)
            w[t * E_ + e] = (e == i1) ? (1.0f / den) : ((e == i2) ? (e2 / den) : 0.f);
    }
}

// ---------------- build per-expert token lists ----------------
__global__ __launch_bounds__(512)
void k_build(const float* __restrict__ gw, int* __restrict__ idx, float* __restrict__ wl,
             int* __restrict__ pos, int* __restrict__ cnt, int* __restrict__ seg)
{
    const int e = threadIdx.x >> 6;
    const int lane = threadIdx.x & 63;
    __shared__ int scnt[E_], sseg[E_];
    int c = 0;
    for (int t0 = 0; t0 < T_; t0 += 64) {
        const float v = gw[(size_t)(t0 + lane) * E_ + e];
        c += __popcll(__ballot(v > 0.f));
    }
    if (lane == 0) scnt[e] = c;
    __syncthreads();
    if (threadIdx.x == 0) {
        int off = 0;
        for (int q = 0; q < E_; q++) {
            sseg[q] = off; cnt[q] = scnt[q]; seg[q] = off;
            off += (scnt[q] + 127) & ~127;
        }
    }
    __syncthreads();
    int p = sseg[e];
    for (int t0 = 0; t0 < T_; t0 += 64) {
        const int t = t0 + lane;
        const float v = gw[(size_t)t * E_ + e];
        const unsigned long long m = __ballot(v > 0.f);
        if (v > 0.f) {
            const int pp = p + __popcll(m & ((1ull << lane) - 1ull));
            idx[pp] = t; wl[pp] = v;
            int slot = 0;
            for (int q = 0; q < e; q++) slot += (gw[(size_t)t * E_ + q] > 0.f) ? 1 : 0;
            pos[t * 2 + slot] = pp;
        }
        p += __popcll(m);
    }
}

// ---------------- combine ----------------
__global__ void k_combine(float* __restrict__ x, const float* __restrict__ ebuf,
                          const float* __restrict__ wl, const int* __restrict__ pos)
{
    const int id = blockIdx.x * 256 + threadIdx.x;
    const int t = id >> 10;
    const int hc = id & 1023;
    const int p0 = pos[t * 2], p1 = pos[t * 2 + 1];
    x[id] += wl[p0] * ebuf[(size_t)p0 * H_ + hc] + wl[p1] * ebuf[(size_t)p1 * H_ + hc];
}

// ---------------- f32 SIMT GEMM (wo projection) ----------------
template<int BL, int EPI>
__global__ __launch_bounds__(256, 2)
void k_gemm(const float* __restrict__ A, const float* __restrict__ B,
            float* __restrict__ C, int M, int N, int K)
{
    __shared__ float As[128][20];
    __shared__ float Bs[16][132];
    const int tid = threadIdx.x;
    const int bm0 = blockIdx.y * 128, bn0 = blockIdx.x * 128;
    const int tx = tid & 15, ty = tid >> 4;
    float acc[8][8];
    #pragma unroll
    for (int i = 0; i < 8; i++)
        #pragma unroll
        for (int j = 0; j < 8; j++) acc[i][j] = 0.f;
    const int ra = tid >> 1, ca = (tid & 1) * 8;
    for (int k0 = 0; k0 < K; k0 += 16) {
        __syncthreads();
        {
            const float* src = A + (size_t)(bm0 + ra) * K + (k0 + ca);
            *reinterpret_cast<float4*>(&As[ra][ca])     = *reinterpret_cast<const float4*>(src);
            *reinterpret_cast<float4*>(&As[ra][ca + 4]) = *reinterpret_cast<const float4*>(src + 4);
        }
        if (BL == 0) {
            const int kb = tid >> 4, n8 = (tid & 15) * 8;
            const float* src = B + (size_t)(k0 + kb) * N + (bn0 + n8);
            *reinterpret_cast<float4*>(&Bs[kb][n8])     = *reinterpret_cast<const float4*>(src);
            *reinterpret_cast<float4*>(&Bs[kb][n8 + 4]) = *reinterpret_cast<const float4*>(src + 4);
        } else {
            const float* src = B + (size_t)(bn0 + ra) * K + (k0 + ca);
            float4 r0 = *reinterpret_cast<const float4*>(src);
            float4 r1 = *reinterpret_cast<const float4*>(src + 4);
            Bs[ca + 0][ra] = r0.x; Bs[ca + 1][ra] = r0.y;
            Bs[ca + 2][ra] = r0.z; Bs[ca + 3][ra] = r0.w;
            Bs[ca + 4][ra] = r1.x; Bs[ca + 5][ra] = r1.y;
            Bs[ca + 6][ra] = r1.z; Bs[ca + 7][ra] = r1.w;
        }
        __syncthreads();
        #pragma unroll
        for (int kkx = 0; kkx < 16; kkx++) {
            float a[8], b[8];
            #pragma unroll
            for (int i = 0; i < 4; i++) {
                a[i]     = As[ty * 4 + i][kkx];
                a[4 + i] = As[64 + ty * 4 + i][kkx];
            }
            const float4 b0 = *reinterpret_cast<const float4*>(&Bs[kkx][tx * 4]);
            const float4 b1 = *reinterpret_cast<const float4*>(&Bs[kkx][64 + tx * 4]);
            b[0] = b0.x; b[1] = b0.y; b[2] = b0.z; b[3] = b0.w;
            b[4] = b1.x; b[5] = b1.y; b[6] = b1.z; b[7] = b1.w;
            #pragma unroll
            for (int i = 0; i < 8; i++)
                #pragma unroll
                for (int j = 0; j < 8; j++) acc[i][j] += a[i] * b[j];
        }
    }
    #pragma unroll
    for (int i = 0; i < 8; i++) {
        const int row = bm0 + (i & 3) + ((i >> 2) * 64) + ty * 4;
        #pragma unroll
        for (int j = 0; j < 8; j++) {
            const int col = bn0 + (j & 3) + ((j >> 2) * 64) + tx * 4;
            const size_t p = (size_t)row * N + col;
            if (EPI == 0)      C[p] = acc[i][j];
            else if (EPI == 2) C[p] += acc[i][j];
        }
    }
}

// ---------------- fused q/k/v GEMM (f32) ----------------
__global__ __launch_bounds__(256, 2)
void k_gemm_qkv(const float* __restrict__ A, const float* __restrict__ Bq,
                const float* __restrict__ Bk, const float* __restrict__ Bv,
                float* __restrict__ Cq, float* __restrict__ Ckv)
{
    const int bn0 = blockIdx.x * 128, bm0 = blockIdx.y * 128;
    const float* B; float* C; int ldb, ldc, bcol, ccol;
    if (bn0 < 1024)      { B = Bq; ldb = 1024; bcol = bn0;        C = Cq;  ldc = 1024; ccol = bn0; }
    else if (bn0 < 1280) { B = Bk; ldb = 256;  bcol = bn0 - 1024; C = Ckv; ldc = 512;  ccol = bn0 - 1024; }
    else                 { B = Bv; ldb = 256;  bcol = bn0 - 1280; C = Ckv; ldc = 512;  ccol = bn0 - 1024; }

    __shared__ float As[128][20];
    __shared__ float Bs[16][132];
    const int tid = threadIdx.x;
    const int tx = tid & 15, ty = tid >> 4;
    float acc[8][8];
    #pragma unroll
    for (int i = 0; i < 8; i++)
        #pragma unroll
        for (int j = 0; j < 8; j++) acc[i][j] = 0.f;
    const int ra = tid >> 1, ca = (tid & 1) * 8;
    for (int k0 = 0; k0 < H_; k0 += 16) {
        __syncthreads();
        {
            const float* src = A + (size_t)(bm0 + ra) * H_ + (k0 + ca);
            *reinterpret_cast<float4*>(&As[ra][ca])     = *reinterpret_cast<const float4*>(src);
            *reinterpret_cast<float4*>(&As[ra][ca + 4]) = *reinterpret_cast<const float4*>(src + 4);
        }
        {
            const int kb = tid >> 4, n8 = (tid & 15) * 8;
            const float* src = B + (size_t)(k0 + kb) * ldb + (bcol + n8);
            *reinterpret_cast<float4*>(&Bs[kb][n8])     = *reinterpret_cast<const float4*>(src);
            *reinterpret_cast<float4*>(&Bs[kb][n8 + 4]) = *reinterpret_cast<const float4*>(src + 4);
        }
        __syncthreads();
        #pragma unroll
        for (int kkx = 0; kkx < 16; kkx++) {
            float a[8], b[8];
            #pragma unroll
            for (int i = 0; i < 4; i++) {
                a[i]     = As[ty * 4 + i][kkx];
                a[4 + i] = As[64 + ty * 4 + i][kkx];
            }
            const float4 b0 = *reinterpret_cast<const float4*>(&Bs[kkx][tx * 4]);
            const float4 b1 = *reinterpret_cast<const float4*>(&Bs[kkx][64 + tx * 4]);
            b[0] = b0.x; b[1] = b0.y; b[2] = b0.z; b[3] = b0.w;
            b[4] = b1.x; b[5] = b1.y; b[6] = b1.z; b[7] = b1.w;
            #pragma unroll
            for (int i = 0; i < 8; i++)
                #pragma unroll
                for (int j = 0; j < 8; j++) acc[i][j] += a[i] * b[j];
        }
    }
    #pragma unroll
    for (int i = 0; i < 8; i++) {
        const int row = bm0 + (i & 3) + ((i >> 2) * 64) + ty * 4;
        #pragma unroll
        for (int j = 0; j < 8; j++) {
            const int col = ccol + (j & 3) + ((j >> 2) * 64) + tx * 4;
            C[(size_t)row * ldc + col] = acc[i][j];
        }
    }
}

// ---------------- bf16-input MFMA GEMM (lm_head): C(M,N) f32 = A_bf(M,K) x B_bf(N,K) ----------------
__global__ __launch_bounds__(256)
void k_mfma_bt_b(const short* __restrict__ A, const short* __restrict__ Bm,
                 float* __restrict__ C, int M, int N, int K)
{
    __shared__ short Als[128 * LDST];
    __shared__ short Bls[128 * LDST];
    const int mB = M >> 7;
    const int l  = blockIdx.x;
    const int g  = l / (mB * 8);
    const int ii = l - g * (mB * 8);
    const int bm0 = (ii % mB) * 128;
    const int bn0 = (g * 8 + ii / mB) * 128;

    const int tid  = threadIdx.x;
    const int lane = tid & 63, w = tid >> 6;
    const int wr = w >> 1, wc = w & 1;
    const int fr = lane & 15, fg = lane >> 4;
    const int srow = tid >> 1, sk = (tid & 1) * 16;

    const short* pa = A  + (size_t)(bm0 + srow) * K + sk;
    const short* pb = Bm + (size_t)(bn0 + srow) * K + sk;

    f32x4 acc[4][4];
    #pragma unroll
    for (int m = 0; m < 4; m++)
        #pragma unroll
        for (int n = 0; n < 4; n++) acc[m][n] = (f32x4){0.f, 0.f, 0.f, 0.f};

    s16x8 ra0 = *reinterpret_cast<const s16x8*>(pa);
    s16x8 ra1 = *reinterpret_cast<const s16x8*>(pa + 8);
    s16x8 rb0 = *reinterpret_cast<const s16x8*>(pb);
    s16x8 rb1 = *reinterpret_cast<const s16x8*>(pb + 8);

    for (int k0 = 0; k0 < K; k0 += 32) {
        __syncthreads();
        *reinterpret_cast<s16x8*>(&Als[srow * LDST + sk])     = ra0;
        *reinterpret_cast<s16x8*>(&Als[srow * LDST + sk + 8]) = ra1;
        *reinterpret_cast<s16x8*>(&Bls[srow * LDST + sk])     = rb0;
        *reinterpret_cast<s16x8*>(&Bls[srow * LDST + sk + 8]) = rb1;
        __syncthreads();
        if (k0 + 32 < K) {
            ra0 = *reinterpret_cast<const s16x8*>(pa + k0 + 32);
            ra1 = *reinterpret_cast<const s16x8*>(pa + k0 + 40);
            rb0 = *reinterpret_cast<const s16x8*>(pb + k0 + 32);
            rb1 = *reinterpret_cast<const s16x8*>(pb + k0 + 40);
        }
        s16x8 af[4], bfv[4];
        #pragma unroll
        for (int m = 0; m < 4; m++) {
            const int base = (wr * 64 + m * 16 + fr) * LDST + fg * 4;
            s16x4 lo = *reinterpret_cast<const s16x4*>(&Als[base]);
            s16x4 hi = *reinterpret_cast<const s16x4*>(&Als[base + 16]);
            af[m] = __builtin_shufflevector(lo, hi, 0, 1, 2, 3, 4, 5, 6, 7);
        }
        #pragma unroll
        for (int n = 0; n < 4; n++) {
            const int base = (wc * 64 + n * 16 + fr) * LDST + fg * 4;
            s16x4 lo = *reinterpret_cast<const s16x4*>(&Bls[base]);
            s16x4 hi = *reinterpret_cast<const s16x4*>(&Bls[base + 16]);
            bfv[n] = __builtin_shufflevector(lo, hi, 0, 1, 2, 3, 4, 5, 6, 7);
        }
        #pragma unroll
        for (int m = 0; m < 4; m++)
            #pragma unroll
            for (int n = 0; n < 4; n++)
                acc[m][n] = __builtin_amdgcn_mfma_f32_16x16x32_bf16(af[m], bfv[n], acc[m][n], 0, 0, 0);
    }

    #pragma unroll
    for (int m = 0; m < 4; m++)
        #pragma unroll
        for (int n = 0; n < 4; n++)
            #pragma unroll
            for (int r = 0; r < 4; r++) {
                const int row = bm0 + wr * 64 + m * 16 + fg * 4 + r;
                const int col = bn0 + wc * 64 + n * 16 + fr;
                C[(size_t)row * N + col] = acc[m][n][r];
            }
}

// ---------------- bf16-input MFMA MoE GEMM (L2 value path) ----------------
// MODE 0: flat A | 1: gather-A via idx | 2: flat compacted A
// EPI  0: Cf = acc | 1: Cbf = bf16(silu(Cf)*acc) | 2: Cf += acc
template<int MODE, int EPI>
__global__ __launch_bounds__(256)
void k_mfma_moe_b(const short* __restrict__ A, const short* __restrict__ Bm,
                  float* __restrict__ Cf, short* __restrict__ Cbf,
                  const int* __restrict__ idx, const int* __restrict__ cnt,
                  const int* __restrict__ seg, int N, int K)
{
    int c = T_, s = 0;
    const int bm0 = blockIdx.y * 128, bn0 = blockIdx.x * 128;
    if (MODE >= 1) {
        const int e = blockIdx.z;
        c = cnt[e];
        if (bm0 >= c) return;
        s = seg[e];
        Bm += (size_t)e * N * K;
    }
    __shared__ short Als[128 * LDST];
    __shared__ short Bls[128 * LDST];
    const int tid  = threadIdx.x;
    const int lane = tid & 63, w = tid >> 6;
    const int wr = w >> 1, wc = w & 1;
    const int fr = lane & 15, fg = lane >> 4;
    const int srow = tid >> 1, sk = (tid & 1) * 16;

    int arow;
    if (MODE == 0)      arow = bm0 + srow;
    else if (MODE == 1) arow = idx[s + min(bm0 + srow, c - 1)];
    else                arow = s + min(bm0 + srow, c - 1);
    const short* pa = A  + (size_t)arow * K + sk;
    const short* pb = Bm + (size_t)(bn0 + srow) * K + sk;

    f32x4 acc[4][4];
    #pragma unroll
    for (int m = 0; m < 4; m++)
        #pragma unroll
        for (int n = 0; n < 4; n++) acc[m][n] = (f32x4){0.f, 0.f, 0.f, 0.f};

    s16x8 ra0 = *reinterpret_cast<const s16x8*>(pa);
    s16x8 ra1 = *reinterpret_cast<const s16x8*>(pa + 8);
    s16x8 rb0 = *reinterpret_cast<const s16x8*>(pb);
    s16x8 rb1 = *reinterpret_cast<const s16x8*>(pb + 8);

    for (int k0 = 0; k0 < K; k0 += 32) {
        __syncthreads();
        *reinterpret_cast<s16x8*>(&Als[srow * LDST + sk])     = ra0;
        *reinterpret_cast<s16x8*>(&Als[srow * LDST + sk + 8]) = ra1;
        *reinterpret_cast<s16x8*>(&Bls[srow * LDST + sk])     = rb0;
        *reinterpret_cast<s16x8*>(&Bls[srow * LDST + sk + 8]) = rb1;
        __syncthreads();
        if (k0 + 32 < K) {
            ra0 = *reinterpret_cast<const s16x8*>(pa + k0 + 32);
            ra1 = *reinterpret_cast<const s16x8*>(pa + k0 + 40);
            rb0 = *reinterpret_cast<const s16x8*>(pb + k0 + 32);
            rb1 = *reinterpret_cast<const s16x8*>(pb + k0 + 40);
        }
        s16x8 af[4], bfv[4];
        #pragma unroll
        for (int m = 0; m < 4; m++) {
            const int base = (wr * 64 + m * 16 + fr) * LDST + fg * 4;
            s16x4 lo = *reinterpret_cast<const s16x4*>(&Als[base]);
            s16x4 hi = *reinterpret_cast<const s16x4*>(&Als[base + 16]);
            af[m] = __builtin_shufflevector(lo, hi, 0, 1, 2, 3, 4, 5, 6, 7);
        }
        #pragma unroll
        for (int n = 0; n < 4; n++) {
            const int base = (wc * 64 + n * 16 + fr) * LDST + fg * 4;
            s16x4 lo = *reinterpret_cast<const s16x4*>(&Bls[base]);
            s16x4 hi = *reinterpret_cast<const s16x4*>(&Bls[base + 16]);
            bfv[n] = __builtin_shufflevector(lo, hi, 0, 1, 2, 3, 4, 5, 6, 7);
        }
        #pragma unroll
        for (int m = 0; m < 4; m++)
            #pragma unroll
            for (int n = 0; n < 4; n++)
                acc[m][n] = __builtin_amdgcn_mfma_f32_16x16x32_bf16(af[m], bfv[n], acc[m][n], 0, 0, 0);
    }

    #pragma unroll
    for (int m = 0; m < 4; m++)
        #pragma unroll
        for (int n = 0; n < 4; n++)
            #pragma unroll
            for (int r = 0; r < 4; r++) {
                const int row = bm0 + wr * 64 + m * 16 + fg * 4 + r;
                if (MODE >= 1 && row >= c) continue;
                const int col = bn0 + wc * 64 + n * 16 + fr;
                const size_t p = (size_t)((MODE >= 1 ? s : 0) + row) * N + col;
                if (EPI == 0)      Cf[p] = acc[m][n][r];
                else if (EPI == 1) {
                    const float gv = Cf[p];
                    Cbf[p] = f2bf(gv * (1.f / (1.f + expf(-gv))) * acc[m][n][r]);
                } else               Cf[p] += acc[m][n][r];
            }
}

// ---------------- split-bf16-input MFMA GEMM (L1, routing-safe) ----------------
// A = Ah+Al, B = Bh+Bl (pre-split planes); acc = Ah*Bh + Al*Bh + Ah*Bl
// EPI 0: Cf = acc | 1: (Chi,Clo) = split(silu(Cf)*acc) | 2: Cf += acc
template<int MODE, int EPI>
__global__ __launch_bounds__(256)
void k_mfma_sp_b(const short* __restrict__ Ah, const short* __restrict__ Alp,
                 const short* __restrict__ Bh, const short* __restrict__ Blp,
                 float* __restrict__ Cf, short* __restrict__ Chi, short* __restrict__ Clo,
                 const int* __restrict__ idx, const int* __restrict__ cnt,
                 const int* __restrict__ seg, int N, int K)
{
    int c = T_, s = 0;
    const int bm0 = blockIdx.y * 128, bn0 = blockIdx.x * 128;
    if (MODE >= 1) {
        const int e = blockIdx.z;
        c = cnt[e];
        if (bm0 >= c) return;
        s = seg[e];
        Bh  += (size_t)e * N * K;
        Blp += (size_t)e * N * K;
    }
    __shared__ short LAh[128 * LDST];
    __shared__ short LAl[128 * LDST];
    __shared__ short LBh[128 * LDST];
    __shared__ short LBl[128 * LDST];
    const int tid  = threadIdx.x;
    const int lane = tid & 63, w = tid >> 6;
    const int wr = w >> 1, wc = w & 1;
    const int fr = lane & 15, fg = lane >> 4;
    const int srow = tid >> 1, sk = (tid & 1) * 16;

    int arow;
    if (MODE == 0)      arow = bm0 + srow;
    else if (MODE == 1) arow = idx[s + min(bm0 + srow, c - 1)];
    else                arow = s + min(bm0 + srow, c - 1);
    const short* pah = Ah  + (size_t)arow * K + sk;
    const short* pal = Alp + (size_t)arow * K + sk;
    const short* pbh = Bh  + (size_t)(bn0 + srow) * K + sk;
    const short* pbl = Blp + (size_t)(bn0 + srow) * K + sk;

    f32x4 acc[4][4];
    #pragma unroll
    for (int m = 0; m < 4; m++)
        #pragma unroll
        for (int n = 0; n < 4; n++) acc[m][n] = (f32x4){0.f, 0.f, 0.f, 0.f};

    s16x8 rah0 = *reinterpret_cast<const s16x8*>(pah);
    s16x8 rah1 = *reinterpret_cast<const s16x8*>(pah + 8);
    s16x8 ral0 = *reinterpret_cast<const s16x8*>(pal);
    s16x8 ral1 = *reinterpret_cast<const s16x8*>(pal + 8);
    s16x8 rbh0 = *reinterpret_cast<const s16x8*>(pbh);
    s16x8 rbh1 = *reinterpret_cast<const s16x8*>(pbh + 8);
    s16x8 rbl0 = *reinterpret_cast<const s16x8*>(pbl);
    s16x8 rbl1 = *reinterpret_cast<const s16x8*>(pbl + 8);

    for (int k0 = 0; k0 < K; k0 += 32) {
        __syncthreads();
        *reinterpret_cast<s16x8*>(&LAh[srow * LDST + sk])     = rah0;
        *reinterpret_cast<s16x8*>(&LAh[srow * LDST + sk + 8]) = rah1;
        *reinterpret_cast<s16x8*>(&LAl[srow * LDST + sk])     = ral0;
        *reinterpret_cast<s16x8*>(&LAl[srow * LDST + sk + 8]) = ral1;
        *reinterpret_cast<s16x8*>(&LBh[srow * LDST + sk])     = rbh0;
        *reinterpret_cast<s16x8*>(&LBh[srow * LDST + sk + 8]) = rbh1;
        *reinterpret_cast<s16x8*>(&LBl[srow * LDST + sk])     = rbl0;
        *reinterpret_cast<s16x8*>(&LBl[srow * LDST + sk + 8]) = rbl1;
        __syncthreads();
        if (k0 + 32 < K) {
            rah0 = *reinterpret_cast<const s16x8*>(pah + k0 + 32);
            rah1 = *reinterpret_cast<const s16x8*>(pah + k0 + 40);
            ral0 = *reinterpret_cast<const s16x8*>(pal + k0 + 32);
            ral1 = *reinterpret_cast<const s16x8*>(pal + k0 + 40);
            rbh0 = *reinterpret_cast<const s16x8*>(pbh + k0 + 32);
            rbh1 = *reinterpret_cast<const s16x8*>(pbh + k0 + 40);
            rbl0 = *reinterpret_cast<const s16x8*>(pbl + k0 + 32);
            rbl1 = *reinterpret_cast<const s16x8*>(pbl + k0 + 40);
        }
        s16x8 afh[4], afl[4];
        #pragma unroll
        for (int m = 0; m < 4; m++) {
            const int base = (wr * 64 + m * 16 + fr) * LDST + fg * 4;
            s16x4 lo = *reinterpret_cast<const s16x4*>(&LAh[base]);
            s16x4 hi = *reinterpret_cast<const s16x4*>(&LAh[base + 16]);
            afh[m] = __builtin_shufflevector(lo, hi, 0, 1, 2, 3, 4, 5, 6, 7);
            lo = *reinterpret_cast<const s16x4*>(&LAl[base]);
            hi = *reinterpret_cast<const s16x4*>(&LAl[base + 16]);
            afl[m] = __builtin_shufflevector(lo, hi, 0, 1, 2, 3, 4, 5, 6, 7);
        }
        #pragma unroll
        for (int n = 0; n < 4; n++) {
            const int base = (wc * 64 + n * 16 + fr) * LDST + fg * 4;
            s16x4 lo = *reinterpret_cast<const s16x4*>(&LBh[base]);
            s16x4 hi = *reinterpret_cast<const s16x4*>(&LBh[base + 16]);
            s16x8 bh = __builtin_shufflevector(lo, hi, 0, 1, 2, 3, 4, 5, 6, 7);
            lo = *reinterpret_cast<const s16x4*>(&LBl[base]);
            hi = *reinterpret_cast<const s16x4*>(&LBl[base + 16]);
            s16x8 bl = __builtin_shufflevector(lo, hi, 0, 1, 2, 3, 4, 5, 6, 7);
            #pragma unroll
            for (int m = 0; m < 4; m++) {
                acc[m][n] = __builtin_amdgcn_mfma_f32_16x16x32_bf16(afh[m], bh, acc[m][n], 0, 0, 0);
                acc[m][n] = __builtin_amdgcn_mfma_f32_16x16x32_bf16(afl[m], bh, acc[m][n], 0, 0, 0);
                acc[m][n] = __builtin_amdgcn_mfma_f32_16x16x32_bf16(afh[m], bl, acc[m][n], 0, 0, 0);
            }
        }
    }

    #pragma unroll
    for (int m = 0; m < 4; m++)
        #pragma unroll
        for (int n = 0; n < 4; n++)
            #pragma unroll
            for (int r = 0; r < 4; r++) {
                const int row = bm0 + wr * 64 + m * 16 + fg * 4 + r;
                if (MODE >= 1 && row >= c) continue;
                const int col = bn0 + wc * 64 + n * 16 + fr;
                const size_t p = (size_t)((MODE >= 1 ? s : 0) + row) * N + col;
                if (EPI == 0)      Cf[p] = acc[m][n][r];
                else if (EPI == 1) {
                    const float gv = Cf[p];
                    const float pr = gv * (1.f / (1.f + expf(-gv))) * acc[m][n][r];
                    const short hh = f2bf(pr);
                    Chi[p] = hh;
                    Clo[p] = f2bf(pr - bf2f(hh));
                } else               Cf[p] += acc[m][n][r];
            }
}

#define GEMM(BL, EPI, A, Bw, CC, M, N, K) \
    k_gemm<BL, EPI><<<dim3((N)/128, (M)/128), 256, 0, stream>>>(A, Bw, CC, M, N, K)

extern "C" void kernel_launch(void* const* d_in, const int* in_sizes, int n_in,
                              void* d_out, int out_size, void* d_ws, size_t ws_size,
                              hipStream_t stream)
{
    const int*   ids    = (const int*)  d_in[0];
    const float* embed  = (const float*)d_in[1];
    const float* ln1_g  = (const float*)d_in[2];
    const float* ln1_b  = (const float*)d_in[3];
    const float* wq     = (const float*)d_in[4];
    const float* wk     = (const float*)d_in[5];
    const float* wv     = (const float*)d_in[6];
    const float* wo     = (const float*)d_in[7];
    const float* ln2_g  = (const float*)d_in[8];
    const float* ln2_b  = (const float*)d_in[9];
    const float* gate_w = (const float*)d_in[10];
    const float* exp_wg = (const float*)d_in[11];
    const float* exp_wu = (const float*)d_in[12];
    const float* exp_wd = (const float*)d_in[13];
    const float* sh_wg  = (const float*)d_in[14];
    const float* sh_wu  = (const float*)d_in[15];
    const float* sh_wd  = (const float*)d_in[16];
    const float* fn_g   = (const float*)d_in[17];
    const float* fn_b   = (const float*)d_in[18];
    const float* lm     = (const float*)d_in[19];
    float* out = (float*)d_out;

    float* x    = (float*)d_ws;                 // T*H
    float* h    = x + 2097152;                  // T*H
    float* qb   = h + 2097152;                  // R1: qb 2M, kv 1M, ob 2M (= 5,242,880)
    float* kv   = qb + 2097152;
    float* ob   = kv + 1048576;
    float* ebuf = qb;                           // CAP*H aliases R1 exactly
    float* gbuf = qb + 5242880;                 // CAP*I f32
    float* gw   = gbuf + 5242880;               // T*8
    float* wl   = gw + (size_t)T_ * E_;         // CAP
    int*   idx  = (int*)(wl + CAP_);            // CAP
    int*   pos  = idx + CAP_;                   // T*2
    int*   cnt  = pos + 2 * T_;                 // 8
    int*   seg  = cnt + E_;                     // 8
    // bf16 regions (shorts), 16B-aligned
    short* hhi  = (short*)(seg + 64);           // 2M
    short* hlo  = hhi + 2097152;                // 2M
    short* hbf  = hlo + 2097152;                // 2M
    short* gbh  = hbf + 2097152;                // CAP*I (ghi / gbuf_bf alias)
    short* gbl  = gbh + 5242880;                // CAP*I (glo)
    short* wb   = gbl + 5242880;                // 56,623,104 shorts, reused L1->L2->lm
    const size_t EW = (size_t)E_ * I_ * H_;     // 8,388,608

    k_embed<<<T_, 256, 0, stream>>>(ids, embed, x);

    for (int l = 0; l < L_; l++) {
        k_layernorm<<<T_, 256, 0, stream>>>(x, ln1_g + (size_t)l * H_, ln1_b + (size_t)l * H_, h);

        k_gemm_qkv<<<dim3(12, 16), 256, 0, stream>>>(
            h, wq + (size_t)l * H_ * H_, wk + (size_t)l * H_ * 256, wv + (size_t)l * H_ * 256, qb, kv);

        k_rope<<<(T_ * NH_  * 32) / 256, 256, 0, stream>>>(qb, 1024, NH_);
        k_rope<<<(T_ * NKV_ * 32) / 256, 256, 0, stream>>>(kv, 512,  NKV_);

        k_attn4<<<dim3(S_ / 64, NH_, B_), 256, 0, stream>>>(qb, kv, ob);

        GEMM(0, 2, ob, wo + (size_t)l * H_ * H_, x, T_, H_, H_);

        k_layernorm<<<T_, 256, 0, stream>>>(x, ln2_g + (size_t)l * H_, ln2_b + (size_t)l * H_, h);
        k_gate<<<T_, 64, 0, stream>>>(h, gate_w + (size_t)l * E_ * H_, gw);
        k_build<<<1, 512, 0, stream>>>(gw, idx, wl, pos, cnt, seg);

        const float* wg_l = exp_wg + (size_t)l * EW;
        const float* wu_l = exp_wu + (size_t)l * EW;
        const float* wd_l = exp_wd + (size_t)l * EW;
        const float* sg_l = sh_wg + (size_t)l * I_ * H_;
        const float* su_l = sh_wu + (size_t)l * I_ * H_;
        const float* sd_l = sh_wd + (size_t)l * H_ * I_;

        if (l == 0) {   // routing-critical layer: pre-split weights + activations, 3-term MFMA
            short* wgh = wb;            short* wgl = wb + EW;
            short* wuh = wb + 2 * EW;   short* wul = wb + 3 * EW;
            short* wdh = wb + 4 * EW;   short* wdl = wb + 5 * EW;
            short* sgh = wb + 6 * EW;   short* sgl = sgh + 1048576;
            short* suh = sgl + 1048576; short* sul = suh + 1048576;
            short* sdh = sul + 1048576; short* sdl = sdh + 1048576;

            k_cvt_sp<<<4096, 256, 0, stream>>>(wg_l, wgh, wgl, (int)(EW / 8));
            k_cvt_sp<<<4096, 256, 0, stream>>>(wu_l, wuh, wul, (int)(EW / 8));
            k_cvt_sp<<<4096, 256, 0, stream>>>(wd_l, wdh, wdl, (int)(EW / 8));
            k_cvt_sp<<<512,  256, 0, stream>>>(sg_l, sgh, sgl, 131072);
            k_cvt_sp<<<512,  256, 0, stream>>>(su_l, suh, sul, 131072);
            k_cvt_sp<<<512,  256, 0, stream>>>(sd_l, sdh, sdl, 131072);
            k_cvt_sp<<<1024, 256, 0, stream>>>(h, hhi, hlo, 262144);

            // shared expert
            k_mfma_sp_b<0, 0><<<dim3(8, 16, 1), 256, 0, stream>>>(hhi, hlo, sgh, sgl, gbuf, nullptr, nullptr, nullptr, nullptr, nullptr, I_, H_);
            k_mfma_sp_b<0, 1><<<dim3(8, 16, 1), 256, 0, stream>>>(hhi, hlo, suh, sul, gbuf, gbh, gbl, nullptr, nullptr, nullptr, I_, H_);
            k_mfma_sp_b<0, 2><<<dim3(8, 16, 1), 256, 0, stream>>>(gbh, gbl, sdh, sdl, x, nullptr, nullptr, nullptr, nullptr, nullptr, H_, I_);
            // routed experts
            k_mfma_sp_b<1, 0><<<dim3(8, 16, E_), 256, 0, stream>>>(hhi, hlo, wgh, wgl, gbuf, nullptr, nullptr, idx, cnt, seg, I_, H_);
            k_mfma_sp_b<1, 1><<<dim3(8, 16, E_), 256, 0, stream>>>(hhi, hlo, wuh, wul, gbuf, gbh, gbl, idx, cnt, seg, I_, H_);
            k_mfma_sp_b<2, 0><<<dim3(8, 16, E_), 256, 0, stream>>>(gbh, gbl, wdh, wdl, ebuf, nullptr, nullptr, idx, cnt, seg, H_, I_);
        } else {        // last layer value path: plain bf16 MFMA on pre-converted weights
            short* wgb = wb;            short* wub = wb + EW;       short* wdb = wb + 2 * EW;
            short* sgb = wb + 3 * EW;   short* sub = sgb + 1048576; short* sdb = sub + 1048576;

            k_cvt<<<4096, 256, 0, stream>>>(wg_l, wgb, (int)(EW / 8));
            k_cvt<<<4096, 256, 0, stream>>>(wu_l, wub, (int)(EW / 8));
            k_cvt<<<4096, 256, 0, stream>>>(wd_l, wdb, (int)(EW / 8));
            k_cvt<<<512,  256, 0, stream>>>(sg_l, sgb, 131072);
            k_cvt<<<512,  256, 0, stream>>>(su_l, sub, 131072);
            k_cvt<<<512,  256, 0, stream>>>(sd_l, sdb, 131072);
            k_cvt<<<1024, 256, 0, stream>>>(h, hbf, 262144);

            k_mfma_moe_b<0, 0><<<dim3(8, 16, 1), 256, 0, stream>>>(hbf, sgb, gbuf, nullptr, nullptr, nullptr, nullptr, I_, H_);
            k_mfma_moe_b<0, 1><<<dim3(8, 16, 1), 256, 0, stream>>>(hbf, sub, gbuf, gbh, nullptr, nullptr, nullptr, I_, H_);
            k_mfma_moe_b<0, 2><<<dim3(8, 16, 1), 256, 0, stream>>>(gbh, sdb, x, nullptr, nullptr, nullptr, nullptr, H_, I_);
            k_mfma_moe_b<1, 0><<<dim3(8, 16, E_), 256, 0, stream>>>(hbf, wgb, gbuf, nullptr, idx, cnt, seg, I_, H_);
            k_mfma_moe_b<1, 1><<<dim3(8, 16, E_), 256, 0, stream>>>(hbf, wub, gbuf, gbh, idx, cnt, seg, I_, H_);
            k_mfma_moe_b<2, 0><<<dim3(8, 16, E_), 256, 0, stream>>>(gbh, wdb, ebuf, nullptr, idx, cnt, seg, H_, I_);
        }
        k_combine<<<(T_ * H_) / 256, 256, 0, stream>>>(x, ebuf, wl, pos);
    }

    k_layernorm<<<T_, 256, 0, stream>>>(x, fn_g, fn_b, h);
    k_cvt<<<1024,  256, 0, stream>>>(h, hbf, 262144);
    k_cvt<<<16000, 256, 0, stream>>>(lm, wb, 4096000);
    k_mfma_bt_b<<<(T_ / 128) * (V_ / 128), 256, 0, stream>>>(hbf, wb, out, T_, V_, H_);
}

// Round 10
// 2162.260 us; speedup vs baseline: 5.5372x; 1.1367x over previous
//
#include <hip/hip_runtime.h>
#include <cmath>

#define L_   2
#define E_   8
#define NH_  16
#define NKV_ 4
#define HD_  64
#define H_   1024
#define I_   1024
#define B_   2
#define S_   1024
#define T_   (B_*S_)
#define V_   32000
#define CAP_ 5120
#define LDST 36   // LDS row stride in shorts for GEMM tiles (conflict-free)
#define AST  72   // LDS row stride in shorts for attention tiles

typedef float f32x4 __attribute__((ext_vector_type(4)));
typedef short s16x4 __attribute__((ext_vector_type(4)));
typedef short s16x8 __attribute__((ext_vector_type(8)));

__device__ __forceinline__ short f2bf(float f) {
    unsigned u = __float_as_uint(f);
    u = (u + 0x7fffu + ((u >> 16) & 1u)) >> 16;   // RNE
    return (short)u;
}
__device__ __forceinline__ float bf2f(short h) {
    return __uint_as_float(((unsigned)(unsigned short)h) << 16);
}
__device__ __forceinline__ s16x8 ldfrag(const short* p) {
    s16x4 lo = *reinterpret_cast<const s16x4*>(p);
    s16x4 hi = *reinterpret_cast<const s16x4*>(p + 16);
    return __builtin_shufflevector(lo, hi, 0, 1, 2, 3, 4, 5, 6, 7);
}

// ---------------- converters ----------------
__global__ __launch_bounds__(256)
void k_cvt(const float* __restrict__ s, short* __restrict__ d, int n8)
{
    const int i = blockIdx.x * 256 + threadIdx.x;
    if (i >= n8) return;
    const float4 a = *reinterpret_cast<const float4*>(s + (size_t)i * 8);
    const float4 b = *reinterpret_cast<const float4*>(s + (size_t)i * 8 + 4);
    s16x8 o;
    o[0]=f2bf(a.x); o[1]=f2bf(a.y); o[2]=f2bf(a.z); o[3]=f2bf(a.w);
    o[4]=f2bf(b.x); o[5]=f2bf(b.y); o[6]=f2bf(b.z); o[7]=f2bf(b.w);
    *reinterpret_cast<s16x8*>(d + (size_t)i * 8) = o;
}

__global__ __launch_bounds__(256)
void k_cvt_sp(const float* __restrict__ s, short* __restrict__ dh, short* __restrict__ dl, int n8)
{
    const int i = blockIdx.x * 256 + threadIdx.x;
    if (i >= n8) return;
    const float4 a = *reinterpret_cast<const float4*>(s + (size_t)i * 8);
    const float4 b = *reinterpret_cast<const float4*>(s + (size_t)i * 8 + 4);
    float v[8] = {a.x, a.y, a.z, a.w, b.x, b.y, b.z, b.w};
    s16x8 oh, ol;
    #pragma unroll
    for (int j = 0; j < 8; j++) {
        const short hh = f2bf(v[j]);
        oh[j] = hh;
        ol[j] = f2bf(v[j] - bf2f(hh));
    }
    *reinterpret_cast<s16x8*>(dh + (size_t)i * 8) = oh;
    *reinterpret_cast<s16x8*>(dl + (size_t)i * 8) = ol;
}

// ---------------- K/V -> split bf16 (K row-major, V transposed) ----------------
// kv: [T][512] f32 ([K|V] per token). khi/klo: [B*NKV][S][64]. vth/vtl: [B*NKV][64][S].
__global__ __launch_bounds__(256)
void k_cvt_kv(const float* __restrict__ kv,
              short* __restrict__ khi, short* __restrict__ klo,
              short* __restrict__ vth, short* __restrict__ vtl)
{
    const int blk = blockIdx.x;              // B*NKV*(S/64) = 128
    const int s0  = (blk & 15) * 64;
    const int kvh = (blk >> 4) & 3;
    const int b   = blk >> 6;
    const int tid = threadIdx.x;
    const int r = tid >> 2, c0 = (tid & 3) * 16;
    __shared__ float Vt[64][65];

    const float* kp = kv + (size_t)(b * S_ + s0 + r) * 512 + kvh * 64 + c0;
    const size_t ko = ((size_t)(b * 4 + kvh) * S_ + s0 + r) * 64 + c0;
    #pragma unroll
    for (int g = 0; g < 2; g++) {
        const float4 a = *reinterpret_cast<const float4*>(kp + g * 8);
        const float4 bq = *reinterpret_cast<const float4*>(kp + g * 8 + 4);
        float v[8] = {a.x, a.y, a.z, a.w, bq.x, bq.y, bq.z, bq.w};
        s16x8 oh, ol;
        #pragma unroll
        for (int j = 0; j < 8; j++) {
            const short hh = f2bf(v[j]);
            oh[j] = hh; ol[j] = f2bf(v[j] - bf2f(hh));
        }
        *reinterpret_cast<s16x8*>(khi + ko + g * 8) = oh;
        *reinterpret_cast<s16x8*>(klo + ko + g * 8) = ol;
    }
    // V tile into LDS transposed: Vt[d][s_local]
    const float* vp = kp + 256;
    #pragma unroll
    for (int g = 0; g < 4; g++) {
        const float4 a = *reinterpret_cast<const float4*>(vp + g * 4);
        Vt[c0 + g*4 + 0][r] = a.x; Vt[c0 + g*4 + 1][r] = a.y;
        Vt[c0 + g*4 + 2][r] = a.z; Vt[c0 + g*4 + 3][r] = a.w;
    }
    __syncthreads();
    const size_t vo = ((size_t)(b * 4 + kvh) * 64 + r) * S_ + s0 + c0;
    #pragma unroll
    for (int g = 0; g < 2; g++) {
        s16x8 oh, ol;
        #pragma unroll
        for (int j = 0; j < 8; j++) {
            const float v = Vt[r][c0 + g * 8 + j];
            const short hh = f2bf(v);
            oh[j] = hh; ol[j] = f2bf(v - bf2f(hh));
        }
        *reinterpret_cast<s16x8*>(vth + vo + g * 8) = oh;
        *reinterpret_cast<s16x8*>(vtl + vo + g * 8) = ol;
    }
}

// ---------------- embedding ----------------
__global__ void k_embed(const int* __restrict__ ids, const float* __restrict__ emb,
                        float* __restrict__ x)
{
    const int t = blockIdx.x;
    const float* src = emb + (size_t)ids[t] * H_;
    float* dst = x + (size_t)t * H_;
    for (int i = threadIdx.x; i < H_; i += 256) dst[i] = src[i];
}

// ---------------- layernorm ----------------
__global__ __launch_bounds__(256)
void k_layernorm(const float* __restrict__ x, const float* __restrict__ g,
                 const float* __restrict__ bb, float* __restrict__ out)
{
    const int t = blockIdx.x;
    const float* row = x + (size_t)t * H_;
    float s = 0.f, ss = 0.f;
    for (int i = threadIdx.x; i < H_; i += 256) { const float v = row[i]; s += v; ss += v * v; }
    #pragma unroll
    for (int off = 32; off > 0; off >>= 1) {
        s  += __shfl_down(s, off, 64);
        ss += __shfl_down(ss, off, 64);
    }
    __shared__ float shs[4], shss[4];
    const int w = threadIdx.x >> 6;
    if ((threadIdx.x & 63) == 0) { shs[w] = s; shss[w] = ss; }
    __syncthreads();
    const float fs  = shs[0] + shs[1] + shs[2] + shs[3];
    const float fss = shss[0] + shss[1] + shss[2] + shss[3];
    const float mean = fs * (1.f / H_);
    const float var  = fss * (1.f / H_) - mean * mean;
    const float rstd = 1.0f / sqrtf(var + 1e-5f);
    float* orow = out + (size_t)t * H_;
    for (int i = threadIdx.x; i < H_; i += 256)
        orow[i] = (row[i] - mean) * rstd * g[i] + bb[i];
}

// ---------------- RoPE ----------------
__global__ void k_rope(float* __restrict__ x, int rowStride, int nheads)
{
    const int idx  = blockIdx.x * 256 + threadIdx.x;
    const int i    = idx & 31;
    const int rest = idx >> 5;
    const int head = rest % nheads;
    const int t    = rest / nheads;
    const int pos  = t & (S_ - 1);
    const float p32  = (float)pow(1.0e6, (double)i / 32.0);
    const float invf = 1.0f / p32;
    const float ang  = (float)pos * invf;
    const float c = (float)cos((double)ang);
    const float s = (float)sin((double)ang);
    float* base = x + (size_t)t * rowStride + head * HD_;
    const float x1 = base[i];
    const float x2 = base[i + 32];
    base[i]      = x1 * c - x2 * s;
    base[i + 32] = x2 * c + x1 * s;
}

// ---------------- split-bf16 MFMA flash attention ----------------
// grid (S/64, NH, B), block 256 = 4 waves; wave w owns q-rows w*16..w*16+15.
// S = Q@K^T via (Qh+Ql)(Kh+Kl) 3-term; no-max softmax; O = P@V via 3-term.
__global__ __launch_bounds__(256)
void k_attn_mfma(const float* __restrict__ q,
                 const short* __restrict__ khi, const short* __restrict__ klo,
                 const short* __restrict__ vth, const short* __restrict__ vtl,
                 float* __restrict__ o)
{
    const int q0 = blockIdx.x * 64, h = blockIdx.y, b = blockIdx.z;
    const int kvh = h >> 2;
    const int tid = threadIdx.x, lane = tid & 63, w = tid >> 6;
    const int fr = lane & 15, fg = lane >> 4;

    __shared__ short Qh[64 * AST], Ql[64 * AST];
    __shared__ short Kh[64 * AST], Kl[64 * AST];
    __shared__ short Vh[64 * AST], Vl[64 * AST];
    __shared__ short Ph[64 * AST], Pl[64 * AST];

    {   // stage Q (scaled 0.125, split)
        const int r = tid >> 2, c0 = (tid & 3) * 16;
        const float* qs = q + (size_t)(b * S_ + q0 + r) * H_ + h * HD_ + c0;
        #pragma unroll
        for (int g = 0; g < 2; g++) {
            const float4 a = *reinterpret_cast<const float4*>(qs + g * 8);
            const float4 bq = *reinterpret_cast<const float4*>(qs + g * 8 + 4);
            float v[8] = {a.x, a.y, a.z, a.w, bq.x, bq.y, bq.z, bq.w};
            s16x8 oh, ol;
            #pragma unroll
            for (int j = 0; j < 8; j++) {
                const float sv = v[j] * 0.125f;
                const short hh = f2bf(sv);
                oh[j] = hh; ol[j] = f2bf(sv - bf2f(hh));
            }
            *reinterpret_cast<s16x8*>(&Qh[r * AST + c0 + g * 8]) = oh;
            *reinterpret_cast<s16x8*>(&Ql[r * AST + c0 + g * 8]) = ol;
        }
    }

    f32x4 accO[4];
    #pragma unroll
    for (int n = 0; n < 4; n++) accO[n] = (f32x4){0.f, 0.f, 0.f, 0.f};
    float rs[4] = {0.f, 0.f, 0.f, 0.f};

    const size_t kbase = (size_t)(b * 4 + kvh) * S_ * 64;
    const size_t vbase = (size_t)(b * 4 + kvh) * 64 * S_;
    const int nkb = (q0 >> 6) + 1;

    for (int kb = 0; kb < nkb; kb++) {
        const int j0 = kb * 64;
        __syncthreads();   // prev PV done (and Q visible on first iter)
        {   // stage K [key][d] and VT [d][key] tiles (pure copies)
            const int r = tid >> 2, c0 = (tid & 3) * 16;
            const short* ks = khi + kbase + (size_t)(j0 + r) * 64 + c0;
            const short* ls = klo + kbase + (size_t)(j0 + r) * 64 + c0;
            *reinterpret_cast<s16x8*>(&Kh[r * AST + c0])     = *reinterpret_cast<const s16x8*>(ks);
            *reinterpret_cast<s16x8*>(&Kh[r * AST + c0 + 8]) = *reinterpret_cast<const s16x8*>(ks + 8);
            *reinterpret_cast<s16x8*>(&Kl[r * AST + c0])     = *reinterpret_cast<const s16x8*>(ls);
            *reinterpret_cast<s16x8*>(&Kl[r * AST + c0 + 8]) = *reinterpret_cast<const s16x8*>(ls + 8);
            const short* vs = vth + vbase + (size_t)r * S_ + j0 + c0;
            const short* vl = vtl + vbase + (size_t)r * S_ + j0 + c0;
            *reinterpret_cast<s16x8*>(&Vh[r * AST + c0])     = *reinterpret_cast<const s16x8*>(vs);
            *reinterpret_cast<s16x8*>(&Vh[r * AST + c0 + 8]) = *reinterpret_cast<const s16x8*>(vs + 8);
            *reinterpret_cast<s16x8*>(&Vl[r * AST + c0])     = *reinterpret_cast<const s16x8*>(vl);
            *reinterpret_cast<s16x8*>(&Vl[r * AST + c0 + 8]) = *reinterpret_cast<const s16x8*>(vl + 8);
        }
        __syncthreads();

        // QK^T (3-term split)
        f32x4 accS[4];
        #pragma unroll
        for (int n = 0; n < 4; n++) accS[n] = (f32x4){0.f, 0.f, 0.f, 0.f};
        #pragma unroll
        for (int ks2 = 0; ks2 < 2; ks2++) {
            const int ko = ks2 * 32 + fg * 4;
            const s16x8 ah = ldfrag(&Qh[(w * 16 + fr) * AST + ko]);
            const s16x8 al = ldfrag(&Ql[(w * 16 + fr) * AST + ko]);
            #pragma unroll
            for (int n = 0; n < 4; n++) {
                const int base = (n * 16 + fr) * AST + ko;
                const s16x8 bh = ldfrag(&Kh[base]);
                const s16x8 bl = ldfrag(&Kl[base]);
                accS[n] = __builtin_amdgcn_mfma_f32_16x16x32_bf16(ah, bh, accS[n], 0, 0, 0);
                accS[n] = __builtin_amdgcn_mfma_f32_16x16x32_bf16(al, bh, accS[n], 0, 0, 0);
                accS[n] = __builtin_amdgcn_mfma_f32_16x16x32_bf16(ah, bl, accS[n], 0, 0, 0);
            }
        }

        // softmax partial + P split store
        #pragma unroll
        for (int r = 0; r < 4; r++) {
            const int qrow = q0 + w * 16 + fg * 4 + r;
            float ev[4];
            float p = 0.f;
            #pragma unroll
            for (int n = 0; n < 4; n++) {
                const int key = j0 + n * 16 + fr;
                const float e = (key <= qrow) ? expf(accS[n][r]) : 0.f;
                ev[n] = e; p += e;
            }
            p += __shfl_xor(p, 1, 64); p += __shfl_xor(p, 2, 64);
            p += __shfl_xor(p, 4, 64); p += __shfl_xor(p, 8, 64);
            rs[r] += p;
            #pragma unroll
            for (int n = 0; n < 4; n++) {
                const int addr = (w * 16 + fg * 4 + r) * AST + n * 16 + fr;
                const short hh = f2bf(ev[n]);
                Ph[addr] = hh;
                Pl[addr] = f2bf(ev[n] - bf2f(hh));
            }
        }
        __builtin_amdgcn_wave_barrier();   // P rows are wave-private; in-order LDS per wave

        // PV (3-term split), accumulate O
        #pragma unroll
        for (int ks2 = 0; ks2 < 2; ks2++) {
            const int ko = ks2 * 32 + fg * 4;
            const s16x8 ph = ldfrag(&Ph[(w * 16 + fr) * AST + ko]);
            const s16x8 pl = ldfrag(&Pl[(w * 16 + fr) * AST + ko]);
            #pragma unroll
            for (int n = 0; n < 4; n++) {
                const int base = (n * 16 + fr) * AST + ko;
                const s16x8 vh = ldfrag(&Vh[base]);
                const s16x8 vl = ldfrag(&Vl[base]);
                accO[n] = __builtin_amdgcn_mfma_f32_16x16x32_bf16(ph, vh, accO[n], 0, 0, 0);
                accO[n] = __builtin_amdgcn_mfma_f32_16x16x32_bf16(pl, vh, accO[n], 0, 0, 0);
                accO[n] = __builtin_amdgcn_mfma_f32_16x16x32_bf16(ph, vl, accO[n], 0, 0, 0);
            }
        }
    }

    // O write
    #pragma unroll
    for (int r = 0; r < 4; r++) {
        const float inv = 1.0f / rs[r];
        const int qrow = q0 + w * 16 + fg * 4 + r;
        float* od = o + (size_t)(b * S_ + qrow) * H_ + h * HD_;
        #pragma unroll
        for (int n = 0; n < 4; n++) od[n * 16 + fr] = accO[n][r] * inv;
    }
}

// ---------------- MoE gate ----------------
__global__ __launch_bounds__(64)
void k_gate(const float* __restrict__ h, const float* __restrict__ gwt, float* __restrict__ w)
{
    const int t = blockIdx.x;
    const int lane = threadIdx.x;
    const float* row = h + (size_t)t * H_;
    float acc[E_];
    #pragma unroll
    for (int e = 0; e < E_; e++) acc[e] = 0.f;
    for (int i = lane; i < H_; i += 64) {
        const float xv = row[i];
        #pragma unroll
        for (int e = 0; e < E_; e++) acc[e] += xv * gwt[(size_t)e * H_ + i];
    }
    #pragma unroll
    for (int e = 0; e < E_; e++) {
        #pragma unroll
        for (int off = 32; off > 0; off >>= 1) acc[e] += __shfl_down(acc[e], off, 64);
    }
    if (lane == 0) {
        int i1 = 0; float m1 = acc[0];
        #pragma unroll
        for (int e = 1; e < E_; e++) if (acc[e] > m1) { m1 = acc[e]; i1 = e; }
        int i2 = -1; float m2 = -1e30f;
        #pragma unroll
        for (int e = 0; e < E_; e++) if (e != i1 && acc[e] > m2) { m2 = acc[e]; i2 = e; }
        const float e2  = expf(m2 - m1);
        const float den = 1.0f + e2;
        #pragma unroll
        for (int e = 0; e < E_; e++)
            w[t * E_ + e] = (e == i1) ? (1.0f / den) : ((e == i2) ? (e2 / den) : 0.f);
    }
}

// ---------------- build per-expert token lists ----------------
__global__ __launch_bounds__(512)
void k_build(const float* __restrict__ gw, int* __restrict__ idx, float* __restrict__ wl,
             int* __restrict__ pos, int* __restrict__ cnt, int* __restrict__ seg)
{
    const int e = threadIdx.x >> 6;
    const int lane = threadIdx.x & 63;
    __shared__ int scnt[E_], sseg[E_];
    int c = 0;
    for (int t0 = 0; t0 < T_; t0 += 64) {
        const float v = gw[(size_t)(t0 + lane) * E_ + e];
        c += __popcll(__ballot(v > 0.f));
    }
    if (lane == 0) scnt[e] = c;
    __syncthreads();
    if (threadIdx.x == 0) {
        int off = 0;
        for (int q = 0; q < E_; q++) {
            sseg[q] = off; cnt[q] = scnt[q]; seg[q] = off;
            off += (scnt[q] + 127) & ~127;
        }
    }
    __syncthreads();
    int p = sseg[e];
    for (int t0 = 0; t0 < T_; t0 += 64) {
        const int t = t0 + lane;
        const float v = gw[(size_t)t * E_ + e];
        const unsigned long long m = __ballot(v > 0.f);
        if (v > 0.f) {
            const int pp = p + __popcll(m & ((1ull << lane) - 1ull));
            idx[pp] = t; wl[pp] = v;
            int slot = 0;
            for (int q = 0; q < e; q++) slot += (gw[(size_t)t * E_ + q] > 0.f) ? 1 : 0;
            pos[t * 2 + slot] = pp;
        }
        p += __popcll(m);
    }
}

// ---------------- combine ----------------
__global__ void k_combine(float* __restrict__ x, const float* __restrict__ ebuf,
                          const float* __restrict__ wl, const int* __restrict__ pos)
{
    const int id = blockIdx.x * 256 + threadIdx.x;
    const int t = id >> 10;
    const int hc = id & 1023;
    const int p0 = pos[t * 2], p1 = pos[t * 2 + 1];
    x[id] += wl[p0] * ebuf[(size_t)p0 * H_ + hc] + wl[p1] * ebuf[(size_t)p1 * H_ + hc];
}

// ---------------- f32 SIMT GEMM (wo projection) ----------------
template<int BL, int EPI>
__global__ __launch_bounds__(256, 2)
void k_gemm(const float* __restrict__ A, const float* __restrict__ B,
            float* __restrict__ C, int M, int N, int K)
{
    __shared__ float As[128][20];
    __shared__ float Bs[16][132];
    const int tid = threadIdx.x;
    const int bm0 = blockIdx.y * 128, bn0 = blockIdx.x * 128;
    const int tx = tid & 15, ty = tid >> 4;
    float acc[8][8];
    #pragma unroll
    for (int i = 0; i < 8; i++)
        #pragma unroll
        for (int j = 0; j < 8; j++) acc[i][j] = 0.f;
    const int ra = tid >> 1, ca = (tid & 1) * 8;
    for (int k0 = 0; k0 < K; k0 += 16) {
        __syncthreads();
        {
            const float* src = A + (size_t)(bm0 + ra) * K + (k0 + ca);
            *reinterpret_cast<float4*>(&As[ra][ca])     = *reinterpret_cast<const float4*>(src);
            *reinterpret_cast<float4*>(&As[ra][ca + 4]) = *reinterpret_cast<const float4*>(src + 4);
        }
        if (BL == 0) {
            const int kb = tid >> 4, n8 = (tid & 15) * 8;
            const float* src = B + (size_t)(k0 + kb) * N + (bn0 + n8);
            *reinterpret_cast<float4*>(&Bs[kb][n8])     = *reinterpret_cast<const float4*>(src);
            *reinterpret_cast<float4*>(&Bs[kb][n8 + 4]) = *reinterpret_cast<const float4*>(src + 4);
        } else {
            const float* src = B + (size_t)(bn0 + ra) * K + (k0 + ca);
            float4 r0 = *reinterpret_cast<const float4*>(src);
            float4 r1 = *reinterpret_cast<const float4*>(src + 4);
            Bs[ca + 0][ra] = r0.x; Bs[ca + 1][ra] = r0.y;
            Bs[ca + 2][ra] = r0.z; Bs[ca + 3][ra] = r0.w;
            Bs[ca + 4][ra] = r1.x; Bs[ca + 5][ra] = r1.y;
            Bs[ca + 6][ra] = r1.z; Bs[ca + 7][ra] = r1.w;
        }
        __syncthreads();
        #pragma unroll
        for (int kkx = 0; kkx < 16; kkx++) {
            float a[8], b[8];
            #pragma unroll
            for (int i = 0; i < 4; i++) {
                a[i]     = As[ty * 4 + i][kkx];
                a[4 + i] = As[64 + ty * 4 + i][kkx];
            }
            const float4 b0 = *reinterpret_cast<const float4*>(&Bs[kkx][tx * 4]);
            const float4 b1 = *reinterpret_cast<const float4*>(&Bs[kkx][64 + tx * 4]);
            b[0] = b0.x; b[1] = b0.y; b[2] = b0.z; b[3] = b0.w;
            b[4] = b1.x; b[5] = b1.y; b[6] = b1.z; b[7] = b1.w;
            #pragma unroll
            for (int i = 0; i < 8; i++)
                #pragma unroll
                for (int j = 0; j < 8; j++) acc[i][j] += a[i] * b[j];
        }
    }
    #pragma unroll
    for (int i = 0; i < 8; i++) {
        const int row = bm0 + (i & 3) + ((i >> 2) * 64) + ty * 4;
        #pragma unroll
        for (int j = 0; j < 8; j++) {
            const int col = bn0 + (j & 3) + ((j >> 2) * 64) + tx * 4;
            const size_t p = (size_t)row * N + col;
            if (EPI == 0)      C[p] = acc[i][j];
            else if (EPI == 2) C[p] += acc[i][j];
        }
    }
}

// ---------------- fused q/k/v GEMM (f32) ----------------
__global__ __launch_bounds__(256, 2)
void k_gemm_qkv(const float* __restrict__ A, const float* __restrict__ Bq,
                const float* __restrict__ Bk, const float* __restrict__ Bv,
                float* __restrict__ Cq, float* __restrict__ Ckv)
{
    const int bn0 = blockIdx.x * 128, bm0 = blockIdx.y * 128;
    const float* B; float* C; int ldb, ldc, bcol, ccol;
    if (bn0 < 1024)      { B = Bq; ldb = 1024; bcol = bn0;        C = Cq;  ldc = 1024; ccol = bn0; }
    else if (bn0 < 1280) { B = Bk; ldb = 256;  bcol = bn0 - 1024; C = Ckv; ldc = 512;  ccol = bn0 - 1024; }
    else                 { B = Bv; ldb = 256;  bcol = bn0 - 1280; C = Ckv; ldc = 512;  ccol = bn0 - 1024; }

    __shared__ float As[128][20];
    __shared__ float Bs[16][132];
    const int tid = threadIdx.x;
    const int tx = tid & 15, ty = tid >> 4;
    float acc[8][8];
    #pragma unroll
    for (int i = 0; i < 8; i++)
        #pragma unroll
        for (int j = 0; j < 8; j++) acc[i][j] = 0.f;
    const int ra = tid >> 1, ca = (tid & 1) * 8;
    for (int k0 = 0; k0 < H_; k0 += 16) {
        __syncthreads();
        {
            const float* src = A + (size_t)(bm0 + ra) * H_ + (k0 + ca);
            *reinterpret_cast<float4*>(&As[ra][ca])     = *reinterpret_cast<const float4*>(src);
            *reinterpret_cast<float4*>(&As[ra][ca + 4]) = *reinterpret_cast<const float4*>(src + 4);
        }
        {
            const int kb = tid >> 4, n8 = (tid & 15) * 8;
            const float* src = B + (size_t)(k0 + kb) * ldb + (bcol + n8);
            *reinterpret_cast<float4*>(&Bs[kb][n8])     = *reinterpret_cast<const float4*>(src);
            *reinterpret_cast<float4*>(&Bs[kb][n8 + 4]) = *reinterpret_cast<const float4*>(src + 4);
        }
        __syncthreads();
        #pragma unroll
        for (int kkx = 0; kkx < 16; kkx++) {
            float a[8], b[8];
            #pragma unroll
            for (int i = 0; i < 4; i++) {
                a[i]     = As[ty * 4 + i][kkx];
                a[4 + i] = As[64 + ty * 4 + i][kkx];
            }
            const float4 b0 = *reinterpret_cast<const float4*>(&Bs[kkx][tx * 4]);
            const float4 b1 = *reinterpret_cast<const float4*>(&Bs[kkx][64 + tx * 4]);
            b[0] = b0.x; b[1] = b0.y; b[2] = b0.z; b[3] = b0.w;
            b[4] = b1.x; b[5] = b1.y; b[6] = b1.z; b[7] = b1.w;
            #pragma unroll
            for (int i = 0; i < 8; i++)
                #pragma unroll
                for (int j = 0; j < 8; j++) acc[i][j] += a[i] * b[j];
        }
    }
    #pragma unroll
    for (int i = 0; i < 8; i++) {
        const int row = bm0 + (i & 3) + ((i >> 2) * 64) + ty * 4;
        #pragma unroll
        for (int j = 0; j < 8; j++) {
            const int col = ccol + (j & 3) + ((j >> 2) * 64) + tx * 4;
            C[(size_t)row * ldc + col] = acc[i][j];
        }
    }
}

// ---------------- bf16-input MFMA GEMM (lm_head) ----------------
__global__ __launch_bounds__(256)
void k_mfma_bt_b(const short* __restrict__ A, const short* __restrict__ Bm,
                 float* __restrict__ C, int M, int N, int K)
{
    __shared__ short Als[128 * LDST];
    __shared__ short Bls[128 * LDST];
    const int mB = M >> 7;
    const int l  = blockIdx.x;
    const int g  = l / (mB * 8);
    const int ii = l - g * (mB * 8);
    const int bm0 = (ii % mB) * 128;
    const int bn0 = (g * 8 + ii / mB) * 128;

    const int tid  = threadIdx.x;
    const int lane = tid & 63, w = tid >> 6;
    const int wr = w >> 1, wc = w & 1;
    const int fr = lane & 15, fg = lane >> 4;
    const int srow = tid >> 1, sk = (tid & 1) * 16;

    const short* pa = A  + (size_t)(bm0 + srow) * K + sk;
    const short* pb = Bm + (size_t)(bn0 + srow) * K + sk;

    f32x4 acc[4][4];
    #pragma unroll
    for (int m = 0; m < 4; m++)
        #pragma unroll
        for (int n = 0; n < 4; n++) acc[m][n] = (f32x4){0.f, 0.f, 0.f, 0.f};

    s16x8 ra0 = *reinterpret_cast<const s16x8*>(pa);
    s16x8 ra1 = *reinterpret_cast<const s16x8*>(pa + 8);
    s16x8 rb0 = *reinterpret_cast<const s16x8*>(pb);
    s16x8 rb1 = *reinterpret_cast<const s16x8*>(pb + 8);

    for (int k0 = 0; k0 < K; k0 += 32) {
        __syncthreads();
        *reinterpret_cast<s16x8*>(&Als[srow * LDST + sk])     = ra0;
        *reinterpret_cast<s16x8*>(&Als[srow * LDST + sk + 8]) = ra1;
        *reinterpret_cast<s16x8*>(&Bls[srow * LDST + sk])     = rb0;
        *reinterpret_cast<s16x8*>(&Bls[srow * LDST + sk + 8]) = rb1;
        __syncthreads();
        if (k0 + 32 < K) {
            ra0 = *reinterpret_cast<const s16x8*>(pa + k0 + 32);
            ra1 = *reinterpret_cast<const s16x8*>(pa + k0 + 40);
            rb0 = *reinterpret_cast<const s16x8*>(pb + k0 + 32);
            rb1 = *reinterpret_cast<const s16x8*>(pb + k0 + 40);
        }
        s16x8 af[4], bfv[4];
        #pragma unroll
        for (int m = 0; m < 4; m++)
            af[m] = ldfrag(&Als[(wr * 64 + m * 16 + fr) * LDST + fg * 4]);
        #pragma unroll
        for (int n = 0; n < 4; n++)
            bfv[n] = ldfrag(&Bls[(wc * 64 + n * 16 + fr) * LDST + fg * 4]);
        #pragma unroll
        for (int m = 0; m < 4; m++)
            #pragma unroll
            for (int n = 0; n < 4; n++)
                acc[m][n] = __builtin_amdgcn_mfma_f32_16x16x32_bf16(af[m], bfv[n], acc[m][n], 0, 0, 0);
    }

    #pragma unroll
    for (int m = 0; m < 4; m++)
        #pragma unroll
        for (int n = 0; n < 4; n++)
            #pragma unroll
            for (int r = 0; r < 4; r++) {
                const int row = bm0 + wr * 64 + m * 16 + fg * 4 + r;
                const int col = bn0 + wc * 64 + n * 16 + fr;
                C[(size_t)row * N + col] = acc[m][n][r];
            }
}

// ---------------- bf16-input MFMA MoE GEMM (L2 value path) ----------------
template<int MODE, int EPI>
__global__ __launch_bounds__(256)
void k_mfma_moe_b(const short* __restrict__ A, const short* __restrict__ Bm,
                  float* __restrict__ Cf, short* __restrict__ Cbf,
                  const int* __restrict__ idx, const int* __restrict__ cnt,
                  const int* __restrict__ seg, int N, int K)
{
    int c = T_, s = 0;
    const int bm0 = blockIdx.y * 128, bn0 = blockIdx.x * 128;
    if (MODE >= 1) {
        const int e = blockIdx.z;
        c = cnt[e];
        if (bm0 >= c) return;
        s = seg[e];
        Bm += (size_t)e * N * K;
    }
    __shared__ short Als[128 * LDST];
    __shared__ short Bls[128 * LDST];
    const int tid  = threadIdx.x;
    const int lane = tid & 63, w = tid >> 6;
    const int wr = w >> 1, wc = w & 1;
    const int fr = lane & 15, fg = lane >> 4;
    const int srow = tid >> 1, sk = (tid & 1) * 16;

    int arow;
    if (MODE == 0)      arow = bm0 + srow;
    else if (MODE == 1) arow = idx[s + min(bm0 + srow, c - 1)];
    else                arow = s + min(bm0 + srow, c - 1);
    const short* pa = A  + (size_t)arow * K + sk;
    const short* pb = Bm + (size_t)(bn0 + srow) * K + sk;

    f32x4 acc[4][4];
    #pragma unroll
    for (int m = 0; m < 4; m++)
        #pragma unroll
        for (int n = 0; n < 4; n++) acc[m][n] = (f32x4){0.f, 0.f, 0.f, 0.f};

    s16x8 ra0 = *reinterpret_cast<const s16x8*>(pa);
    s16x8 ra1 = *reinterpret_cast<const s16x8*>(pa + 8);
    s16x8 rb0 = *reinterpret_cast<const s16x8*>(pb);
    s16x8 rb1 = *reinterpret_cast<const s16x8*>(pb + 8);

    for (int k0 = 0; k0 < K; k0 += 32) {
        __syncthreads();
        *reinterpret_cast<s16x8*>(&Als[srow * LDST + sk])     = ra0;
        *reinterpret_cast<s16x8*>(&Als[srow * LDST + sk + 8]) = ra1;
        *reinterpret_cast<s16x8*>(&Bls[srow * LDST + sk])     = rb0;
        *reinterpret_cast<s16x8*>(&Bls[srow * LDST + sk + 8]) = rb1;
        __syncthreads();
        if (k0 + 32 < K) {
            ra0 = *reinterpret_cast<const s16x8*>(pa + k0 + 32);
            ra1 = *reinterpret_cast<const s16x8*>(pa + k0 + 40);
            rb0 = *reinterpret_cast<const s16x8*>(pb + k0 + 32);
            rb1 = *reinterpret_cast<const s16x8*>(pb + k0 + 40);
        }
        s16x8 af[4], bfv[4];
        #pragma unroll
        for (int m = 0; m < 4; m++)
            af[m] = ldfrag(&Als[(wr * 64 + m * 16 + fr) * LDST + fg * 4]);
        #pragma unroll
        for (int n = 0; n < 4; n++)
            bfv[n] = ldfrag(&Bls[(wc * 64 + n * 16 + fr) * LDST + fg * 4]);
        #pragma unroll
        for (int m = 0; m < 4; m++)
            #pragma unroll
            for (int n = 0; n < 4; n++)
                acc[m][n] = __builtin_amdgcn_mfma_f32_16x16x32_bf16(af[m], bfv[n], acc[m][n], 0, 0, 0);
    }

    #pragma unroll
    for (int m = 0; m < 4; m++)
        #pragma unroll
        for (int n = 0; n < 4; n++)
            #pragma unroll
            for (int r = 0; r < 4; r++) {
                const int row = bm0 + wr * 64 + m * 16 + fg * 4 + r;
                if (MODE >= 1 && row >= c) continue;
                const int col = bn0 + wc * 64 + n * 16 + fr;
                const size_t p = (size_t)((MODE >= 1 ? s : 0) + row) * N + col;
                if (EPI == 0)      Cf[p] = acc[m][n][r];
                else if (EPI == 1) {
                    const float gv = Cf[p];
                    Cbf[p] = f2bf(gv * (1.f / (1.f + expf(-gv))) * acc[m][n][r]);
                } else               Cf[p] += acc[m][n][r];
            }
}

// ---------------- split-bf16-input MFMA GEMM (L1, routing-safe) ----------------
template<int MODE, int EPI>
__global__ __launch_bounds__(256)
void k_mfma_sp_b(const short* __restrict__ Ah, const short* __restrict__ Alp,
                 const short* __restrict__ Bh, const short* __restrict__ Blp,
                 float* __restrict__ Cf, short* __restrict__ Chi, short* __restrict__ Clo,
                 const int* __restrict__ idx, const int* __restrict__ cnt,
                 const int* __restrict__ seg, int N, int K)
{
    int c = T_, s = 0;
    const int bm0 = blockIdx.y * 128, bn0 = blockIdx.x * 128;
    if (MODE >= 1) {
        const int e = blockIdx.z;
        c = cnt[e];
        if (bm0 >= c) return;
        s = seg[e];
        Bh  += (size_t)e * N * K;
        Blp += (size_t)e * N * K;
    }
    __shared__ short LAh[128 * LDST];
    __shared__ short LAl[128 * LDST];
    __shared__ short LBh[128 * LDST];
    __shared__ short LBl[128 * LDST];
    const int tid  = threadIdx.x;
    const int lane = tid & 63, w = tid >> 6;
    const int wr = w >> 1, wc = w & 1;
    const int fr = lane & 15, fg = lane >> 4;
    const int srow = tid >> 1, sk = (tid & 1) * 16;

    int arow;
    if (MODE == 0)      arow = bm0 + srow;
    else if (MODE == 1) arow = idx[s + min(bm0 + srow, c - 1)];
    else                arow = s + min(bm0 + srow, c - 1);
    const short* pah = Ah  + (size_t)arow * K + sk;
    const short* pal = Alp + (size_t)arow * K + sk;
    const short* pbh = Bh  + (size_t)(bn0 + srow) * K + sk;
    const short* pbl = Blp + (size_t)(bn0 + srow) * K + sk;

    f32x4 acc[4][4];
    #pragma unroll
    for (int m = 0; m < 4; m++)
        #pragma unroll
        for (int n = 0; n < 4; n++) acc[m][n] = (f32x4){0.f, 0.f, 0.f, 0.f};

    s16x8 rah0 = *reinterpret_cast<const s16x8*>(pah);
    s16x8 rah1 = *reinterpret_cast<const s16x8*>(pah + 8);
    s16x8 ral0 = *reinterpret_cast<const s16x8*>(pal);
    s16x8 ral1 = *reinterpret_cast<const s16x8*>(pal + 8);
    s16x8 rbh0 = *reinterpret_cast<const s16x8*>(pbh);
    s16x8 rbh1 = *reinterpret_cast<const s16x8*>(pbh + 8);
    s16x8 rbl0 = *reinterpret_cast<const s16x8*>(pbl);
    s16x8 rbl1 = *reinterpret_cast<const s16x8*>(pbl + 8);

    for (int k0 = 0; k0 < K; k0 += 32) {
        __syncthreads();
        *reinterpret_cast<s16x8*>(&LAh[srow * LDST + sk])     = rah0;
        *reinterpret_cast<s16x8*>(&LAh[srow * LDST + sk + 8]) = rah1;
        *reinterpret_cast<s16x8*>(&LAl[srow * LDST + sk])     = ral0;
        *reinterpret_cast<s16x8*>(&LAl[srow * LDST + sk + 8]) = ral1;
        *reinterpret_cast<s16x8*>(&LBh[srow * LDST + sk])     = rbh0;
        *reinterpret_cast<s16x8*>(&LBh[srow * LDST + sk + 8]) = rbh1;
        *reinterpret_cast<s16x8*>(&LBl[srow * LDST + sk])     = rbl0;
        *reinterpret_cast<s16x8*>(&LBl[srow * LDST + sk + 8]) = rbl1;
        __syncthreads();
        if (k0 + 32 < K) {
            rah0 = *reinterpret_cast<const s16x8*>(pah + k0 + 32);
            rah1 = *reinterpret_cast<const s16x8*>(pah + k0 + 40);
            ral0 = *reinterpret_cast<const s16x8*>(pal + k0 + 32);
            ral1 = *reinterpret_cast<const s16x8*>(pal + k0 + 40);
            rbh0 = *reinterpret_cast<const s16x8*>(pbh + k0 + 32);
            rbh1 = *reinterpret_cast<const s16x8*>(pbh + k0 + 40);
            rbl0 = *reinterpret_cast<const s16x8*>(pbl + k0 + 32);
            rbl1 = *reinterpret_cast<const s16x8*>(pbl + k0 + 40);
        }
        s16x8 afh[4], afl[4];
        #pragma unroll
        for (int m = 0; m < 4; m++) {
            afh[m] = ldfrag(&LAh[(wr * 64 + m * 16 + fr) * LDST + fg * 4]);
            afl[m] = ldfrag(&LAl[(wr * 64 + m * 16 + fr) * LDST + fg * 4]);
        }
        #pragma unroll
        for (int n = 0; n < 4; n++) {
            const s16x8 bh = ldfrag(&LBh[(wc * 64 + n * 16 + fr) * LDST + fg * 4]);
            const s16x8 bl = ldfrag(&LBl[(wc * 64 + n * 16 + fr) * LDST + fg * 4]);
            #pragma unroll
            for (int m = 0; m < 4; m++) {
                acc[m][n] = __builtin_amdgcn_mfma_f32_16x16x32_bf16(afh[m], bh, acc[m][n], 0, 0, 0);
                acc[m][n] = __builtin_amdgcn_mfma_f32_16x16x32_bf16(afl[m], bh, acc[m][n], 0, 0, 0);
                acc[m][n] = __builtin_amdgcn_mfma_f32_16x16x32_bf16(afh[m], bl, acc[m][n], 0, 0, 0);
            }
        }
    }

    #pragma unroll
    for (int m = 0; m < 4; m++)
        #pragma unroll
        for (int n = 0; n < 4; n++)
            #pragma unroll
            for (int r = 0; r < 4; r++) {
                const int row = bm0 + wr * 64 + m * 16 + fg * 4 + r;
                if (MODE >= 1 && row >= c) continue;
                const int col = bn0 + wc * 64 + n * 16 + fr;
                const size_t p = (size_t)((MODE >= 1 ? s : 0) + row) * N + col;
                if (EPI == 0)      Cf[p] = acc[m][n][r];
                else if (EPI == 1) {
                    const float gv = Cf[p];
                    const float pr = gv * (1.f / (1.f + expf(-gv))) * acc[m][n][r];
                    const short hh = f2bf(pr);
                    Chi[p] = hh;
                    Clo[p] = f2bf(pr - bf2f(hh));
                } else               Cf[p] += acc[m][n][r];
            }
}

#define GEMM(BL, EPI, A, Bw, CC, M, N, K) \
    k_gemm<BL, EPI><<<dim3((N)/128, (M)/128), 256, 0, stream>>>(A, Bw, CC, M, N, K)

extern "C" void kernel_launch(void* const* d_in, const int* in_sizes, int n_in,
                              void* d_out, int out_size, void* d_ws, size_t ws_size,
                              hipStream_t stream)
{
    const int*   ids    = (const int*)  d_in[0];
    const float* embed  = (const float*)d_in[1];
    const float* ln1_g  = (const float*)d_in[2];
    const float* ln1_b  = (const float*)d_in[3];
    const float* wq     = (const float*)d_in[4];
    const float* wk     = (const float*)d_in[5];
    const float* wv     = (const float*)d_in[6];
    const float* wo     = (const float*)d_in[7];
    const float* ln2_g  = (const float*)d_in[8];
    const float* ln2_b  = (const float*)d_in[9];
    const float* gate_w = (const float*)d_in[10];
    const float* exp_wg = (const float*)d_in[11];
    const float* exp_wu = (const float*)d_in[12];
    const float* exp_wd = (const float*)d_in[13];
    const float* sh_wg  = (const float*)d_in[14];
    const float* sh_wu  = (const float*)d_in[15];
    const float* sh_wd  = (const float*)d_in[16];
    const float* fn_g   = (const float*)d_in[17];
    const float* fn_b   = (const float*)d_in[18];
    const float* lm     = (const float*)d_in[19];
    float* out = (float*)d_out;

    float* x    = (float*)d_ws;                 // T*H
    float* h    = x + 2097152;                  // T*H
    float* qb   = h + 2097152;                  // R1: qb 2M, kv 1M, ob 2M
    float* kv   = qb + 2097152;
    float* ob   = kv + 1048576;
    float* ebuf = qb;                           // CAP*H aliases R1
    float* gbuf = qb + 5242880;                 // CAP*I f32
    float* gw   = gbuf + 5242880;               // T*8
    float* wl   = gw + (size_t)T_ * E_;         // CAP
    int*   idx  = (int*)(wl + CAP_);            // CAP
    int*   pos  = idx + CAP_;                   // T*2
    int*   cnt  = pos + 2 * T_;                 // 8
    int*   seg  = cnt + E_;                     // 8
    short* hhi  = (short*)(seg + 64);           // 2M
    short* hlo  = hhi + 2097152;                // 2M
    short* hbf  = hlo + 2097152;                // 2M
    short* gbh  = hbf + 2097152;                // CAP*I
    short* gbl  = gbh + 5242880;                // CAP*I
    short* wb   = gbl + 5242880;                // 56.6M shorts, phase-reused
    const size_t EW = (size_t)E_ * I_ * H_;     // 8,388,608

    // attention bf16 K/V scratch aliases wb (phase-disjoint with MoE/lm use)
    short* khi_p = wb;
    short* klo_p = wb + 524288;
    short* vth_p = wb + 1048576;
    short* vtl_p = wb + 1572864;

    k_embed<<<T_, 256, 0, stream>>>(ids, embed, x);

    for (int l = 0; l < L_; l++) {
        k_layernorm<<<T_, 256, 0, stream>>>(x, ln1_g + (size_t)l * H_, ln1_b + (size_t)l * H_, h);

        k_gemm_qkv<<<dim3(12, 16), 256, 0, stream>>>(
            h, wq + (size_t)l * H_ * H_, wk + (size_t)l * H_ * 256, wv + (size_t)l * H_ * 256, qb, kv);

        k_rope<<<(T_ * NH_  * 32) / 256, 256, 0, stream>>>(qb, 1024, NH_);
        k_rope<<<(T_ * NKV_ * 32) / 256, 256, 0, stream>>>(kv, 512,  NKV_);

        k_cvt_kv<<<B_ * NKV_ * (S_ / 64), 256, 0, stream>>>(kv, khi_p, klo_p, vth_p, vtl_p);
        k_attn_mfma<<<dim3(S_ / 64, NH_, B_), 256, 0, stream>>>(qb, khi_p, klo_p, vth_p, vtl_p, ob);

        GEMM(0, 2, ob, wo + (size_t)l * H_ * H_, x, T_, H_, H_);

        k_layernorm<<<T_, 256, 0, stream>>>(x, ln2_g + (size_t)l * H_, ln2_b + (size_t)l * H_, h);
        k_gate<<<T_, 64, 0, stream>>>(h, gate_w + (size_t)l * E_ * H_, gw);
        k_build<<<1, 512, 0, stream>>>(gw, idx, wl, pos, cnt, seg);

        const float* wg_l = exp_wg + (size_t)l * EW;
        const float* wu_l = exp_wu + (size_t)l * EW;
        const float* wd_l = exp_wd + (size_t)l * EW;
        const float* sg_l = sh_wg + (size_t)l * I_ * H_;
        const float* su_l = sh_wu + (size_t)l * I_ * H_;
        const float* sd_l = sh_wd + (size_t)l * H_ * I_;

        if (l == 0) {
            short* wgh = wb;            short* wgl = wb + EW;
            short* wuh = wb + 2 * EW;   short* wul = wb + 3 * EW;
            short* wdh = wb + 4 * EW;   short* wdl = wb + 5 * EW;
            short* sgh = wb + 6 * EW;   short* sgl = sgh + 1048576;
            short* suh = sgl + 1048576; short* sul = suh + 1048576;
            short* sdh = sul + 1048576; short* sdl = sdh + 1048576;

            k_cvt_sp<<<4096, 256, 0, stream>>>(wg_l, wgh, wgl, (int)(EW / 8));
            k_cvt_sp<<<4096, 256, 0, stream>>>(wu_l, wuh, wul, (int)(EW / 8));
            k_cvt_sp<<<4096, 256, 0, stream>>>(wd_l, wdh, wdl, (int)(EW / 8));
            k_cvt_sp<<<512,  256, 0, stream>>>(sg_l, sgh, sgl, 131072);
            k_cvt_sp<<<512,  256, 0, stream>>>(su_l, suh, sul, 131072);
            k_cvt_sp<<<512,  256, 0, stream>>>(sd_l, sdh, sdl, 131072);
            k_cvt_sp<<<1024, 256, 0, stream>>>(h, hhi, hlo, 262144);

            k_mfma_sp_b<0, 0><<<dim3(8, 16, 1), 256, 0, stream>>>(hhi, hlo, sgh, sgl, gbuf, nullptr, nullptr, nullptr, nullptr, nullptr, I_, H_);
            k_mfma_sp_b<0, 1><<<dim3(8, 16, 1), 256, 0, stream>>>(hhi, hlo, suh, sul, gbuf, gbh, gbl, nullptr, nullptr, nullptr, I_, H_);
            k_mfma_sp_b<0, 2><<<dim3(8, 16, 1), 256, 0, stream>>>(gbh, gbl, sdh, sdl, x, nullptr, nullptr, nullptr, nullptr, nullptr, H_, I_);
            k_mfma_sp_b<1, 0><<<dim3(8, 16, E_), 256, 0, stream>>>(hhi, hlo, wgh, wgl, gbuf, nullptr, nullptr, idx, cnt, seg, I_, H_);
            k_mfma_sp_b<1, 1><<<dim3(8, 16, E_), 256, 0, stream>>>(hhi, hlo, wuh, wul, gbuf, gbh, gbl, idx, cnt, seg, I_, H_);
            k_mfma_sp_b<2, 0><<<dim3(8, 16, E_), 256, 0, stream>>>(gbh, gbl, wdh, wdl, ebuf, nullptr, nullptr, idx, cnt, seg, H_, I_);
        } else {
            short* wgb = wb;            short* wub = wb + EW;       short* wdb = wb + 2 * EW;
            short* sgb = wb + 3 * EW;   short* sub = sgb + 1048576; short* sdb = sub + 1048576;

            k_cvt<<<4096, 256, 0, stream>>>(wg_l, wgb, (int)(EW / 8));
            k_cvt<<<4096, 256, 0, stream>>>(wu_l, wub, (int)(EW / 8));
            k_cvt<<<4096, 256, 0, stream>>>(wd_l, wdb, (int)(EW / 8));
            k_cvt<<<512,  256, 0, stream>>>(sg_l, sgb, 131072);
            k_cvt<<<512,  256, 0, stream>>>(su_l, sub, 131072);
            k_cvt<<<512,  256, 0, stream>>>(sd_l, sdb, 131072);
            k_cvt<<<1024, 256, 0, stream>>>(h, hbf, 262144);

            k_mfma_moe_b<0, 0><<<dim3(8, 16, 1), 256, 0, stream>>>(hbf, sgb, gbuf, nullptr, nullptr, nullptr, nullptr, I_, H_);
            k_mfma_moe_b<0, 1><<<dim3(8, 16, 1), 256, 0, stream>>>(hbf, sub, gbuf, gbh, nullptr, nullptr, nullptr, I_, H_);
            k_mfma_moe_b<0, 2><<<dim3(8, 16, 1), 256, 0, stream>>>(gbh, sdb, x, nullptr, nullptr, nullptr, nullptr, H_, I_);
            k_mfma_moe_b<1, 0><<<dim3(8, 16, E_), 256, 0, stream>>>(hbf, wgb, gbuf, nullptr, idx, cnt, seg, I_, H_);
            k_mfma_moe_b<1, 1><<<dim3(8, 16, E_), 256, 0, stream>>>(hbf, wub, gbuf, gbh, idx, cnt, seg, I_, H_);
            k_mfma_moe_b<2, 0><<<dim3(8, 16, E_), 256, 0, stream>>>(gbh, wdb, ebuf, nullptr, idx, cnt, seg, H_, I_);
        }
        k_combine<<<(T_ * H_) / 256, 256, 0, stream>>>(x, ebuf, wl, pos);
    }

    k_layernorm<<<T_, 256, 0, stream>>>(x, fn_g, fn_b, h);
    k_cvt<<<1024,  256, 0, stream>>>(h, hbf, 262144);
    k_cvt<<<16000, 256, 0, stream>>>(lm, wb, 4096000);
    k_mfma_bt_b<<<(T_ / 128) * (V_ / 128), 256, 0, stream>>>(hbf, wb, out, T_, V_, H_);
}

// Round 11
// 1859.162 us; speedup vs baseline: 6.4399x; 1.1630x over previous
//
#include <hip/hip_runtime.h>
#include <cmath>

#define L_   2
#define E_   8
#define NH_  16
#define NKV_ 4
#define HD_  64
#define H_   1024
#define I_   1024
#define B_   2
#define S_   1024
#define T_   (B_*S_)
#define V_   32000
#define CAP_ 5120
#define QKVN 1536
#define LDST 36   // LDS row stride in shorts for GEMM tiles (conflict-free)
#define AST  72   // LDS row stride in shorts for attention tiles

typedef float f32x4 __attribute__((ext_vector_type(4)));
typedef short s16x4 __attribute__((ext_vector_type(4)));
typedef short s16x8 __attribute__((ext_vector_type(8)));

__device__ __forceinline__ short f2bf(float f) {
    unsigned u = __float_as_uint(f);
    u = (u + 0x7fffu + ((u >> 16) & 1u)) >> 16;   // RNE
    return (short)u;
}
__device__ __forceinline__ float bf2f(short h) {
    return __uint_as_float(((unsigned)(unsigned short)h) << 16);
}
__device__ __forceinline__ s16x8 ldfrag(const short* p) {
    s16x4 lo = *reinterpret_cast<const s16x4*>(p);
    s16x4 hi = *reinterpret_cast<const s16x4*>(p + 16);
    return __builtin_shufflevector(lo, hi, 0, 1, 2, 3, 4, 5, 6, 7);
}

// ---------------- converters ----------------
__global__ __launch_bounds__(256)
void k_cvt(const float* __restrict__ s, short* __restrict__ d, int n8)
{
    const int i = blockIdx.x * 256 + threadIdx.x;
    if (i >= n8) return;
    const float4 a = *reinterpret_cast<const float4*>(s + (size_t)i * 8);
    const float4 b = *reinterpret_cast<const float4*>(s + (size_t)i * 8 + 4);
    s16x8 o;
    o[0]=f2bf(a.x); o[1]=f2bf(a.y); o[2]=f2bf(a.z); o[3]=f2bf(a.w);
    o[4]=f2bf(b.x); o[5]=f2bf(b.y); o[6]=f2bf(b.z); o[7]=f2bf(b.w);
    *reinterpret_cast<s16x8*>(d + (size_t)i * 8) = o;
}

__global__ __launch_bounds__(256)
void k_cvt_sp(const float* __restrict__ s, short* __restrict__ dh, short* __restrict__ dl, int n8)
{
    const int i = blockIdx.x * 256 + threadIdx.x;
    if (i >= n8) return;
    const float4 a = *reinterpret_cast<const float4*>(s + (size_t)i * 8);
    const float4 b = *reinterpret_cast<const float4*>(s + (size_t)i * 8 + 4);
    float v[8] = {a.x, a.y, a.z, a.w, b.x, b.y, b.z, b.w};
    s16x8 oh, ol;
    #pragma unroll
    for (int j = 0; j < 8; j++) {
        const short hh = f2bf(v[j]);
        oh[j] = hh;
        ol[j] = f2bf(v[j] - bf2f(hh));
    }
    *reinterpret_cast<s16x8*>(dh + (size_t)i * 8) = oh;
    *reinterpret_cast<s16x8*>(dl + (size_t)i * 8) = ol;
}

// ---------------- transposing split converter: W[K][N] f32 -> out[N][K] hi/lo ----------------
// grid (N/64, K/64), 256 threads. Caller may offset oh/ol by rowOffset*K.
__global__ __launch_bounds__(256)
void k_cvt_sp_t(const float* __restrict__ w, short* __restrict__ oh, short* __restrict__ ol,
                int N, int K)
{
    const int n0 = blockIdx.x * 64, k0 = blockIdx.y * 64;
    const int r = threadIdx.x >> 2, c0 = (threadIdx.x & 3) * 16;
    __shared__ float Tt[64][65];
    const float* src = w + (size_t)(k0 + r) * N + n0 + c0;
    #pragma unroll
    for (int g = 0; g < 4; g++) {
        const float4 a = *reinterpret_cast<const float4*>(src + g * 4);
        Tt[c0 + g*4 + 0][r] = a.x; Tt[c0 + g*4 + 1][r] = a.y;
        Tt[c0 + g*4 + 2][r] = a.z; Tt[c0 + g*4 + 3][r] = a.w;
    }
    __syncthreads();
    const size_t o = (size_t)(n0 + r) * K + k0 + c0;
    #pragma unroll
    for (int g = 0; g < 2; g++) {
        s16x8 vh, vl;
        #pragma unroll
        for (int j = 0; j < 8; j++) {
            const float v = Tt[r][c0 + g * 8 + j];
            const short hh = f2bf(v);
            vh[j] = hh; vl[j] = f2bf(v - bf2f(hh));
        }
        *reinterpret_cast<s16x8*>(oh + o + g * 8) = vh;
        *reinterpret_cast<s16x8*>(ol + o + g * 8) = vl;
    }
}

// ---------------- K/V (packed qkv buffer) -> split bf16 (K row-major, V transposed) ----------------
// qkvp: [T][1536] f32. khi/klo: [B*NKV][S][64]. vth/vtl: [B*NKV][64][S].
__global__ __launch_bounds__(256)
void k_cvt_kv(const float* __restrict__ qkvp,
              short* __restrict__ khi, short* __restrict__ klo,
              short* __restrict__ vth, short* __restrict__ vtl)
{
    const int blk = blockIdx.x;              // B*NKV*(S/64) = 128
    const int s0  = (blk & 15) * 64;
    const int kvh = (blk >> 4) & 3;
    const int b   = blk >> 6;
    const int tid = threadIdx.x;
    const int r = tid >> 2, c0 = (tid & 3) * 16;
    __shared__ float Vt[64][65];

    const float* kp = qkvp + (size_t)(b * S_ + s0 + r) * QKVN + 1024 + kvh * 64 + c0;
    const size_t ko = ((size_t)(b * 4 + kvh) * S_ + s0 + r) * 64 + c0;
    #pragma unroll
    for (int g = 0; g < 2; g++) {
        const float4 a = *reinterpret_cast<const float4*>(kp + g * 8);
        const float4 bq = *reinterpret_cast<const float4*>(kp + g * 8 + 4);
        float v[8] = {a.x, a.y, a.z, a.w, bq.x, bq.y, bq.z, bq.w};
        s16x8 oh, ol;
        #pragma unroll
        for (int j = 0; j < 8; j++) {
            const short hh = f2bf(v[j]);
            oh[j] = hh; ol[j] = f2bf(v[j] - bf2f(hh));
        }
        *reinterpret_cast<s16x8*>(khi + ko + g * 8) = oh;
        *reinterpret_cast<s16x8*>(klo + ko + g * 8) = ol;
    }
    const float* vp = kp + 256;
    #pragma unroll
    for (int g = 0; g < 4; g++) {
        const float4 a = *reinterpret_cast<const float4*>(vp + g * 4);
        Vt[c0 + g*4 + 0][r] = a.x; Vt[c0 + g*4 + 1][r] = a.y;
        Vt[c0 + g*4 + 2][r] = a.z; Vt[c0 + g*4 + 3][r] = a.w;
    }
    __syncthreads();
    const size_t vo = ((size_t)(b * 4 + kvh) * 64 + r) * S_ + s0 + c0;
    #pragma unroll
    for (int g = 0; g < 2; g++) {
        s16x8 oh, ol;
        #pragma unroll
        for (int j = 0; j < 8; j++) {
            const float v = Vt[r][c0 + g * 8 + j];
            const short hh = f2bf(v);
            oh[j] = hh; ol[j] = f2bf(v - bf2f(hh));
        }
        *reinterpret_cast<s16x8*>(vth + vo + g * 8) = oh;
        *reinterpret_cast<s16x8*>(vtl + vo + g * 8) = ol;
    }
}

// ---------------- embedding ----------------
__global__ void k_embed(const int* __restrict__ ids, const float* __restrict__ emb,
                        float* __restrict__ x)
{
    const int t = blockIdx.x;
    const float* src = emb + (size_t)ids[t] * H_;
    float* dst = x + (size_t)t * H_;
    for (int i = threadIdx.x; i < H_; i += 256) dst[i] = src[i];
}

// ---------------- layernorm (OMODE 0: f32 | 1: +bf16 | 2: +hi/lo split) ----------------
template<int OMODE>
__global__ __launch_bounds__(256)
void k_layernorm(const float* __restrict__ x, const float* __restrict__ g,
                 const float* __restrict__ bb, float* __restrict__ out,
                 short* __restrict__ oh, short* __restrict__ ol)
{
    const int t = blockIdx.x;
    const float* row = x + (size_t)t * H_;
    float s = 0.f, ss = 0.f;
    for (int i = threadIdx.x; i < H_; i += 256) { const float v = row[i]; s += v; ss += v * v; }
    #pragma unroll
    for (int off = 32; off > 0; off >>= 1) {
        s  += __shfl_down(s, off, 64);
        ss += __shfl_down(ss, off, 64);
    }
    __shared__ float shs[4], shss[4];
    const int w = threadIdx.x >> 6;
    if ((threadIdx.x & 63) == 0) { shs[w] = s; shss[w] = ss; }
    __syncthreads();
    const float fs  = shs[0] + shs[1] + shs[2] + shs[3];
    const float fss = shss[0] + shss[1] + shss[2] + shss[3];
    const float mean = fs * (1.f / H_);
    const float var  = fss * (1.f / H_) - mean * mean;
    const float rstd = 1.0f / sqrtf(var + 1e-5f);
    float* orow = out + (size_t)t * H_;
    for (int i = threadIdx.x; i < H_; i += 256) {
        const float v = (row[i] - mean) * rstd * g[i] + bb[i];
        orow[i] = v;
        if (OMODE == 1) {
            oh[(size_t)t * H_ + i] = f2bf(v);
        } else if (OMODE == 2) {
            const short hh = f2bf(v);
            oh[(size_t)t * H_ + i] = hh;
            ol[(size_t)t * H_ + i] = f2bf(v - bf2f(hh));
        }
    }
}

// ---------------- RoPE (generic stride/base) ----------------
__global__ void k_rope(float* __restrict__ x, int rowStride, int nheads)
{
    const int idx  = blockIdx.x * 256 + threadIdx.x;
    const int i    = idx & 31;
    const int rest = idx >> 5;
    const int head = rest % nheads;
    const int t    = rest / nheads;
    const int pos  = t & (S_ - 1);
    const float p32  = (float)pow(1.0e6, (double)i / 32.0);
    const float invf = 1.0f / p32;
    const float ang  = (float)pos * invf;
    const float c = (float)cos((double)ang);
    const float s = (float)sin((double)ang);
    float* base = x + (size_t)t * rowStride + head * HD_;
    const float x1 = base[i];
    const float x2 = base[i + 32];
    base[i]      = x1 * c - x2 * s;
    base[i + 32] = x2 * c + x1 * s;
}

// ---------------- split-bf16 MFMA flash attention (packed q, split O out) ----------------
__global__ __launch_bounds__(256)
void k_attn_mfma(const float* __restrict__ q,
                 const short* __restrict__ khi, const short* __restrict__ klo,
                 const short* __restrict__ vth, const short* __restrict__ vtl,
                 short* __restrict__ obh, short* __restrict__ obl)
{
    const int q0 = blockIdx.x * 64, h = blockIdx.y, b = blockIdx.z;
    const int kvh = h >> 2;
    const int tid = threadIdx.x, lane = tid & 63, w = tid >> 6;
    const int fr = lane & 15, fg = lane >> 4;

    __shared__ short Qh[64 * AST], Ql[64 * AST];
    __shared__ short Kh[64 * AST], Kl[64 * AST];
    __shared__ short Vh[64 * AST], Vl[64 * AST];
    __shared__ short Ph[64 * AST], Pl[64 * AST];

    {   // stage Q (scaled 0.125, split)
        const int r = tid >> 2, c0 = (tid & 3) * 16;
        const float* qs = q + (size_t)(b * S_ + q0 + r) * QKVN + h * HD_ + c0;
        #pragma unroll
        for (int g = 0; g < 2; g++) {
            const float4 a = *reinterpret_cast<const float4*>(qs + g * 8);
            const float4 bq = *reinterpret_cast<const float4*>(qs + g * 8 + 4);
            float v[8] = {a.x, a.y, a.z, a.w, bq.x, bq.y, bq.z, bq.w};
            s16x8 oh, ol;
            #pragma unroll
            for (int j = 0; j < 8; j++) {
                const float sv = v[j] * 0.125f;
                const short hh = f2bf(sv);
                oh[j] = hh; ol[j] = f2bf(sv - bf2f(hh));
            }
            *reinterpret_cast<s16x8*>(&Qh[r * AST + c0 + g * 8]) = oh;
            *reinterpret_cast<s16x8*>(&Ql[r * AST + c0 + g * 8]) = ol;
        }
    }

    f32x4 accO[4];
    #pragma unroll
    for (int n = 0; n < 4; n++) accO[n] = (f32x4){0.f, 0.f, 0.f, 0.f};
    float rs[4] = {0.f, 0.f, 0.f, 0.f};

    const size_t kbase = (size_t)(b * 4 + kvh) * S_ * 64;
    const size_t vbase = (size_t)(b * 4 + kvh) * 64 * S_;
    const int nkb = (q0 >> 6) + 1;

    for (int kb = 0; kb < nkb; kb++) {
        const int j0 = kb * 64;
        __syncthreads();
        {
            const int r = tid >> 2, c0 = (tid & 3) * 16;
            const short* ks = khi + kbase + (size_t)(j0 + r) * 64 + c0;
            const short* ls = klo + kbase + (size_t)(j0 + r) * 64 + c0;
            *reinterpret_cast<s16x8*>(&Kh[r * AST + c0])     = *reinterpret_cast<const s16x8*>(ks);
            *reinterpret_cast<s16x8*>(&Kh[r * AST + c0 + 8]) = *reinterpret_cast<const s16x8*>(ks + 8);
            *reinterpret_cast<s16x8*>(&Kl[r * AST + c0])     = *reinterpret_cast<const s16x8*>(ls);
            *reinterpret_cast<s16x8*>(&Kl[r * AST + c0 + 8]) = *reinterpret_cast<const s16x8*>(ls + 8);
            const short* vs = vth + vbase + (size_t)r * S_ + j0 + c0;
            const short* vl = vtl + vbase + (size_t)r * S_ + j0 + c0;
            *reinterpret_cast<s16x8*>(&Vh[r * AST + c0])     = *reinterpret_cast<const s16x8*>(vs);
            *reinterpret_cast<s16x8*>(&Vh[r * AST + c0 + 8]) = *reinterpret_cast<const s16x8*>(vs + 8);
            *reinterpret_cast<s16x8*>(&Vl[r * AST + c0])     = *reinterpret_cast<const s16x8*>(vl);
            *reinterpret_cast<s16x8*>(&Vl[r * AST + c0 + 8]) = *reinterpret_cast<const s16x8*>(vl + 8);
        }
        __syncthreads();

        f32x4 accS[4];
        #pragma unroll
        for (int n = 0; n < 4; n++) accS[n] = (f32x4){0.f, 0.f, 0.f, 0.f};
        #pragma unroll
        for (int ks2 = 0; ks2 < 2; ks2++) {
            const int ko = ks2 * 32 + fg * 4;
            const s16x8 ah = ldfrag(&Qh[(w * 16 + fr) * AST + ko]);
            const s16x8 al = ldfrag(&Ql[(w * 16 + fr) * AST + ko]);
            #pragma unroll
            for (int n = 0; n < 4; n++) {
                const int base = (n * 16 + fr) * AST + ko;
                const s16x8 bh = ldfrag(&Kh[base]);
                const s16x8 bl = ldfrag(&Kl[base]);
                accS[n] = __builtin_amdgcn_mfma_f32_16x16x32_bf16(ah, bh, accS[n], 0, 0, 0);
                accS[n] = __builtin_amdgcn_mfma_f32_16x16x32_bf16(al, bh, accS[n], 0, 0, 0);
                accS[n] = __builtin_amdgcn_mfma_f32_16x16x32_bf16(ah, bl, accS[n], 0, 0, 0);
            }
        }

        #pragma unroll
        for (int r = 0; r < 4; r++) {
            const int qrow = q0 + w * 16 + fg * 4 + r;
            float ev[4];
            float p = 0.f;
            #pragma unroll
            for (int n = 0; n < 4; n++) {
                const int key = j0 + n * 16 + fr;
                const float e = (key <= qrow) ? expf(accS[n][r]) : 0.f;
                ev[n] = e; p += e;
            }
            p += __shfl_xor(p, 1, 64); p += __shfl_xor(p, 2, 64);
            p += __shfl_xor(p, 4, 64); p += __shfl_xor(p, 8, 64);
            rs[r] += p;
            #pragma unroll
            for (int n = 0; n < 4; n++) {
                const int addr = (w * 16 + fg * 4 + r) * AST + n * 16 + fr;
                const short hh = f2bf(ev[n]);
                Ph[addr] = hh;
                Pl[addr] = f2bf(ev[n] - bf2f(hh));
            }
        }
        __builtin_amdgcn_wave_barrier();

        #pragma unroll
        for (int ks2 = 0; ks2 < 2; ks2++) {
            const int ko = ks2 * 32 + fg * 4;
            const s16x8 ph = ldfrag(&Ph[(w * 16 + fr) * AST + ko]);
            const s16x8 pl = ldfrag(&Pl[(w * 16 + fr) * AST + ko]);
            #pragma unroll
            for (int n = 0; n < 4; n++) {
                const int base = (n * 16 + fr) * AST + ko;
                const s16x8 vh = ldfrag(&Vh[base]);
                const s16x8 vl = ldfrag(&Vl[base]);
                accO[n] = __builtin_amdgcn_mfma_f32_16x16x32_bf16(ph, vh, accO[n], 0, 0, 0);
                accO[n] = __builtin_amdgcn_mfma_f32_16x16x32_bf16(pl, vh, accO[n], 0, 0, 0);
                accO[n] = __builtin_amdgcn_mfma_f32_16x16x32_bf16(ph, vl, accO[n], 0, 0, 0);
            }
        }
    }

    // O write (split hi/lo, feeds wo split-MFMA directly)
    #pragma unroll
    for (int r = 0; r < 4; r++) {
        const float inv = 1.0f / rs[r];
        const int qrow = q0 + w * 16 + fg * 4 + r;
        const size_t ob = (size_t)(b * S_ + qrow) * H_ + h * HD_;
        #pragma unroll
        for (int n = 0; n < 4; n++) {
            const float v = accO[n][r] * inv;
            const short hh = f2bf(v);
            obh[ob + n * 16 + fr] = hh;
            obl[ob + n * 16 + fr] = f2bf(v - bf2f(hh));
        }
    }
}

// ---------------- MoE gate ----------------
__global__ __launch_bounds__(64)
void k_gate(const float* __restrict__ h, const float* __restrict__ gwt, float* __restrict__ w)
{
    const int t = blockIdx.x;
    const int lane = threadIdx.x;
    const float* row = h + (size_t)t * H_;
    float acc[E_];
    #pragma unroll
    for (int e = 0; e < E_; e++) acc[e] = 0.f;
    for (int i = lane; i < H_; i += 64) {
        const float xv = row[i];
        #pragma unroll
        for (int e = 0; e < E_; e++) acc[e] += xv * gwt[(size_t)e * H_ + i];
    }
    #pragma unroll
    for (int e = 0; e < E_; e++) {
        #pragma unroll
        for (int off = 32; off > 0; off >>= 1) acc[e] += __shfl_down(acc[e], off, 64);
    }
    if (lane == 0) {
        int i1 = 0; float m1 = acc[0];
        #pragma unroll
        for (int e = 1; e < E_; e++) if (acc[e] > m1) { m1 = acc[e]; i1 = e; }
        int i2 = -1; float m2 = -1e30f;
        #pragma unroll
        for (int e = 0; e < E_; e++) if (e != i1 && acc[e] > m2) { m2 = acc[e]; i2 = e; }
        const float e2  = expf(m2 - m1);
        const float den = 1.0f + e2;
        #pragma unroll
        for (int e = 0; e < E_; e++)
            w[t * E_ + e] = (e == i1) ? (1.0f / den) : ((e == i2) ? (e2 / den) : 0.f);
    }
}

// ---------------- build per-expert token lists ----------------
__global__ __launch_bounds__(512)
void k_build(const float* __restrict__ gw, int* __restrict__ idx, float* __restrict__ wl,
             int* __restrict__ pos, int* __restrict__ cnt, int* __restrict__ seg)
{
    const int e = threadIdx.x >> 6;
    const int lane = threadIdx.x & 63;
    __shared__ int scnt[E_], sseg[E_];
    int c = 0;
    for (int t0 = 0; t0 < T_; t0 += 64) {
        const float v = gw[(size_t)(t0 + lane) * E_ + e];
        c += __popcll(__ballot(v > 0.f));
    }
    if (lane == 0) scnt[e] = c;
    __syncthreads();
    if (threadIdx.x == 0) {
        int off = 0;
        for (int q = 0; q < E_; q++) {
            sseg[q] = off; cnt[q] = scnt[q]; seg[q] = off;
            off += (scnt[q] + 127) & ~127;
        }
    }
    __syncthreads();
    int p = sseg[e];
    for (int t0 = 0; t0 < T_; t0 += 64) {
        const int t = t0 + lane;
        const float v = gw[(size_t)t * E_ + e];
        const unsigned long long m = __ballot(v > 0.f);
        if (v > 0.f) {
            const int pp = p + __popcll(m & ((1ull << lane) - 1ull));
            idx[pp] = t; wl[pp] = v;
            int slot = 0;
            for (int q = 0; q < e; q++) slot += (gw[(size_t)t * E_ + q] > 0.f) ? 1 : 0;
            pos[t * 2 + slot] = pp;
        }
        p += __popcll(m);
    }
}

// ---------------- combine ----------------
__global__ void k_combine(float* __restrict__ x, const float* __restrict__ ebuf,
                          const float* __restrict__ wl, const int* __restrict__ pos)
{
    const int id = blockIdx.x * 256 + threadIdx.x;
    const int t = id >> 10;
    const int hc = id & 1023;
    const int p0 = pos[t * 2], p1 = pos[t * 2 + 1];
    x[id] += wl[p0] * ebuf[(size_t)p0 * H_ + hc] + wl[p1] * ebuf[(size_t)p1 * H_ + hc];
}

// ---------------- bf16-input MFMA GEMM (lm_head), XCD-swizzled ----------------
__global__ __launch_bounds__(256)
void k_mfma_bt_b(const short* __restrict__ A, const short* __restrict__ Bm,
                 float* __restrict__ C, int M, int N, int K)
{
    __shared__ short Als[128 * LDST];
    __shared__ short Bls[128 * LDST];
    const int mB = M >> 7;
    const int nwg = mB * (N >> 7);
    int l = blockIdx.x;
    l = (l & 7) * (nwg >> 3) + (l >> 3);     // bijective XCD swizzle (nwg % 8 == 0)
    const int g  = l / (mB * 8);
    const int ii = l - g * (mB * 8);
    const int bm0 = (ii % mB) * 128;
    const int bn0 = (g * 8 + ii / mB) * 128;

    const int tid  = threadIdx.x;
    const int lane = tid & 63, w = tid >> 6;
    const int wr = w >> 1, wc = w & 1;
    const int fr = lane & 15, fg = lane >> 4;
    const int srow = tid >> 1, sk = (tid & 1) * 16;

    const short* pa = A  + (size_t)(bm0 + srow) * K + sk;
    const short* pb = Bm + (size_t)(bn0 + srow) * K + sk;

    f32x4 acc[4][4];
    #pragma unroll
    for (int m = 0; m < 4; m++)
        #pragma unroll
        for (int n = 0; n < 4; n++) acc[m][n] = (f32x4){0.f, 0.f, 0.f, 0.f};

    s16x8 ra0 = *reinterpret_cast<const s16x8*>(pa);
    s16x8 ra1 = *reinterpret_cast<const s16x8*>(pa + 8);
    s16x8 rb0 = *reinterpret_cast<const s16x8*>(pb);
    s16x8 rb1 = *reinterpret_cast<const s16x8*>(pb + 8);

    for (int k0 = 0; k0 < K; k0 += 32) {
        __syncthreads();
        *reinterpret_cast<s16x8*>(&Als[srow * LDST + sk])     = ra0;
        *reinterpret_cast<s16x8*>(&Als[srow * LDST + sk + 8]) = ra1;
        *reinterpret_cast<s16x8*>(&Bls[srow * LDST + sk])     = rb0;
        *reinterpret_cast<s16x8*>(&Bls[srow * LDST + sk + 8]) = rb1;
        __syncthreads();
        if (k0 + 32 < K) {
            ra0 = *reinterpret_cast<const s16x8*>(pa + k0 + 32);
            ra1 = *reinterpret_cast<const s16x8*>(pa + k0 + 40);
            rb0 = *reinterpret_cast<const s16x8*>(pb + k0 + 32);
            rb1 = *reinterpret_cast<const s16x8*>(pb + k0 + 40);
        }
        s16x8 af[4], bfv[4];
        #pragma unroll
        for (int m = 0; m < 4; m++)
            af[m] = ldfrag(&Als[(wr * 64 + m * 16 + fr) * LDST + fg * 4]);
        #pragma unroll
        for (int n = 0; n < 4; n++)
            bfv[n] = ldfrag(&Bls[(wc * 64 + n * 16 + fr) * LDST + fg * 4]);
        #pragma unroll
        for (int m = 0; m < 4; m++)
            #pragma unroll
            for (int n = 0; n < 4; n++)
                acc[m][n] = __builtin_amdgcn_mfma_f32_16x16x32_bf16(af[m], bfv[n], acc[m][n], 0, 0, 0);
    }

    #pragma unroll
    for (int m = 0; m < 4; m++)
        #pragma unroll
        for (int n = 0; n < 4; n++)
            #pragma unroll
            for (int r = 0; r < 4; r++) {
                const int row = bm0 + wr * 64 + m * 16 + fg * 4 + r;
                const int col = bn0 + wc * 64 + n * 16 + fr;
                C[(size_t)row * N + col] = acc[m][n][r];
            }
}

// ---------------- bf16-input MFMA MoE GEMM (L2 value path) ----------------
template<int MODE, int EPI>
__global__ __launch_bounds__(256)
void k_mfma_moe_b(const short* __restrict__ A, const short* __restrict__ Bm,
                  float* __restrict__ Cf, short* __restrict__ Cbf,
                  const int* __restrict__ idx, const int* __restrict__ cnt,
                  const int* __restrict__ seg, int N, int K)
{
    int c = T_, s = 0;
    const int bm0 = blockIdx.y * 128, bn0 = blockIdx.x * 128;
    if (MODE >= 1) {
        const int e = blockIdx.z;
        c = cnt[e];
        if (bm0 >= c) return;
        s = seg[e];
        Bm += (size_t)e * N * K;
    }
    __shared__ short Als[128 * LDST];
    __shared__ short Bls[128 * LDST];
    const int tid  = threadIdx.x;
    const int lane = tid & 63, w = tid >> 6;
    const int wr = w >> 1, wc = w & 1;
    const int fr = lane & 15, fg = lane >> 4;
    const int srow = tid >> 1, sk = (tid & 1) * 16;

    int arow;
    if (MODE == 0)      arow = bm0 + srow;
    else if (MODE == 1) arow = idx[s + min(bm0 + srow, c - 1)];
    else                arow = s + min(bm0 + srow, c - 1);
    const short* pa = A  + (size_t)arow * K + sk;
    const short* pb = Bm + (size_t)(bn0 + srow) * K + sk;

    f32x4 acc[4][4];
    #pragma unroll
    for (int m = 0; m < 4; m++)
        #pragma unroll
        for (int n = 0; n < 4; n++) acc[m][n] = (f32x4){0.f, 0.f, 0.f, 0.f};

    s16x8 ra0 = *reinterpret_cast<const s16x8*>(pa);
    s16x8 ra1 = *reinterpret_cast<const s16x8*>(pa + 8);
    s16x8 rb0 = *reinterpret_cast<const s16x8*>(pb);
    s16x8 rb1 = *reinterpret_cast<const s16x8*>(pb + 8);

    for (int k0 = 0; k0 < K; k0 += 32) {
        __syncthreads();
        *reinterpret_cast<s16x8*>(&Als[srow * LDST + sk])     = ra0;
        *reinterpret_cast<s16x8*>(&Als[srow * LDST + sk + 8]) = ra1;
        *reinterpret_cast<s16x8*>(&Bls[srow * LDST + sk])     = rb0;
        *reinterpret_cast<s16x8*>(&Bls[srow * LDST + sk + 8]) = rb1;
        __syncthreads();
        if (k0 + 32 < K) {
            ra0 = *reinterpret_cast<const s16x8*>(pa + k0 + 32);
            ra1 = *reinterpret_cast<const s16x8*>(pa + k0 + 40);
            rb0 = *reinterpret_cast<const s16x8*>(pb + k0 + 32);
            rb1 = *reinterpret_cast<const s16x8*>(pb + k0 + 40);
        }
        s16x8 af[4], bfv[4];
        #pragma unroll
        for (int m = 0; m < 4; m++)
            af[m] = ldfrag(&Als[(wr * 64 + m * 16 + fr) * LDST + fg * 4]);
        #pragma unroll
        for (int n = 0; n < 4; n++)
            bfv[n] = ldfrag(&Bls[(wc * 64 + n * 16 + fr) * LDST + fg * 4]);
        #pragma unroll
        for (int m = 0; m < 4; m++)
            #pragma unroll
            for (int n = 0; n < 4; n++)
                acc[m][n] = __builtin_amdgcn_mfma_f32_16x16x32_bf16(af[m], bfv[n], acc[m][n], 0, 0, 0);
    }

    #pragma unroll
    for (int m = 0; m < 4; m++)
        #pragma unroll
        for (int n = 0; n < 4; n++)
            #pragma unroll
            for (int r = 0; r < 4; r++) {
                const int row = bm0 + wr * 64 + m * 16 + fg * 4 + r;
                if (MODE >= 1 && row >= c) continue;
                const int col = bn0 + wc * 64 + n * 16 + fr;
                const size_t p = (size_t)((MODE >= 1 ? s : 0) + row) * N + col;
                if (EPI == 0)      Cf[p] = acc[m][n][r];
                else if (EPI == 1) {
                    const float gv = Cf[p];
                    Cbf[p] = f2bf(gv * (1.f / (1.f + expf(-gv))) * acc[m][n][r]);
                } else               Cf[p] += acc[m][n][r];
            }
}

// ---------------- split-bf16-input MFMA GEMM (routing-safe) ----------------
template<int MODE, int EPI>
__global__ __launch_bounds__(256)
void k_mfma_sp_b(const short* __restrict__ Ah, const short* __restrict__ Alp,
                 const short* __restrict__ Bh, const short* __restrict__ Blp,
                 float* __restrict__ Cf, short* __restrict__ Chi, short* __restrict__ Clo,
                 const int* __restrict__ idx, const int* __restrict__ cnt,
                 const int* __restrict__ seg, int N, int K)
{
    int c = T_, s = 0;
    const int bm0 = blockIdx.y * 128, bn0 = blockIdx.x * 128;
    if (MODE >= 1) {
        const int e = blockIdx.z;
        c = cnt[e];
        if (bm0 >= c) return;
        s = seg[e];
        Bh  += (size_t)e * N * K;
        Blp += (size_t)e * N * K;
    }
    __shared__ short LAh[128 * LDST];
    __shared__ short LAl[128 * LDST];
    __shared__ short LBh[128 * LDST];
    __shared__ short LBl[128 * LDST];
    const int tid  = threadIdx.x;
    const int lane = tid & 63, w = tid >> 6;
    const int wr = w >> 1, wc = w & 1;
    const int fr = lane & 15, fg = lane >> 4;
    const int srow = tid >> 1, sk = (tid & 1) * 16;

    int arow;
    if (MODE == 0)      arow = bm0 + srow;
    else if (MODE == 1) arow = idx[s + min(bm0 + srow, c - 1)];
    else                arow = s + min(bm0 + srow, c - 1);
    const short* pah = Ah  + (size_t)arow * K + sk;
    const short* pal = Alp + (size_t)arow * K + sk;
    const short* pbh = Bh  + (size_t)(bn0 + srow) * K + sk;
    const short* pbl = Blp + (size_t)(bn0 + srow) * K + sk;

    f32x4 acc[4][4];
    #pragma unroll
    for (int m = 0; m < 4; m++)
        #pragma unroll
        for (int n = 0; n < 4; n++) acc[m][n] = (f32x4){0.f, 0.f, 0.f, 0.f};

    s16x8 rah0 = *reinterpret_cast<const s16x8*>(pah);
    s16x8 rah1 = *reinterpret_cast<const s16x8*>(pah + 8);
    s16x8 ral0 = *reinterpret_cast<const s16x8*>(pal);
    s16x8 ral1 = *reinterpret_cast<const s16x8*>(pal + 8);
    s16x8 rbh0 = *reinterpret_cast<const s16x8*>(pbh);
    s16x8 rbh1 = *reinterpret_cast<const s16x8*>(pbh + 8);
    s16x8 rbl0 = *reinterpret_cast<const s16x8*>(pbl);
    s16x8 rbl1 = *reinterpret_cast<const s16x8*>(pbl + 8);

    for (int k0 = 0; k0 < K; k0 += 32) {
        __syncthreads();
        *reinterpret_cast<s16x8*>(&LAh[srow * LDST + sk])     = rah0;
        *reinterpret_cast<s16x8*>(&LAh[srow * LDST + sk + 8]) = rah1;
        *reinterpret_cast<s16x8*>(&LAl[srow * LDST + sk])     = ral0;
        *reinterpret_cast<s16x8*>(&LAl[srow * LDST + sk + 8]) = ral1;
        *reinterpret_cast<s16x8*>(&LBh[srow * LDST + sk])     = rbh0;
        *reinterpret_cast<s16x8*>(&LBh[srow * LDST + sk + 8]) = rbh1;
        *reinterpret_cast<s16x8*>(&LBl[srow * LDST + sk])     = rbl0;
        *reinterpret_cast<s16x8*>(&LBl[srow * LDST + sk + 8]) = rbl1;
        __syncthreads();
        if (k0 + 32 < K) {
            rah0 = *reinterpret_cast<const s16x8*>(pah + k0 + 32);
            rah1 = *reinterpret_cast<const s16x8*>(pah + k0 + 40);
            ral0 = *reinterpret_cast<const s16x8*>(pal + k0 + 32);
            ral1 = *reinterpret_cast<const s16x8*>(pal + k0 + 40);
            rbh0 = *reinterpret_cast<const s16x8*>(pbh + k0 + 32);
            rbh1 = *reinterpret_cast<const s16x8*>(pbh + k0 + 40);
            rbl0 = *reinterpret_cast<const s16x8*>(pbl + k0 + 32);
            rbl1 = *reinterpret_cast<const s16x8*>(pbl + k0 + 40);
        }
        s16x8 afh[4], afl[4];
        #pragma unroll
        for (int m = 0; m < 4; m++) {
            afh[m] = ldfrag(&LAh[(wr * 64 + m * 16 + fr) * LDST + fg * 4]);
            afl[m] = ldfrag(&LAl[(wr * 64 + m * 16 + fr) * LDST + fg * 4]);
        }
        #pragma unroll
        for (int n = 0; n < 4; n++) {
            const s16x8 bh = ldfrag(&LBh[(wc * 64 + n * 16 + fr) * LDST + fg * 4]);
            const s16x8 bl = ldfrag(&LBl[(wc * 64 + n * 16 + fr) * LDST + fg * 4]);
            #pragma unroll
            for (int m = 0; m < 4; m++) {
                acc[m][n] = __builtin_amdgcn_mfma_f32_16x16x32_bf16(afh[m], bh, acc[m][n], 0, 0, 0);
                acc[m][n] = __builtin_amdgcn_mfma_f32_16x16x32_bf16(afl[m], bh, acc[m][n], 0, 0, 0);
                acc[m][n] = __builtin_amdgcn_mfma_f32_16x16x32_bf16(afh[m], bl, acc[m][n], 0, 0, 0);
            }
        }
    }

    #pragma unroll
    for (int m = 0; m < 4; m++)
        #pragma unroll
        for (int n = 0; n < 4; n++)
            #pragma unroll
            for (int r = 0; r < 4; r++) {
                const int row = bm0 + wr * 64 + m * 16 + fg * 4 + r;
                if (MODE >= 1 && row >= c) continue;
                const int col = bn0 + wc * 64 + n * 16 + fr;
                const size_t p = (size_t)((MODE >= 1 ? s : 0) + row) * N + col;
                if (EPI == 0)      Cf[p] = acc[m][n][r];
                else if (EPI == 1) {
                    const float gv = Cf[p];
                    const float pr = gv * (1.f / (1.f + expf(-gv))) * acc[m][n][r];
                    const short hh = f2bf(pr);
                    Chi[p] = hh;
                    Clo[p] = f2bf(pr - bf2f(hh));
                } else               Cf[p] += acc[m][n][r];
            }
}

extern "C" void kernel_launch(void* const* d_in, const int* in_sizes, int n_in,
                              void* d_out, int out_size, void* d_ws, size_t ws_size,
                              hipStream_t stream)
{
    const int*   ids    = (const int*)  d_in[0];
    const float* embed  = (const float*)d_in[1];
    const float* ln1_g  = (const float*)d_in[2];
    const float* ln1_b  = (const float*)d_in[3];
    const float* wq     = (const float*)d_in[4];
    const float* wk     = (const float*)d_in[5];
    const float* wv     = (const float*)d_in[6];
    const float* wo     = (const float*)d_in[7];
    const float* ln2_g  = (const float*)d_in[8];
    const float* ln2_b  = (const float*)d_in[9];
    const float* gate_w = (const float*)d_in[10];
    const float* exp_wg = (const float*)d_in[11];
    const float* exp_wu = (const float*)d_in[12];
    const float* exp_wd = (const float*)d_in[13];
    const float* sh_wg  = (const float*)d_in[14];
    const float* sh_wu  = (const float*)d_in[15];
    const float* sh_wd  = (const float*)d_in[16];
    const float* fn_g   = (const float*)d_in[17];
    const float* fn_b   = (const float*)d_in[18];
    const float* lm     = (const float*)d_in[19];
    float* out = (float*)d_out;

    float* x    = (float*)d_ws;                 // T*H
    float* h    = x + 2097152;                  // T*H
    float* qkvp = h + 2097152;                  // R1: [T][1536] (3.15M) ; ebuf aliases (5.24M)
    float* ebuf = qkvp;
    float* gbuf = qkvp + 5242880;               // CAP*I f32
    float* gw   = gbuf + 5242880;               // T*8
    float* wl   = gw + (size_t)T_ * E_;         // CAP
    int*   idx  = (int*)(wl + CAP_);            // CAP
    int*   pos  = idx + CAP_;                   // T*2
    int*   cnt  = pos + 2 * T_;                 // 8
    int*   seg  = cnt + E_;                     // 8 (+pad)
    short* hhi  = (short*)(seg + 64);           // T*H
    short* hlo  = hhi + 2097152;
    short* hbf  = hlo + 2097152;
    short* obh  = hbf + 2097152;                // attn O hi
    short* obl  = obh + 2097152;                // attn O lo
    short* gbh  = obl + 2097152;                // CAP*I
    short* gbl  = gbh + 5242880;                // CAP*I
    short* wb   = gbl + 5242880;                // 56.6M shorts, phase-reused
    const size_t EW = (size_t)E_ * I_ * H_;     // 8,388,608

    // attention-phase scratch inside wb
    short* qkvwh = wb;                          // [1536][1024] hi
    short* qkvwl = wb + 1572864;                // lo
    short* wowh  = wb + 3145728;                // [1024][1024] hi
    short* wowl  = wb + 4194304;                // lo
    short* khi_p = wb + 5242880;
    short* klo_p = khi_p + 524288;
    short* vth_p = klo_p + 524288;
    short* vtl_p = vth_p + 524288;

    k_embed<<<T_, 256, 0, stream>>>(ids, embed, x);

    for (int l = 0; l < L_; l++) {
        k_layernorm<2><<<T_, 256, 0, stream>>>(x, ln1_g + (size_t)l * H_, ln1_b + (size_t)l * H_, h, hhi, hlo);

        // weights -> transposed split bf16 (per layer)
        k_cvt_sp_t<<<dim3(16, 16), 256, 0, stream>>>(wq + (size_t)l * H_ * H_,   qkvwh,                qkvwl,                H_,  H_);
        k_cvt_sp_t<<<dim3(4, 16),  256, 0, stream>>>(wk + (size_t)l * H_ * 256,  qkvwh + 1024 * 1024,  qkvwl + 1024 * 1024,  256, H_);
        k_cvt_sp_t<<<dim3(4, 16),  256, 0, stream>>>(wv + (size_t)l * H_ * 256,  qkvwh + 1280 * 1024,  qkvwl + 1280 * 1024,  256, H_);
        k_cvt_sp_t<<<dim3(16, 16), 256, 0, stream>>>(wo + (size_t)l * H_ * H_,   wowh,                 wowl,                 H_,  H_);

        // fused qkv projection (split-MFMA) -> packed [T][1536]
        k_mfma_sp_b<0, 0><<<dim3(QKVN / 128, 16, 1), 256, 0, stream>>>(
            hhi, hlo, qkvwh, qkvwl, qkvp, nullptr, nullptr, nullptr, nullptr, nullptr, QKVN, H_);

        k_rope<<<(T_ * NH_  * 32) / 256, 256, 0, stream>>>(qkvp,        QKVN, NH_);
        k_rope<<<(T_ * NKV_ * 32) / 256, 256, 0, stream>>>(qkvp + 1024, QKVN, NKV_);

        k_cvt_kv<<<B_ * NKV_ * (S_ / 64), 256, 0, stream>>>(qkvp, khi_p, klo_p, vth_p, vtl_p);
        k_attn_mfma<<<dim3(S_ / 64, NH_, B_), 256, 0, stream>>>(qkvp, khi_p, klo_p, vth_p, vtl_p, obh, obl);

        // wo projection (split-MFMA), accumulate into residual
        k_mfma_sp_b<0, 2><<<dim3(8, 16, 1), 256, 0, stream>>>(
            obh, obl, wowh, wowl, x, nullptr, nullptr, nullptr, nullptr, nullptr, H_, H_);

        if (l == 0)
            k_layernorm<2><<<T_, 256, 0, stream>>>(x, ln2_g + (size_t)l * H_, ln2_b + (size_t)l * H_, h, hhi, hlo);
        else
            k_layernorm<1><<<T_, 256, 0, stream>>>(x, ln2_g + (size_t)l * H_, ln2_b + (size_t)l * H_, h, hbf, nullptr);
        k_gate<<<T_, 64, 0, stream>>>(h, gate_w + (size_t)l * E_ * H_, gw);
        k_build<<<1, 512, 0, stream>>>(gw, idx, wl, pos, cnt, seg);

        const float* wg_l = exp_wg + (size_t)l * EW;
        const float* wu_l = exp_wu + (size_t)l * EW;
        const float* wd_l = exp_wd + (size_t)l * EW;
        const float* sg_l = sh_wg + (size_t)l * I_ * H_;
        const float* su_l = sh_wu + (size_t)l * I_ * H_;
        const float* sd_l = sh_wd + (size_t)l * H_ * I_;

        if (l == 0) {
            short* wgh = wb;            short* wgl = wb + EW;
            short* wuh = wb + 2 * EW;   short* wul = wb + 3 * EW;
            short* wdh = wb + 4 * EW;   short* wdl = wb + 5 * EW;
            short* sgh = wb + 6 * EW;   short* sgl = sgh + 1048576;
            short* suh = sgl + 1048576; short* sul = suh + 1048576;
            short* sdh = sul + 1048576; short* sdl = sdh + 1048576;

            k_cvt_sp<<<4096, 256, 0, stream>>>(wg_l, wgh, wgl, (int)(EW / 8));
            k_cvt_sp<<<4096, 256, 0, stream>>>(wu_l, wuh, wul, (int)(EW / 8));
            k_cvt_sp<<<4096, 256, 0, stream>>>(wd_l, wdh, wdl, (int)(EW / 8));
            k_cvt_sp<<<512,  256, 0, stream>>>(sg_l, sgh, sgl, 131072);
            k_cvt_sp<<<512,  256, 0, stream>>>(su_l, suh, sul, 131072);
            k_cvt_sp<<<512,  256, 0, stream>>>(sd_l, sdh, sdl, 131072);

            k_mfma_sp_b<0, 0><<<dim3(8, 16, 1), 256, 0, stream>>>(hhi, hlo, sgh, sgl, gbuf, nullptr, nullptr, nullptr, nullptr, nullptr, I_, H_);
            k_mfma_sp_b<0, 1><<<dim3(8, 16, 1), 256, 0, stream>>>(hhi, hlo, suh, sul, gbuf, gbh, gbl, nullptr, nullptr, nullptr, I_, H_);
            k_mfma_sp_b<0, 2><<<dim3(8, 16, 1), 256, 0, stream>>>(gbh, gbl, sdh, sdl, x, nullptr, nullptr, nullptr, nullptr, nullptr, H_, I_);
            k_mfma_sp_b<1, 0><<<dim3(8, 16, E_), 256, 0, stream>>>(hhi, hlo, wgh, wgl, gbuf, nullptr, nullptr, idx, cnt, seg, I_, H_);
            k_mfma_sp_b<1, 1><<<dim3(8, 16, E_), 256, 0, stream>>>(hhi, hlo, wuh, wul, gbuf, gbh, gbl, idx, cnt, seg, I_, H_);
            k_mfma_sp_b<2, 0><<<dim3(8, 16, E_), 256, 0, stream>>>(gbh, gbl, wdh, wdl, ebuf, nullptr, nullptr, idx, cnt, seg, H_, I_);
        } else {
            short* wgb = wb;            short* wub = wb + EW;       short* wdb = wb + 2 * EW;
            short* sgb = wb + 3 * EW;   short* sub = sgb + 1048576; short* sdb = sub + 1048576;

            k_cvt<<<4096, 256, 0, stream>>>(wg_l, wgb, (int)(EW / 8));
            k_cvt<<<4096, 256, 0, stream>>>(wu_l, wub, (int)(EW / 8));
            k_cvt<<<4096, 256, 0, stream>>>(wd_l, wdb, (int)(EW / 8));
            k_cvt<<<512,  256, 0, stream>>>(sg_l, sgb, 131072);
            k_cvt<<<512,  256, 0, stream>>>(su_l, sub, 131072);
            k_cvt<<<512,  256, 0, stream>>>(sd_l, sdb, 131072);

            k_mfma_moe_b<0, 0><<<dim3(8, 16, 1), 256, 0, stream>>>(hbf, sgb, gbuf, nullptr, nullptr, nullptr, nullptr, I_, H_);
            k_mfma_moe_b<0, 1><<<dim3(8, 16, 1), 256, 0, stream>>>(hbf, sub, gbuf, gbh, nullptr, nullptr, nullptr, I_, H_);
            k_mfma_moe_b<0, 2><<<dim3(8, 16, 1), 256, 0, stream>>>(gbh, sdb, x, nullptr, nullptr, nullptr, nullptr, H_, I_);
            k_mfma_moe_b<1, 0><<<dim3(8, 16, E_), 256, 0, stream>>>(hbf, wgb, gbuf, nullptr, idx, cnt, seg, I_, H_);
            k_mfma_moe_b<1, 1><<<dim3(8, 16, E_), 256, 0, stream>>>(hbf, wub, gbuf, gbh, idx, cnt, seg, I_, H_);
            k_mfma_moe_b<2, 0><<<dim3(8, 16, E_), 256, 0, stream>>>(gbh, wdb, ebuf, nullptr, idx, cnt, seg, H_, I_);
        }
        k_combine<<<(T_ * H_) / 256, 256, 0, stream>>>(x, ebuf, wl, pos);
    }

    k_layernorm<1><<<T_, 256, 0, stream>>>(x, fn_g, fn_b, h, hbf, nullptr);
    k_cvt<<<16000, 256, 0, stream>>>(lm, wb, 4096000);
    k_mfma_bt_b<<<(T_ / 128) * (V_ / 128), 256, 0, stream>>>(hbf, wb, out, T_, V_, H_);
}

// Round 12
// 1557.352 us; speedup vs baseline: 7.6880x; 1.1938x over previous
//
#include <hip/hip_runtime.h>
#include <cmath>

#define L_   2
#define E_   8
#define NH_  16
#define NKV_ 4
#define HD_  64
#define H_   1024
#define I_   1024
#define B_   2
#define S_   1024
#define T_   (B_*S_)
#define V_   32000
#define CAP_ 5120
#define QKVN 1536
#define LDST 36   // LDS row stride (shorts) for BK=32 tiles
#define LD64 72   // LDS row stride (shorts) for BK=64 tiles
#define AST  72   // LDS row stride (shorts) for attention tiles

typedef float f32x4 __attribute__((ext_vector_type(4)));
typedef short s16x4 __attribute__((ext_vector_type(4)));
typedef short s16x8 __attribute__((ext_vector_type(8)));

__device__ __forceinline__ short f2bf(float f) {
    unsigned u = __float_as_uint(f);
    u = (u + 0x7fffu + ((u >> 16) & 1u)) >> 16;   // RNE
    return (short)u;
}
__device__ __forceinline__ float bf2f(short h) {
    return __uint_as_float(((unsigned)(unsigned short)h) << 16);
}
__device__ __forceinline__ s16x8 ldfrag(const short* p) {
    s16x4 lo = *reinterpret_cast<const s16x4*>(p);
    s16x4 hi = *reinterpret_cast<const s16x4*>(p + 16);
    return __builtin_shufflevector(lo, hi, 0, 1, 2, 3, 4, 5, 6, 7);
}

// ---------------- converters ----------------
__global__ __launch_bounds__(256)
void k_cvt(const float* __restrict__ s, short* __restrict__ d, int n8)
{
    const int i = blockIdx.x * 256 + threadIdx.x;
    if (i >= n8) return;
    const float4 a = *reinterpret_cast<const float4*>(s + (size_t)i * 8);
    const float4 b = *reinterpret_cast<const float4*>(s + (size_t)i * 8 + 4);
    s16x8 o;
    o[0]=f2bf(a.x); o[1]=f2bf(a.y); o[2]=f2bf(a.z); o[3]=f2bf(a.w);
    o[4]=f2bf(b.x); o[5]=f2bf(b.y); o[6]=f2bf(b.z); o[7]=f2bf(b.w);
    *reinterpret_cast<s16x8*>(d + (size_t)i * 8) = o;
}

__global__ __launch_bounds__(256)
void k_cvt_sp(const float* __restrict__ s, short* __restrict__ dh, short* __restrict__ dl, int n8)
{
    const int i = blockIdx.x * 256 + threadIdx.x;
    if (i >= n8) return;
    const float4 a = *reinterpret_cast<const float4*>(s + (size_t)i * 8);
    const float4 b = *reinterpret_cast<const float4*>(s + (size_t)i * 8 + 4);
    float v[8] = {a.x, a.y, a.z, a.w, b.x, b.y, b.z, b.w};
    s16x8 oh, ol;
    #pragma unroll
    for (int j = 0; j < 8; j++) {
        const short hh = f2bf(v[j]);
        oh[j] = hh;
        ol[j] = f2bf(v[j] - bf2f(hh));
    }
    *reinterpret_cast<s16x8*>(dh + (size_t)i * 8) = oh;
    *reinterpret_cast<s16x8*>(dl + (size_t)i * 8) = ol;
}

// ---------------- transposing split converter ----------------
__global__ __launch_bounds__(256)
void k_cvt_sp_t(const float* __restrict__ w, short* __restrict__ oh, short* __restrict__ ol,
                int N, int K)
{
    const int n0 = blockIdx.x * 64, k0 = blockIdx.y * 64;
    const int r = threadIdx.x >> 2, c0 = (threadIdx.x & 3) * 16;
    __shared__ float Tt[64][65];
    const float* src = w + (size_t)(k0 + r) * N + n0 + c0;
    #pragma unroll
    for (int g = 0; g < 4; g++) {
        const float4 a = *reinterpret_cast<const float4*>(src + g * 4);
        Tt[c0 + g*4 + 0][r] = a.x; Tt[c0 + g*4 + 1][r] = a.y;
        Tt[c0 + g*4 + 2][r] = a.z; Tt[c0 + g*4 + 3][r] = a.w;
    }
    __syncthreads();
    const size_t o = (size_t)(n0 + r) * K + k0 + c0;
    #pragma unroll
    for (int g = 0; g < 2; g++) {
        s16x8 vh, vl;
        #pragma unroll
        for (int j = 0; j < 8; j++) {
            const float v = Tt[r][c0 + g * 8 + j];
            const short hh = f2bf(v);
            vh[j] = hh; vl[j] = f2bf(v - bf2f(hh));
        }
        *reinterpret_cast<s16x8*>(oh + o + g * 8) = vh;
        *reinterpret_cast<s16x8*>(ol + o + g * 8) = vl;
    }
}

// ---------------- K/V -> split bf16 ----------------
__global__ __launch_bounds__(256)
void k_cvt_kv(const float* __restrict__ qkvp,
              short* __restrict__ khi, short* __restrict__ klo,
              short* __restrict__ vth, short* __restrict__ vtl)
{
    const int blk = blockIdx.x;
    const int s0  = (blk & 15) * 64;
    const int kvh = (blk >> 4) & 3;
    const int b   = blk >> 6;
    const int tid = threadIdx.x;
    const int r = tid >> 2, c0 = (tid & 3) * 16;
    __shared__ float Vt[64][65];

    const float* kp = qkvp + (size_t)(b * S_ + s0 + r) * QKVN + 1024 + kvh * 64 + c0;
    const size_t ko = ((size_t)(b * 4 + kvh) * S_ + s0 + r) * 64 + c0;
    #pragma unroll
    for (int g = 0; g < 2; g++) {
        const float4 a = *reinterpret_cast<const float4*>(kp + g * 8);
        const float4 bq = *reinterpret_cast<const float4*>(kp + g * 8 + 4);
        float v[8] = {a.x, a.y, a.z, a.w, bq.x, bq.y, bq.z, bq.w};
        s16x8 oh, ol;
        #pragma unroll
        for (int j = 0; j < 8; j++) {
            const short hh = f2bf(v[j]);
            oh[j] = hh; ol[j] = f2bf(v[j] - bf2f(hh));
        }
        *reinterpret_cast<s16x8*>(khi + ko + g * 8) = oh;
        *reinterpret_cast<s16x8*>(klo + ko + g * 8) = ol;
    }
    const float* vp = kp + 256;
    #pragma unroll
    for (int g = 0; g < 4; g++) {
        const float4 a = *reinterpret_cast<const float4*>(vp + g * 4);
        Vt[c0 + g*4 + 0][r] = a.x; Vt[c0 + g*4 + 1][r] = a.y;
        Vt[c0 + g*4 + 2][r] = a.z; Vt[c0 + g*4 + 3][r] = a.w;
    }
    __syncthreads();
    const size_t vo = ((size_t)(b * 4 + kvh) * 64 + r) * S_ + s0 + c0;
    #pragma unroll
    for (int g = 0; g < 2; g++) {
        s16x8 oh, ol;
        #pragma unroll
        for (int j = 0; j < 8; j++) {
            const float v = Vt[r][c0 + g * 8 + j];
            const short hh = f2bf(v);
            oh[j] = hh; ol[j] = f2bf(v - bf2f(hh));
        }
        *reinterpret_cast<s16x8*>(vth + vo + g * 8) = oh;
        *reinterpret_cast<s16x8*>(vtl + vo + g * 8) = ol;
    }
}

// ---------------- embedding ----------------
__global__ void k_embed(const int* __restrict__ ids, const float* __restrict__ emb,
                        float* __restrict__ x)
{
    const int t = blockIdx.x;
    const float* src = emb + (size_t)ids[t] * H_;
    float* dst = x + (size_t)t * H_;
    for (int i = threadIdx.x; i < H_; i += 256) dst[i] = src[i];
}

// ---------------- layernorm (OMODE 0: f32 | 1: +bf16 | 2: +hi/lo split) ----------------
template<int OMODE>
__global__ __launch_bounds__(256)
void k_layernorm(const float* __restrict__ x, const float* __restrict__ g,
                 const float* __restrict__ bb, float* __restrict__ out,
                 short* __restrict__ oh, short* __restrict__ ol)
{
    const int t = blockIdx.x;
    const float* row = x + (size_t)t * H_;
    float s = 0.f, ss = 0.f;
    for (int i = threadIdx.x; i < H_; i += 256) { const float v = row[i]; s += v; ss += v * v; }
    #pragma unroll
    for (int off = 32; off > 0; off >>= 1) {
        s  += __shfl_down(s, off, 64);
        ss += __shfl_down(ss, off, 64);
    }
    __shared__ float shs[4], shss[4];
    const int w = threadIdx.x >> 6;
    if ((threadIdx.x & 63) == 0) { shs[w] = s; shss[w] = ss; }
    __syncthreads();
    const float fs  = shs[0] + shs[1] + shs[2] + shs[3];
    const float fss = shss[0] + shss[1] + shss[2] + shss[3];
    const float mean = fs * (1.f / H_);
    const float var  = fss * (1.f / H_) - mean * mean;
    const float rstd = 1.0f / sqrtf(var + 1e-5f);
    float* orow = out + (size_t)t * H_;
    for (int i = threadIdx.x; i < H_; i += 256) {
        const float v = (row[i] - mean) * rstd * g[i] + bb[i];
        orow[i] = v;
        if (OMODE == 1) {
            oh[(size_t)t * H_ + i] = f2bf(v);
        } else if (OMODE == 2) {
            const short hh = f2bf(v);
            oh[(size_t)t * H_ + i] = hh;
            ol[(size_t)t * H_ + i] = f2bf(v - bf2f(hh));
        }
    }
}

// ---------------- RoPE ----------------
__global__ void k_rope(float* __restrict__ x, int rowStride, int nheads)
{
    const int idx  = blockIdx.x * 256 + threadIdx.x;
    const int i    = idx & 31;
    const int rest = idx >> 5;
    const int head = rest % nheads;
    const int t    = rest / nheads;
    const int pos  = t & (S_ - 1);
    const float p32  = (float)pow(1.0e6, (double)i / 32.0);
    const float invf = 1.0f / p32;
    const float ang  = (float)pos * invf;
    const float c = (float)cos((double)ang);
    const float s = (float)sin((double)ang);
    float* base = x + (size_t)t * rowStride + head * HD_;
    const float x1 = base[i];
    const float x2 = base[i + 32];
    base[i]      = x1 * c - x2 * s;
    base[i + 32] = x2 * c + x1 * s;
}

// ---------------- split-bf16 MFMA flash attention ----------------
__global__ __launch_bounds__(256)
void k_attn_mfma(const float* __restrict__ q,
                 const short* __restrict__ khi, const short* __restrict__ klo,
                 const short* __restrict__ vth, const short* __restrict__ vtl,
                 short* __restrict__ obh, short* __restrict__ obl)
{
    const int q0 = blockIdx.x * 64, h = blockIdx.y, b = blockIdx.z;
    const int kvh = h >> 2;
    const int tid = threadIdx.x, lane = tid & 63, w = tid >> 6;
    const int fr = lane & 15, fg = lane >> 4;

    __shared__ short Qh[64 * AST], Ql[64 * AST];
    __shared__ short Kh[64 * AST], Kl[64 * AST];
    __shared__ short Vh[64 * AST], Vl[64 * AST];
    __shared__ short Ph[64 * AST], Pl[64 * AST];

    {
        const int r = tid >> 2, c0 = (tid & 3) * 16;
        const float* qs = q + (size_t)(b * S_ + q0 + r) * QKVN + h * HD_ + c0;
        #pragma unroll
        for (int g = 0; g < 2; g++) {
            const float4 a = *reinterpret_cast<const float4*>(qs + g * 8);
            const float4 bq = *reinterpret_cast<const float4*>(qs + g * 8 + 4);
            float v[8] = {a.x, a.y, a.z, a.w, bq.x, bq.y, bq.z, bq.w};
            s16x8 oh, ol;
            #pragma unroll
            for (int j = 0; j < 8; j++) {
                const float sv = v[j] * 0.125f;
                const short hh = f2bf(sv);
                oh[j] = hh; ol[j] = f2bf(sv - bf2f(hh));
            }
            *reinterpret_cast<s16x8*>(&Qh[r * AST + c0 + g * 8]) = oh;
            *reinterpret_cast<s16x8*>(&Ql[r * AST + c0 + g * 8]) = ol;
        }
    }

    f32x4 accO[4];
    #pragma unroll
    for (int n = 0; n < 4; n++) accO[n] = (f32x4){0.f, 0.f, 0.f, 0.f};
    float rs[4] = {0.f, 0.f, 0.f, 0.f};

    const size_t kbase = (size_t)(b * 4 + kvh) * S_ * 64;
    const size_t vbase = (size_t)(b * 4 + kvh) * 64 * S_;
    const int nkb = (q0 >> 6) + 1;

    for (int kb = 0; kb < nkb; kb++) {
        const int j0 = kb * 64;
        __syncthreads();
        {
            const int r = tid >> 2, c0 = (tid & 3) * 16;
            const short* ks = khi + kbase + (size_t)(j0 + r) * 64 + c0;
            const short* ls = klo + kbase + (size_t)(j0 + r) * 64 + c0;
            *reinterpret_cast<s16x8*>(&Kh[r * AST + c0])     = *reinterpret_cast<const s16x8*>(ks);
            *reinterpret_cast<s16x8*>(&Kh[r * AST + c0 + 8]) = *reinterpret_cast<const s16x8*>(ks + 8);
            *reinterpret_cast<s16x8*>(&Kl[r * AST + c0])     = *reinterpret_cast<const s16x8*>(ls);
            *reinterpret_cast<s16x8*>(&Kl[r * AST + c0 + 8]) = *reinterpret_cast<const s16x8*>(ls + 8);
            const short* vs = vth + vbase + (size_t)r * S_ + j0 + c0;
            const short* vl = vtl + vbase + (size_t)r * S_ + j0 + c0;
            *reinterpret_cast<s16x8*>(&Vh[r * AST + c0])     = *reinterpret_cast<const s16x8*>(vs);
            *reinterpret_cast<s16x8*>(&Vh[r * AST + c0 + 8]) = *reinterpret_cast<const s16x8*>(vs + 8);
            *reinterpret_cast<s16x8*>(&Vl[r * AST + c0])     = *reinterpret_cast<const s16x8*>(vl);
            *reinterpret_cast<s16x8*>(&Vl[r * AST + c0 + 8]) = *reinterpret_cast<const s16x8*>(vl + 8);
        }
        __syncthreads();

        f32x4 accS[4];
        #pragma unroll
        for (int n = 0; n < 4; n++) accS[n] = (f32x4){0.f, 0.f, 0.f, 0.f};
        #pragma unroll
        for (int ks2 = 0; ks2 < 2; ks2++) {
            const int ko = ks2 * 32 + fg * 4;
            const s16x8 ah = ldfrag(&Qh[(w * 16 + fr) * AST + ko]);
            const s16x8 al = ldfrag(&Ql[(w * 16 + fr) * AST + ko]);
            #pragma unroll
            for (int n = 0; n < 4; n++) {
                const int base = (n * 16 + fr) * AST + ko;
                const s16x8 bh = ldfrag(&Kh[base]);
                const s16x8 bl = ldfrag(&Kl[base]);
                accS[n] = __builtin_amdgcn_mfma_f32_16x16x32_bf16(ah, bh, accS[n], 0, 0, 0);
                accS[n] = __builtin_amdgcn_mfma_f32_16x16x32_bf16(al, bh, accS[n], 0, 0, 0);
                accS[n] = __builtin_amdgcn_mfma_f32_16x16x32_bf16(ah, bl, accS[n], 0, 0, 0);
            }
        }

        #pragma unroll
        for (int r = 0; r < 4; r++) {
            const int qrow = q0 + w * 16 + fg * 4 + r;
            float ev[4];
            float p = 0.f;
            #pragma unroll
            for (int n = 0; n < 4; n++) {
                const int key = j0 + n * 16 + fr;
                const float e = (key <= qrow) ? expf(accS[n][r]) : 0.f;
                ev[n] = e; p += e;
            }
            p += __shfl_xor(p, 1, 64); p += __shfl_xor(p, 2, 64);
            p += __shfl_xor(p, 4, 64); p += __shfl_xor(p, 8, 64);
            rs[r] += p;
            #pragma unroll
            for (int n = 0; n < 4; n++) {
                const int addr = (w * 16 + fg * 4 + r) * AST + n * 16 + fr;
                const short hh = f2bf(ev[n]);
                Ph[addr] = hh;
                Pl[addr] = f2bf(ev[n] - bf2f(hh));
            }
        }
        __builtin_amdgcn_wave_barrier();

        #pragma unroll
        for (int ks2 = 0; ks2 < 2; ks2++) {
            const int ko = ks2 * 32 + fg * 4;
            const s16x8 ph = ldfrag(&Ph[(w * 16 + fr) * AST + ko]);
            const s16x8 pl = ldfrag(&Pl[(w * 16 + fr) * AST + ko]);
            #pragma unroll
            for (int n = 0; n < 4; n++) {
                const int base = (n * 16 + fr) * AST + ko;
                const s16x8 vh = ldfrag(&Vh[base]);
                const s16x8 vl = ldfrag(&Vl[base]);
                accO[n] = __builtin_amdgcn_mfma_f32_16x16x32_bf16(ph, vh, accO[n], 0, 0, 0);
                accO[n] = __builtin_amdgcn_mfma_f32_16x16x32_bf16(pl, vh, accO[n], 0, 0, 0);
                accO[n] = __builtin_amdgcn_mfma_f32_16x16x32_bf16(ph, vl, accO[n], 0, 0, 0);
            }
        }
    }

    #pragma unroll
    for (int r = 0; r < 4; r++) {
        const float inv = 1.0f / rs[r];
        const int qrow = q0 + w * 16 + fg * 4 + r;
        const size_t ob = (size_t)(b * S_ + qrow) * H_ + h * HD_;
        #pragma unroll
        for (int n = 0; n < 4; n++) {
            const float v = accO[n][r] * inv;
            const short hh = f2bf(v);
            obh[ob + n * 16 + fr] = hh;
            obl[ob + n * 16 + fr] = f2bf(v - bf2f(hh));
        }
    }
}

// ---------------- MoE gate ----------------
__global__ __launch_bounds__(64)
void k_gate(const float* __restrict__ h, const float* __restrict__ gwt, float* __restrict__ w)
{
    const int t = blockIdx.x;
    const int lane = threadIdx.x;
    const float* row = h + (size_t)t * H_;
    float acc[E_];
    #pragma unroll
    for (int e = 0; e < E_; e++) acc[e] = 0.f;
    for (int i = lane; i < H_; i += 64) {
        const float xv = row[i];
        #pragma unroll
        for (int e = 0; e < E_; e++) acc[e] += xv * gwt[(size_t)e * H_ + i];
    }
    #pragma unroll
    for (int e = 0; e < E_; e++) {
        #pragma unroll
        for (int off = 32; off > 0; off >>= 1) acc[e] += __shfl_down(acc[e], off, 64);
    }
    if (lane == 0) {
        int i1 = 0; float m1 = acc[0];
        #pragma unroll
        for (int e = 1; e < E_; e++) if (acc[e] > m1) { m1 = acc[e]; i1 = e; }
        int i2 = -1; float m2 = -1e30f;
        #pragma unroll
        for (int e = 0; e < E_; e++) if (e != i1 && acc[e] > m2) { m2 = acc[e]; i2 = e; }
        const float e2  = expf(m2 - m1);
        const float den = 1.0f + e2;
        #pragma unroll
        for (int e = 0; e < E_; e++)
            w[t * E_ + e] = (e == i1) ? (1.0f / den) : ((e == i2) ? (e2 / den) : 0.f);
    }
}

// ---------------- build per-expert token lists ----------------
__global__ __launch_bounds__(512)
void k_build(const float* __restrict__ gw, int* __restrict__ idx, float* __restrict__ wl,
             int* __restrict__ pos, int* __restrict__ cnt, int* __restrict__ seg)
{
    const int e = threadIdx.x >> 6;
    const int lane = threadIdx.x & 63;
    __shared__ int scnt[E_], sseg[E_];
    int c = 0;
    for (int t0 = 0; t0 < T_; t0 += 64) {
        const float v = gw[(size_t)(t0 + lane) * E_ + e];
        c += __popcll(__ballot(v > 0.f));
    }
    if (lane == 0) scnt[e] = c;
    __syncthreads();
    if (threadIdx.x == 0) {
        int off = 0;
        for (int q = 0; q < E_; q++) {
            sseg[q] = off; cnt[q] = scnt[q]; seg[q] = off;
            off += (scnt[q] + 127) & ~127;
        }
    }
    __syncthreads();
    int p = sseg[e];
    for (int t0 = 0; t0 < T_; t0 += 64) {
        const int t = t0 + lane;
        const float v = gw[(size_t)t * E_ + e];
        const unsigned long long m = __ballot(v > 0.f);
        if (v > 0.f) {
            const int pp = p + __popcll(m & ((1ull << lane) - 1ull));
            idx[pp] = t; wl[pp] = v;
            int slot = 0;
            for (int q = 0; q < e; q++) slot += (gw[(size_t)t * E_ + q] > 0.f) ? 1 : 0;
            pos[t * 2 + slot] = pp;
        }
        p += __popcll(m);
    }
}

// ---------------- combine ----------------
__global__ void k_combine(float* __restrict__ x, const float* __restrict__ ebuf,
                          const float* __restrict__ wl, const int* __restrict__ pos)
{
    const int id = blockIdx.x * 256 + threadIdx.x;
    const int t = id >> 10;
    const int hc = id & 1023;
    const int p0 = pos[t * 2], p1 = pos[t * 2 + 1];
    x[id] += wl[p0] * ebuf[(size_t)p0 * H_ + hc] + wl[p1] * ebuf[(size_t)p1 * H_ + hc];
}

// ---------------- silu combine: split u (hi/lo) -> split p, in place ----------------
__global__ __launch_bounds__(256)
void k_silu_sp(const float* __restrict__ g, short* __restrict__ uh, short* __restrict__ ul)
{
    const size_t i = (size_t)blockIdx.x * 256 + threadIdx.x;
    const float gv = g[i];
    const float u = bf2f(uh[i]) + bf2f(ul[i]);
    const float p = gv * (1.f / (1.f + expf(-gv))) * u;
    const short hh = f2bf(p);
    uh[i] = hh;
    ul[i] = f2bf(p - bf2f(hh));
}

// ---------------- silu combine: plain bf16 u -> bf16 p, in place ----------------
__global__ __launch_bounds__(256)
void k_silu_b(const float* __restrict__ g, short* __restrict__ ub)
{
    const size_t i = (size_t)blockIdx.x * 256 + threadIdx.x;
    const float gv = g[i];
    const float p = gv * (1.f / (1.f + expf(-gv))) * bf2f(ub[i]);
    ub[i] = f2bf(p);
}

// ---------------- bf16-input MFMA GEMM, BK=64 (lm_head), XCD-swizzled ----------------
__global__ __launch_bounds__(256)
void k_mfma_bt64(const short* __restrict__ A, const short* __restrict__ Bm,
                 float* __restrict__ C, int M, int N, int K)
{
    __shared__ short Als[128 * LD64];
    __shared__ short Bls[128 * LD64];
    const int mB = M >> 7;
    const int nwg = mB * (N >> 7);
    int l = blockIdx.x;
    l = (l & 7) * (nwg >> 3) + (l >> 3);     // bijective XCD swizzle (nwg % 8 == 0)
    const int g  = l / (mB * 8);
    const int ii = l - g * (mB * 8);
    const int bm0 = (ii % mB) * 128;
    const int bn0 = (g * 8 + ii / mB) * 128;

    const int tid  = threadIdx.x;
    const int lane = tid & 63, w = tid >> 6;
    const int wr = w >> 1, wc = w & 1;
    const int fr = lane & 15, fg = lane >> 4;
    const int srow = tid >> 1, sk = (tid & 1) * 32;

    const short* pa = A  + (size_t)(bm0 + srow) * K + sk;
    const short* pb = Bm + (size_t)(bn0 + srow) * K + sk;

    f32x4 acc[4][4];
    #pragma unroll
    for (int m = 0; m < 4; m++)
        #pragma unroll
        for (int n = 0; n < 4; n++) acc[m][n] = (f32x4){0.f, 0.f, 0.f, 0.f};

    s16x8 ra[4], rb[4];
    #pragma unroll
    for (int q = 0; q < 4; q++) {
        ra[q] = *reinterpret_cast<const s16x8*>(pa + q * 8);
        rb[q] = *reinterpret_cast<const s16x8*>(pb + q * 8);
    }

    for (int k0 = 0; k0 < K; k0 += 64) {
        __syncthreads();
        #pragma unroll
        for (int q = 0; q < 4; q++) {
            *reinterpret_cast<s16x8*>(&Als[srow * LD64 + sk + q * 8]) = ra[q];
            *reinterpret_cast<s16x8*>(&Bls[srow * LD64 + sk + q * 8]) = rb[q];
        }
        __syncthreads();
        if (k0 + 64 < K) {
            #pragma unroll
            for (int q = 0; q < 4; q++) {
                ra[q] = *reinterpret_cast<const s16x8*>(pa + k0 + 64 + q * 8);
                rb[q] = *reinterpret_cast<const s16x8*>(pb + k0 + 64 + q * 8);
            }
        }
        #pragma unroll
        for (int ks2 = 0; ks2 < 2; ks2++) {
            const int ko = ks2 * 32 + fg * 4;
            s16x8 af[4], bfv[4];
            #pragma unroll
            for (int m = 0; m < 4; m++)
                af[m] = ldfrag(&Als[(wr * 64 + m * 16 + fr) * LD64 + ko]);
            #pragma unroll
            for (int n = 0; n < 4; n++)
                bfv[n] = ldfrag(&Bls[(wc * 64 + n * 16 + fr) * LD64 + ko]);
            #pragma unroll
            for (int m = 0; m < 4; m++)
                #pragma unroll
                for (int n = 0; n < 4; n++)
                    acc[m][n] = __builtin_amdgcn_mfma_f32_16x16x32_bf16(af[m], bfv[n], acc[m][n], 0, 0, 0);
        }
    }

    #pragma unroll
    for (int m = 0; m < 4; m++)
        #pragma unroll
        for (int n = 0; n < 4; n++)
            #pragma unroll
            for (int r = 0; r < 4; r++) {
                const int row = bm0 + wr * 64 + m * 16 + fg * 4 + r;
                const int col = bn0 + wc * 64 + n * 16 + fr;
                C[(size_t)row * N + col] = acc[m][n][r];
            }
}

// ---------------- bf16-input MFMA MoE GEMM (L2 value path; sd/wd) ----------------
// MODE 0: flat A | 1: gather-A | 2: flat compacted A. EPI 0: store f32 | 2: +=
template<int MODE, int EPI>
__global__ __launch_bounds__(256)
void k_mfma_moe_b(const short* __restrict__ A, const short* __restrict__ Bm,
                  float* __restrict__ Cf,
                  const int* __restrict__ idx, const int* __restrict__ cnt,
                  const int* __restrict__ seg, int N, int K)
{
    int c = T_, s = 0;
    const int bm0 = blockIdx.y * 128, bn0 = blockIdx.x * 128;
    if (MODE >= 1) {
        const int e = blockIdx.z;
        c = cnt[e];
        if (bm0 >= c) return;
        s = seg[e];
        Bm += (size_t)e * N * K;
    }
    __shared__ short Als[128 * LDST];
    __shared__ short Bls[128 * LDST];
    const int tid  = threadIdx.x;
    const int lane = tid & 63, w = tid >> 6;
    const int wr = w >> 1, wc = w & 1;
    const int fr = lane & 15, fg = lane >> 4;
    const int srow = tid >> 1, sk = (tid & 1) * 16;

    int arow;
    if (MODE == 0)      arow = bm0 + srow;
    else if (MODE == 1) arow = idx[s + min(bm0 + srow, c - 1)];
    else                arow = s + min(bm0 + srow, c - 1);
    const short* pa = A  + (size_t)arow * K + sk;
    const short* pb = Bm + (size_t)(bn0 + srow) * K + sk;

    f32x4 acc[4][4];
    #pragma unroll
    for (int m = 0; m < 4; m++)
        #pragma unroll
        for (int n = 0; n < 4; n++) acc[m][n] = (f32x4){0.f, 0.f, 0.f, 0.f};

    s16x8 ra0 = *reinterpret_cast<const s16x8*>(pa);
    s16x8 ra1 = *reinterpret_cast<const s16x8*>(pa + 8);
    s16x8 rb0 = *reinterpret_cast<const s16x8*>(pb);
    s16x8 rb1 = *reinterpret_cast<const s16x8*>(pb + 8);

    for (int k0 = 0; k0 < K; k0 += 32) {
        __syncthreads();
        *reinterpret_cast<s16x8*>(&Als[srow * LDST + sk])     = ra0;
        *reinterpret_cast<s16x8*>(&Als[srow * LDST + sk + 8]) = ra1;
        *reinterpret_cast<s16x8*>(&Bls[srow * LDST + sk])     = rb0;
        *reinterpret_cast<s16x8*>(&Bls[srow * LDST + sk + 8]) = rb1;
        __syncthreads();
        if (k0 + 32 < K) {
            ra0 = *reinterpret_cast<const s16x8*>(pa + k0 + 32);
            ra1 = *reinterpret_cast<const s16x8*>(pa + k0 + 40);
            rb0 = *reinterpret_cast<const s16x8*>(pb + k0 + 32);
            rb1 = *reinterpret_cast<const s16x8*>(pb + k0 + 40);
        }
        s16x8 af[4], bfv[4];
        #pragma unroll
        for (int m = 0; m < 4; m++)
            af[m] = ldfrag(&Als[(wr * 64 + m * 16 + fr) * LDST + fg * 4]);
        #pragma unroll
        for (int n = 0; n < 4; n++)
            bfv[n] = ldfrag(&Bls[(wc * 64 + n * 16 + fr) * LDST + fg * 4]);
        #pragma unroll
        for (int m = 0; m < 4; m++)
            #pragma unroll
            for (int n = 0; n < 4; n++)
                acc[m][n] = __builtin_amdgcn_mfma_f32_16x16x32_bf16(af[m], bfv[n], acc[m][n], 0, 0, 0);
    }

    #pragma unroll
    for (int m = 0; m < 4; m++)
        #pragma unroll
        for (int n = 0; n < 4; n++)
            #pragma unroll
            for (int r = 0; r < 4; r++) {
                const int row = bm0 + wr * 64 + m * 16 + fg * 4 + r;
                if (MODE >= 1 && row >= c) continue;
                const int col = bn0 + wc * 64 + n * 16 + fr;
                const size_t p = (size_t)((MODE >= 1 ? s : 0) + row) * N + col;
                if (EPI == 0) Cf[p] = acc[m][n][r];
                else          Cf[p] += acc[m][n][r];
            }
}

// ---------------- plain bf16 fused wg|wu GEMM (L2): g -> f32, u -> bf16 ----------------
template<int MODE>
__global__ __launch_bounds__(256)
void k_mfma_b_gu(const short* __restrict__ A, const short* __restrict__ Bg,
                 const short* __restrict__ Bu, float* __restrict__ Cg,
                 short* __restrict__ Cu,
                 const int* __restrict__ idx, const int* __restrict__ cnt,
                 const int* __restrict__ seg, int K)
{
    int c = T_, s = 0;
    const int bm0 = blockIdx.y * 128;
    const int bn0all = blockIdx.x * 128;
    if (MODE >= 1) {
        const int e = blockIdx.z;
        c = cnt[e];
        if (bm0 >= c) return;
        s = seg[e];
        Bg += (size_t)e * I_ * K;
        Bu += (size_t)e * I_ * K;
    }
    const int isU = (bn0all >= I_) ? 1 : 0;
    const int bn0 = bn0all - isU * I_;
    const short* Bm = isU ? Bu : Bg;

    __shared__ short Als[128 * LDST];
    __shared__ short Bls[128 * LDST];
    const int tid  = threadIdx.x;
    const int lane = tid & 63, w = tid >> 6;
    const int wr = w >> 1, wc = w & 1;
    const int fr = lane & 15, fg = lane >> 4;
    const int srow = tid >> 1, sk = (tid & 1) * 16;

    int arow;
    if (MODE == 0) arow = bm0 + srow;
    else           arow = idx[s + min(bm0 + srow, c - 1)];
    const short* pa = A  + (size_t)arow * K + sk;
    const short* pb = Bm + (size_t)(bn0 + srow) * K + sk;

    f32x4 acc[4][4];
    #pragma unroll
    for (int m = 0; m < 4; m++)
        #pragma unroll
        for (int n = 0; n < 4; n++) acc[m][n] = (f32x4){0.f, 0.f, 0.f, 0.f};

    s16x8 ra0 = *reinterpret_cast<const s16x8*>(pa);
    s16x8 ra1 = *reinterpret_cast<const s16x8*>(pa + 8);
    s16x8 rb0 = *reinterpret_cast<const s16x8*>(pb);
    s16x8 rb1 = *reinterpret_cast<const s16x8*>(pb + 8);

    for (int k0 = 0; k0 < K; k0 += 32) {
        __syncthreads();
        *reinterpret_cast<s16x8*>(&Als[srow * LDST + sk])     = ra0;
        *reinterpret_cast<s16x8*>(&Als[srow * LDST + sk + 8]) = ra1;
        *reinterpret_cast<s16x8*>(&Bls[srow * LDST + sk])     = rb0;
        *reinterpret_cast<s16x8*>(&Bls[srow * LDST + sk + 8]) = rb1;
        __syncthreads();
        if (k0 + 32 < K) {
            ra0 = *reinterpret_cast<const s16x8*>(pa + k0 + 32);
            ra1 = *reinterpret_cast<const s16x8*>(pa + k0 + 40);
            rb0 = *reinterpret_cast<const s16x8*>(pb + k0 + 32);
            rb1 = *reinterpret_cast<const s16x8*>(pb + k0 + 40);
        }
        s16x8 af[4], bfv[4];
        #pragma unroll
        for (int m = 0; m < 4; m++)
            af[m] = ldfrag(&Als[(wr * 64 + m * 16 + fr) * LDST + fg * 4]);
        #pragma unroll
        for (int n = 0; n < 4; n++)
            bfv[n] = ldfrag(&Bls[(wc * 64 + n * 16 + fr) * LDST + fg * 4]);
        #pragma unroll
        for (int m = 0; m < 4; m++)
            #pragma unroll
            for (int n = 0; n < 4; n++)
                acc[m][n] = __builtin_amdgcn_mfma_f32_16x16x32_bf16(af[m], bfv[n], acc[m][n], 0, 0, 0);
    }

    #pragma unroll
    for (int m = 0; m < 4; m++)
        #pragma unroll
        for (int n = 0; n < 4; n++)
            #pragma unroll
            for (int r = 0; r < 4; r++) {
                const int row = bm0 + wr * 64 + m * 16 + fg * 4 + r;
                if (MODE >= 1 && row >= c) continue;
                const int col = bn0 + wc * 64 + n * 16 + fr;
                const size_t p = (size_t)((MODE >= 1 ? s : 0) + row) * I_ + col;
                if (!isU) Cg[p] = acc[m][n][r];
                else      Cu[p] = f2bf(acc[m][n][r]);
            }
}

// ---------------- split-bf16-input MFMA GEMM (routing-safe; qkv/wo/sd/wd) ----------------
// EPI 0: store f32 | 2: += f32 | 3: split store hi/lo
template<int MODE, int EPI>
__global__ __launch_bounds__(256)
void k_mfma_sp_b(const short* __restrict__ Ah, const short* __restrict__ Alp,
                 const short* __restrict__ Bh, const short* __restrict__ Blp,
                 float* __restrict__ Cf, short* __restrict__ Chi, short* __restrict__ Clo,
                 const int* __restrict__ idx, const int* __restrict__ cnt,
                 const int* __restrict__ seg, int N, int K)
{
    int c = T_, s = 0;
    const int bm0 = blockIdx.y * 128, bn0 = blockIdx.x * 128;
    if (MODE >= 1) {
        const int e = blockIdx.z;
        c = cnt[e];
        if (bm0 >= c) return;
        s = seg[e];
        Bh  += (size_t)e * N * K;
        Blp += (size_t)e * N * K;
    }
    __shared__ short LAh[128 * LDST];
    __shared__ short LAl[128 * LDST];
    __shared__ short LBh[128 * LDST];
    __shared__ short LBl[128 * LDST];
    const int tid  = threadIdx.x;
    const int lane = tid & 63, w = tid >> 6;
    const int wr = w >> 1, wc = w & 1;
    const int fr = lane & 15, fg = lane >> 4;
    const int srow = tid >> 1, sk = (tid & 1) * 16;

    int arow;
    if (MODE == 0)      arow = bm0 + srow;
    else if (MODE == 1) arow = idx[s + min(bm0 + srow, c - 1)];
    else                arow = s + min(bm0 + srow, c - 1);
    const short* pah = Ah  + (size_t)arow * K + sk;
    const short* pal = Alp + (size_t)arow * K + sk;
    const short* pbh = Bh  + (size_t)(bn0 + srow) * K + sk;
    const short* pbl = Blp + (size_t)(bn0 + srow) * K + sk;

    f32x4 acc[4][4];
    #pragma unroll
    for (int m = 0; m < 4; m++)
        #pragma unroll
        for (int n = 0; n < 4; n++) acc[m][n] = (f32x4){0.f, 0.f, 0.f, 0.f};

    s16x8 rah0 = *reinterpret_cast<const s16x8*>(pah);
    s16x8 rah1 = *reinterpret_cast<const s16x8*>(pah + 8);
    s16x8 ral0 = *reinterpret_cast<const s16x8*>(pal);
    s16x8 ral1 = *reinterpret_cast<const s16x8*>(pal + 8);
    s16x8 rbh0 = *reinterpret_cast<const s16x8*>(pbh);
    s16x8 rbh1 = *reinterpret_cast<const s16x8*>(pbh + 8);
    s16x8 rbl0 = *reinterpret_cast<const s16x8*>(pbl);
    s16x8 rbl1 = *reinterpret_cast<const s16x8*>(pbl + 8);

    for (int k0 = 0; k0 < K; k0 += 32) {
        __syncthreads();
        *reinterpret_cast<s16x8*>(&LAh[srow * LDST + sk])     = rah0;
        *reinterpret_cast<s16x8*>(&LAh[srow * LDST + sk + 8]) = rah1;
        *reinterpret_cast<s16x8*>(&LAl[srow * LDST + sk])     = ral0;
        *reinterpret_cast<s16x8*>(&LAl[srow * LDST + sk + 8]) = ral1;
        *reinterpret_cast<s16x8*>(&LBh[srow * LDST + sk])     = rbh0;
        *reinterpret_cast<s16x8*>(&LBh[srow * LDST + sk + 8]) = rbh1;
        *reinterpret_cast<s16x8*>(&LBl[srow * LDST + sk])     = rbl0;
        *reinterpret_cast<s16x8*>(&LBl[srow * LDST + sk + 8]) = rbl1;
        __syncthreads();
        if (k0 + 32 < K) {
            rah0 = *reinterpret_cast<const s16x8*>(pah + k0 + 32);
            rah1 = *reinterpret_cast<const s16x8*>(pah + k0 + 40);
            ral0 = *reinterpret_cast<const s16x8*>(pal + k0 + 32);
            ral1 = *reinterpret_cast<const s16x8*>(pal + k0 + 40);
            rbh0 = *reinterpret_cast<const s16x8*>(pbh + k0 + 32);
            rbh1 = *reinterpret_cast<const s16x8*>(pbh + k0 + 40);
            rbl0 = *reinterpret_cast<const s16x8*>(pbl + k0 + 32);
            rbl1 = *reinterpret_cast<const s16x8*>(pbl + k0 + 40);
        }
        s16x8 afh[4], afl[4];
        #pragma unroll
        for (int m = 0; m < 4; m++) {
            afh[m] = ldfrag(&LAh[(wr * 64 + m * 16 + fr) * LDST + fg * 4]);
            afl[m] = ldfrag(&LAl[(wr * 64 + m * 16 + fr) * LDST + fg * 4]);
        }
        #pragma unroll
        for (int n = 0; n < 4; n++) {
            const s16x8 bh = ldfrag(&LBh[(wc * 64 + n * 16 + fr) * LDST + fg * 4]);
            const s16x8 bl = ldfrag(&LBl[(wc * 64 + n * 16 + fr) * LDST + fg * 4]);
            #pragma unroll
            for (int m = 0; m < 4; m++) {
                acc[m][n] = __builtin_amdgcn_mfma_f32_16x16x32_bf16(afh[m], bh, acc[m][n], 0, 0, 0);
                acc[m][n] = __builtin_amdgcn_mfma_f32_16x16x32_bf16(afl[m], bh, acc[m][n], 0, 0, 0);
                acc[m][n] = __builtin_amdgcn_mfma_f32_16x16x32_bf16(afh[m], bl, acc[m][n], 0, 0, 0);
            }
        }
    }

    #pragma unroll
    for (int m = 0; m < 4; m++)
        #pragma unroll
        for (int n = 0; n < 4; n++)
            #pragma unroll
            for (int r = 0; r < 4; r++) {
                const int row = bm0 + wr * 64 + m * 16 + fg * 4 + r;
                if (MODE >= 1 && row >= c) continue;
                const int col = bn0 + wc * 64 + n * 16 + fr;
                const size_t p = (size_t)((MODE >= 1 ? s : 0) + row) * N + col;
                if (EPI == 0)      Cf[p] = acc[m][n][r];
                else if (EPI == 2) Cf[p] += acc[m][n][r];
                else {
                    const short hh = f2bf(acc[m][n][r]);
                    Chi[p] = hh;
                    Clo[p] = f2bf(acc[m][n][r] - bf2f(hh));
                }
            }
}

// ---------------- split-bf16 fused wg|wu GEMM (L1): g -> f32, u -> split hi/lo ----------------
template<int MODE>
__global__ __launch_bounds__(256)
void k_mfma_sp_gu(const short* __restrict__ Ah, const short* __restrict__ Alp,
                  const short* __restrict__ Bgh, const short* __restrict__ Bgl,
                  const short* __restrict__ Buh, const short* __restrict__ Bul,
                  float* __restrict__ Cg, short* __restrict__ Cuh, short* __restrict__ Cul,
                  const int* __restrict__ idx, const int* __restrict__ cnt,
                  const int* __restrict__ seg, int K)
{
    int c = T_, s = 0;
    const int bm0 = blockIdx.y * 128;
    const int bn0all = blockIdx.x * 128;
    if (MODE >= 1) {
        const int e = blockIdx.z;
        c = cnt[e];
        if (bm0 >= c) return;
        s = seg[e];
        Bgh += (size_t)e * I_ * K; Bgl += (size_t)e * I_ * K;
        Buh += (size_t)e * I_ * K; Bul += (size_t)e * I_ * K;
    }
    const int isU = (bn0all >= I_) ? 1 : 0;
    const int bn0 = bn0all - isU * I_;
    const short* Bh  = isU ? Buh : Bgh;
    const short* Blp = isU ? Bul : Bgl;

    __shared__ short LAh[128 * LDST];
    __shared__ short LAl[128 * LDST];
    __shared__ short LBh[128 * LDST];
    __shared__ short LBl[128 * LDST];
    const int tid  = threadIdx.x;
    const int lane = tid & 63, w = tid >> 6;
    const int wr = w >> 1, wc = w & 1;
    const int fr = lane & 15, fg = lane >> 4;
    const int srow = tid >> 1, sk = (tid & 1) * 16;

    int arow;
    if (MODE == 0) arow = bm0 + srow;
    else           arow = idx[s + min(bm0 + srow, c - 1)];
    const short* pah = Ah  + (size_t)arow * K + sk;
    const short* pal = Alp + (size_t)arow * K + sk;
    const short* pbh = Bh  + (size_t)(bn0 + srow) * K + sk;
    const short* pbl = Blp + (size_t)(bn0 + srow) * K + sk;

    f32x4 acc[4][4];
    #pragma unroll
    for (int m = 0; m < 4; m++)
        #pragma unroll
        for (int n = 0; n < 4; n++) acc[m][n] = (f32x4){0.f, 0.f, 0.f, 0.f};

    s16x8 rah0 = *reinterpret_cast<const s16x8*>(pah);
    s16x8 rah1 = *reinterpret_cast<const s16x8*>(pah + 8);
    s16x8 ral0 = *reinterpret_cast<const s16x8*>(pal);
    s16x8 ral1 = *reinterpret_cast<const s16x8*>(pal + 8);
    s16x8 rbh0 = *reinterpret_cast<const s16x8*>(pbh);
    s16x8 rbh1 = *reinterpret_cast<const s16x8*>(pbh + 8);
    s16x8 rbl0 = *reinterpret_cast<const s16x8*>(pbl);
    s16x8 rbl1 = *reinterpret_cast<const s16x8*>(pbl + 8);

    for (int k0 = 0; k0 < K; k0 += 32) {
        __syncthreads();
        *reinterpret_cast<s16x8*>(&LAh[srow * LDST + sk])     = rah0;
        *reinterpret_cast<s16x8*>(&LAh[srow * LDST + sk + 8]) = rah1;
        *reinterpret_cast<s16x8*>(&LAl[srow * LDST + sk])     = ral0;
        *reinterpret_cast<s16x8*>(&LAl[srow * LDST + sk + 8]) = ral1;
        *reinterpret_cast<s16x8*>(&LBh[srow * LDST + sk])     = rbh0;
        *reinterpret_cast<s16x8*>(&LBh[srow * LDST + sk + 8]) = rbh1;
        *reinterpret_cast<s16x8*>(&LBl[srow * LDST + sk])     = rbl0;
        *reinterpret_cast<s16x8*>(&LBl[srow * LDST + sk + 8]) = rbl1;
        __syncthreads();
        if (k0 + 32 < K) {
            rah0 = *reinterpret_cast<const s16x8*>(pah + k0 + 32);
            rah1 = *reinterpret_cast<const s16x8*>(pah + k0 + 40);
            ral0 = *reinterpret_cast<const s16x8*>(pal + k0 + 32);
            ral1 = *reinterpret_cast<const s16x8*>(pal + k0 + 40);
            rbh0 = *reinterpret_cast<const s16x8*>(pbh + k0 + 32);
            rbh1 = *reinterpret_cast<const s16x8*>(pbh + k0 + 40);
            rbl0 = *reinterpret_cast<const s16x8*>(pbl + k0 + 32);
            rbl1 = *reinterpret_cast<const s16x8*>(pbl + k0 + 40);
        }
        s16x8 afh[4], afl[4];
        #pragma unroll
        for (int m = 0; m < 4; m++) {
            afh[m] = ldfrag(&LAh[(wr * 64 + m * 16 + fr) * LDST + fg * 4]);
            afl[m] = ldfrag(&LAl[(wr * 64 + m * 16 + fr) * LDST + fg * 4]);
        }
        #pragma unroll
        for (int n = 0; n < 4; n++) {
            const s16x8 bh = ldfrag(&LBh[(wc * 64 + n * 16 + fr) * LDST + fg * 4]);
            const s16x8 bl = ldfrag(&LBl[(wc * 64 + n * 16 + fr) * LDST + fg * 4]);
            #pragma unroll
            for (int m = 0; m < 4; m++) {
                acc[m][n] = __builtin_amdgcn_mfma_f32_16x16x32_bf16(afh[m], bh, acc[m][n], 0, 0, 0);
                acc[m][n] = __builtin_amdgcn_mfma_f32_16x16x32_bf16(afl[m], bh, acc[m][n], 0, 0, 0);
                acc[m][n] = __builtin_amdgcn_mfma_f32_16x16x32_bf16(afh[m], bl, acc[m][n], 0, 0, 0);
            }
        }
    }

    #pragma unroll
    for (int m = 0; m < 4; m++)
        #pragma unroll
        for (int n = 0; n < 4; n++)
            #pragma unroll
            for (int r = 0; r < 4; r++) {
                const int row = bm0 + wr * 64 + m * 16 + fg * 4 + r;
                if (MODE >= 1 && row >= c) continue;
                const int col = bn0 + wc * 64 + n * 16 + fr;
                const size_t p = (size_t)((MODE >= 1 ? s : 0) + row) * I_ + col;
                if (!isU) {
                    Cg[p] = acc[m][n][r];
                } else {
                    const short hh = f2bf(acc[m][n][r]);
                    Cuh[p] = hh;
                    Cul[p] = f2bf(acc[m][n][r] - bf2f(hh));
                }
            }
}

extern "C" void kernel_launch(void* const* d_in, const int* in_sizes, int n_in,
                              void* d_out, int out_size, void* d_ws, size_t ws_size,
                              hipStream_t stream)
{
    const int*   ids    = (const int*)  d_in[0];
    const float* embed  = (const float*)d_in[1];
    const float* ln1_g  = (const float*)d_in[2];
    const float* ln1_b  = (const float*)d_in[3];
    const float* wq     = (const float*)d_in[4];
    const float* wk     = (const float*)d_in[5];
    const float* wv     = (const float*)d_in[6];
    const float* wo     = (const float*)d_in[7];
    const float* ln2_g  = (const float*)d_in[8];
    const float* ln2_b  = (const float*)d_in[9];
    const float* gate_w = (const float*)d_in[10];
    const float* exp_wg = (const float*)d_in[11];
    const float* exp_wu = (const float*)d_in[12];
    const float* exp_wd = (const float*)d_in[13];
    const float* sh_wg  = (const float*)d_in[14];
    const float* sh_wu  = (const float*)d_in[15];
    const float* sh_wd  = (const float*)d_in[16];
    const float* fn_g   = (const float*)d_in[17];
    const float* fn_b   = (const float*)d_in[18];
    const float* lm     = (const float*)d_in[19];
    float* out = (float*)d_out;

    float* x    = (float*)d_ws;                 // T*H
    float* h    = x + 2097152;                  // T*H
    float* qkvp = h + 2097152;                  // R1: [T][1536]; ebuf aliases (5.24M f32)
    float* ebuf = qkvp;
    float* gbuf = qkvp + 5242880;               // CAP*I f32
    float* gw   = gbuf + 5242880;               // T*8
    float* wl   = gw + (size_t)T_ * E_;         // CAP
    int*   idx  = (int*)(wl + CAP_);            // CAP
    int*   pos  = idx + CAP_;                   // T*2
    int*   cnt  = pos + 2 * T_;                 // 8
    int*   seg  = cnt + E_;                     // 8 (+pad)
    short* hhi  = (short*)(seg + 64);           // T*H
    short* hlo  = hhi + 2097152;
    short* hbf  = hlo + 2097152;
    short* obh  = hbf + 2097152;                // attn O hi
    short* obl  = obh + 2097152;                // attn O lo
    short* gbh  = obl + 2097152;                // CAP*I
    short* gbl  = gbh + 5242880;                // CAP*I
    short* wb   = gbl + 5242880;                // 56.6M shorts, phase-reused
    const size_t EW = (size_t)E_ * I_ * H_;     // 8,388,608

    // attention-phase scratch inside wb
    short* qkvwh = wb;                          // [1536][1024] hi
    short* qkvwl = wb + 1572864;                // lo
    short* wowh  = wb + 3145728;                // [1024][1024] hi
    short* wowl  = wb + 4194304;                // lo
    short* khi_p = wb + 5242880;
    short* klo_p = khi_p + 524288;
    short* vth_p = klo_p + 524288;
    short* vtl_p = vth_p + 524288;

    k_embed<<<T_, 256, 0, stream>>>(ids, embed, x);

    for (int l = 0; l < L_; l++) {
        k_layernorm<2><<<T_, 256, 0, stream>>>(x, ln1_g + (size_t)l * H_, ln1_b + (size_t)l * H_, h, hhi, hlo);

        k_cvt_sp_t<<<dim3(16, 16), 256, 0, stream>>>(wq + (size_t)l * H_ * H_,   qkvwh,                qkvwl,                H_,  H_);
        k_cvt_sp_t<<<dim3(4, 16),  256, 0, stream>>>(wk + (size_t)l * H_ * 256,  qkvwh + 1024 * 1024,  qkvwl + 1024 * 1024,  256, H_);
        k_cvt_sp_t<<<dim3(4, 16),  256, 0, stream>>>(wv + (size_t)l * H_ * 256,  qkvwh + 1280 * 1024,  qkvwl + 1280 * 1024,  256, H_);
        k_cvt_sp_t<<<dim3(16, 16), 256, 0, stream>>>(wo + (size_t)l * H_ * H_,   wowh,                 wowl,                 H_,  H_);

        k_mfma_sp_b<0, 0><<<dim3(QKVN / 128, 16, 1), 256, 0, stream>>>(
            hhi, hlo, qkvwh, qkvwl, qkvp, nullptr, nullptr, nullptr, nullptr, nullptr, QKVN, H_);

        k_rope<<<(T_ * NH_  * 32) / 256, 256, 0, stream>>>(qkvp,        QKVN, NH_);
        k_rope<<<(T_ * NKV_ * 32) / 256, 256, 0, stream>>>(qkvp + 1024, QKVN, NKV_);

        k_cvt_kv<<<B_ * NKV_ * (S_ / 64), 256, 0, stream>>>(qkvp, khi_p, klo_p, vth_p, vtl_p);
        k_attn_mfma<<<dim3(S_ / 64, NH_, B_), 256, 0, stream>>>(qkvp, khi_p, klo_p, vth_p, vtl_p, obh, obl);

        k_mfma_sp_b<0, 2><<<dim3(8, 16, 1), 256, 0, stream>>>(
            obh, obl, wowh, wowl, x, nullptr, nullptr, nullptr, nullptr, nullptr, H_, H_);

        if (l == 0)
            k_layernorm<2><<<T_, 256, 0, stream>>>(x, ln2_g + (size_t)l * H_, ln2_b + (size_t)l * H_, h, hhi, hlo);
        else
            k_layernorm<1><<<T_, 256, 0, stream>>>(x, ln2_g + (size_t)l * H_, ln2_b + (size_t)l * H_, h, hbf, nullptr);
        k_gate<<<T_, 64, 0, stream>>>(h, gate_w + (size_t)l * E_ * H_, gw);
        k_build<<<1, 512, 0, stream>>>(gw, idx, wl, pos, cnt, seg);

        const float* wg_l = exp_wg + (size_t)l * EW;
        const float* wu_l = exp_wu + (size_t)l * EW;
        const float* wd_l = exp_wd + (size_t)l * EW;
        const float* sg_l = sh_wg + (size_t)l * I_ * H_;
        const float* su_l = sh_wu + (size_t)l * I_ * H_;
        const float* sd_l = sh_wd + (size_t)l * H_ * I_;

        if (l == 0) {
            short* wgh = wb;            short* wgl = wb + EW;
            short* wuh = wb + 2 * EW;   short* wul = wb + 3 * EW;
            short* wdh = wb + 4 * EW;   short* wdl = wb + 5 * EW;
            short* sgh = wb + 6 * EW;   short* sgl = sgh + 1048576;
            short* suh = sgl + 1048576; short* sul = suh + 1048576;
            short* sdh = sul + 1048576; short* sdl = sdh + 1048576;

            k_cvt_sp<<<4096, 256, 0, stream>>>(wg_l, wgh, wgl, (int)(EW / 8));
            k_cvt_sp<<<4096, 256, 0, stream>>>(wu_l, wuh, wul, (int)(EW / 8));
            k_cvt_sp<<<4096, 256, 0, stream>>>(wd_l, wdh, wdl, (int)(EW / 8));
            k_cvt_sp<<<512,  256, 0, stream>>>(sg_l, sgh, sgl, 131072);
            k_cvt_sp<<<512,  256, 0, stream>>>(su_l, suh, sul, 131072);
            k_cvt_sp<<<512,  256, 0, stream>>>(sd_l, sdh, sdl, 131072);

            // shared expert: fused wg|wu -> silu -> sd
            k_mfma_sp_gu<0><<<dim3(16, 16, 1), 256, 0, stream>>>(
                hhi, hlo, sgh, sgl, suh, sul, gbuf, gbh, gbl, nullptr, nullptr, nullptr, H_);
            k_silu_sp<<<(T_ * I_) / 256, 256, 0, stream>>>(gbuf, gbh, gbl);
            k_mfma_sp_b<0, 2><<<dim3(8, 16, 1), 256, 0, stream>>>(
                gbh, gbl, sdh, sdl, x, nullptr, nullptr, nullptr, nullptr, nullptr, H_, I_);
            // routed experts: fused wg|wu -> silu -> wd
            k_mfma_sp_gu<1><<<dim3(16, 16, E_), 256, 0, stream>>>(
                hhi, hlo, wgh, wgl, wuh, wul, gbuf, gbh, gbl, idx, cnt, seg, H_);
            k_silu_sp<<<(CAP_ * I_) / 256, 256, 0, stream>>>(gbuf, gbh, gbl);
            k_mfma_sp_b<2, 0><<<dim3(8, 16, E_), 256, 0, stream>>>(
                gbh, gbl, wdh, wdl, ebuf, nullptr, nullptr, idx, cnt, seg, H_, I_);
        } else {
            short* wgb = wb;            short* wub = wb + EW;       short* wdb = wb + 2 * EW;
            short* sgb = wb + 3 * EW;   short* sub = sgb + 1048576; short* sdb = sub + 1048576;

            k_cvt<<<4096, 256, 0, stream>>>(wg_l, wgb, (int)(EW / 8));
            k_cvt<<<4096, 256, 0, stream>>>(wu_l, wub, (int)(EW / 8));
            k_cvt<<<4096, 256, 0, stream>>>(wd_l, wdb, (int)(EW / 8));
            k_cvt<<<512,  256, 0, stream>>>(sg_l, sgb, 131072);
            k_cvt<<<512,  256, 0, stream>>>(su_l, sub, 131072);
            k_cvt<<<512,  256, 0, stream>>>(sd_l, sdb, 131072);

            k_mfma_b_gu<0><<<dim3(16, 16, 1), 256, 0, stream>>>(
                hbf, sgb, sub, gbuf, gbh, nullptr, nullptr, nullptr, H_);
            k_silu_b<<<(T_ * I_) / 256, 256, 0, stream>>>(gbuf, gbh);
            k_mfma_moe_b<0, 2><<<dim3(8, 16, 1), 256, 0, stream>>>(
                gbh, sdb, x, nullptr, nullptr, nullptr, H_, I_);
            k_mfma_b_gu<1><<<dim3(16, 16, E_), 256, 0, stream>>>(
                hbf, wgb, wub, gbuf, gbh, idx, cnt, seg, H_);
            k_silu_b<<<(CAP_ * I_) / 256, 256, 0, stream>>>(gbuf, gbh);
            k_mfma_moe_b<2, 0><<<dim3(8, 16, E_), 256, 0, stream>>>(
                gbh, wdb, ebuf, idx, cnt, seg, H_, I_);
        }
        k_combine<<<(T_ * H_) / 256, 256, 0, stream>>>(x, ebuf, wl, pos);
    }

    k_layernorm<1><<<T_, 256, 0, stream>>>(x, fn_g, fn_b, h, hbf, nullptr);
    k_cvt<<<16000, 256, 0, stream>>>(lm, wb, 4096000);
    k_mfma_bt64<<<(T_ / 128) * (V_ / 128), 256, 0, stream>>>(hbf, wb, out, T_, V_, H_);
}